// Round 1
// baseline (28939.316 us; speedup 1.0000x reference)
//
#include <hip/hip_runtime.h>
#include <cstdint>
#include <cstddef>

typedef _Float16 f16;
typedef _Float16 f16x8 __attribute__((ext_vector_type(8)));
typedef float f32x4 __attribute__((ext_vector_type(4)));
typedef float f32x2 __attribute__((ext_vector_type(2)));

#define MFMA_F16(a,b,c) __builtin_amdgcn_mfma_f32_16x16x32_f16((a),(b),(c),0,0,0)

#define NCLS 16
// counter sets
#define CT_A1 0   // layer1 z-stats round
#define CT_P1 1   // layer1 (c,so) publish round
#define CT_A2 2   // layer2 z-stats round
#define CT_P2 3   // layer2 (c,so) publish round
#define CT_C  4   // layer2 consumed co1 slot (throttle)

#define LOG2E2 2.885390081777927f

__device__ __forceinline__ float sigf(float x){ return 1.f/(1.f + expf(-x)); }

__device__ __forceinline__ void st_wt_f16(f16* p, f16 v){
  asm volatile("global_store_short %0, %1, off sc0 sc1" :: "v"(p), "v"(v) : "memory");
}
__device__ __forceinline__ void vm_drain(){ asm volatile("s_waitcnt vmcnt(0)" ::: "memory"); }
__device__ __forceinline__ void vm_wait_sb(){
  asm volatile("s_waitcnt vmcnt(0)" ::: "memory");
  __builtin_amdgcn_sched_barrier(0);
}

__device__ __forceinline__ void bar_arrive(unsigned* c){
  __hip_atomic_fetch_add(c, 1u, __ATOMIC_RELAXED, __HIP_MEMORY_SCOPE_AGENT);
}
__device__ __forceinline__ void bar_poll(const unsigned* ctrs, int set, int tid, unsigned target){
  if (tid < NCLS){
    const unsigned* p = ctrs + (set*NCLS + tid)*16;
    while (__hip_atomic_load(p, __ATOMIC_RELAXED, __HIP_MEMORY_SCOPE_AGENT) < target)
      __builtin_amdgcn_s_sleep(1);
  }
}

// Coherent load of 16 class-partial (s,q) pairs + LN stats.
__device__ __forceinline__ void ln_stats(const float* p, float invn, float& m, float& rs){
  f32x2 v0,v1,v2,v3,v4,v5,v6,v7,v8,v9,v10,v11,v12,v13,v14,v15;
  asm volatile(
    "global_load_dwordx2 %0, %16, off sc0 sc1\n\t"
    "global_load_dwordx2 %1, %16, off offset:256 sc0 sc1\n\t"
    "global_load_dwordx2 %2, %16, off offset:512 sc0 sc1\n\t"
    "global_load_dwordx2 %3, %16, off offset:768 sc0 sc1\n\t"
    "global_load_dwordx2 %4, %16, off offset:1024 sc0 sc1\n\t"
    "global_load_dwordx2 %5, %16, off offset:1280 sc0 sc1\n\t"
    "global_load_dwordx2 %6, %16, off offset:1536 sc0 sc1\n\t"
    "global_load_dwordx2 %7, %16, off offset:1792 sc0 sc1\n\t"
    "global_load_dwordx2 %8, %16, off offset:2048 sc0 sc1\n\t"
    "global_load_dwordx2 %9, %16, off offset:2304 sc0 sc1\n\t"
    "global_load_dwordx2 %10, %16, off offset:2560 sc0 sc1\n\t"
    "global_load_dwordx2 %11, %16, off offset:2816 sc0 sc1\n\t"
    "global_load_dwordx2 %12, %16, off offset:3072 sc0 sc1\n\t"
    "global_load_dwordx2 %13, %16, off offset:3328 sc0 sc1\n\t"
    "global_load_dwordx2 %14, %16, off offset:3584 sc0 sc1\n\t"
    "global_load_dwordx2 %15, %16, off offset:3840 sc0 sc1\n\t"
    "s_waitcnt vmcnt(0)"
    : "=&v"(v0),"=&v"(v1),"=&v"(v2),"=&v"(v3),"=&v"(v4),"=&v"(v5),"=&v"(v6),"=&v"(v7),
      "=&v"(v8),"=&v"(v9),"=&v"(v10),"=&v"(v11),"=&v"(v12),"=&v"(v13),"=&v"(v14),"=&v"(v15)
    : "v"(p) : "memory");
  float s = v0.x+v1.x+v2.x+v3.x+v4.x+v5.x+v6.x+v7.x+v8.x+v9.x+v10.x+v11.x+v12.x+v13.x+v14.x+v15.x;
  float q = v0.y+v1.y+v2.y+v3.y+v4.y+v5.y+v6.y+v7.y+v8.y+v9.y+v10.y+v11.y+v12.y+v13.y+v14.y+v15.y;
  m = s*invn; rs = rsqrtf(q*invn - m*m + 1e-5f);
}

// Coherent batched ISSUE (no wait) of 8+8 contiguous 16B chunks (c-row and so-row).
__device__ __forceinline__ void ld16_issue(const f16* cp, const f16* sp, f16x8* cf, f16x8* sf){
  asm volatile(
    "global_load_dwordx4 %0, %16, off sc0 sc1\n\t"
    "global_load_dwordx4 %1, %16, off offset:16 sc0 sc1\n\t"
    "global_load_dwordx4 %2, %16, off offset:32 sc0 sc1\n\t"
    "global_load_dwordx4 %3, %16, off offset:48 sc0 sc1\n\t"
    "global_load_dwordx4 %4, %16, off offset:64 sc0 sc1\n\t"
    "global_load_dwordx4 %5, %16, off offset:80 sc0 sc1\n\t"
    "global_load_dwordx4 %6, %16, off offset:96 sc0 sc1\n\t"
    "global_load_dwordx4 %7, %16, off offset:112 sc0 sc1\n\t"
    "global_load_dwordx4 %8, %17, off sc0 sc1\n\t"
    "global_load_dwordx4 %9, %17, off offset:16 sc0 sc1\n\t"
    "global_load_dwordx4 %10, %17, off offset:32 sc0 sc1\n\t"
    "global_load_dwordx4 %11, %17, off offset:48 sc0 sc1\n\t"
    "global_load_dwordx4 %12, %17, off offset:64 sc0 sc1\n\t"
    "global_load_dwordx4 %13, %17, off offset:80 sc0 sc1\n\t"
    "global_load_dwordx4 %14, %17, off offset:96 sc0 sc1\n\t"
    "global_load_dwordx4 %15, %17, off offset:112 sc0 sc1"
    : "=&v"(cf[0]),"=&v"(cf[1]),"=&v"(cf[2]),"=&v"(cf[3]),
      "=&v"(cf[4]),"=&v"(cf[5]),"=&v"(cf[6]),"=&v"(cf[7]),
      "=&v"(sf[0]),"=&v"(sf[1]),"=&v"(sf[2]),"=&v"(sf[3]),
      "=&v"(sf[4]),"=&v"(sf[5]),"=&v"(sf[6]),"=&v"(sf[7])
    : "v"(cp), "v"(sp) : "memory");
}

// Convert 8 chunks of (c,so) -> h = so*tanh(LN(c)*gc+bc) and store to swizzled LDS h-tile.
// Coefs in LDS are pre-scaled by 2*log2(e); nm = -mean*rstd, rc = rstd (per row).
__device__ __forceinline__ void cvt_store8(char* ht, int row, int k0,
    const f16x8* cf, const f16x8* sf, const f16* gA, const f16* bA,
    float nm, float rc){
  const int swz = (row & 7) << 4;
  const int rbase = row << 11;
  #pragma unroll
  for (int j = 0; j < 8; ++j){
    f16x8 g8 = *(const f16x8*)(gA + k0 + j*8);
    f16x8 b8 = *(const f16x8*)(bA + k0 + j*8);
    f16x8 hv;
    #pragma unroll
    for (int l = 0; l < 8; ++l){
      float c = (float)cf[j][l];
      float arg = fmaf(fmaf(c, rc, nm), (float)g8[l], (float)b8[l]);
      float e = exp2f(arg);
      float h = (float)sf[j][l] * fmaf(-2.f, __builtin_amdgcn_rcpf(e + 1.f), 1.f);
      hv[l] = (f16)h;
    }
    *(f16x8*)(ht + (rbase + (((k0 + j*8) << 1) ^ swz))) = hv;
  }
}

// 32x32 K=1024 GEMM slice: A from swizzled LDS h-tile, B from register frags.
__device__ __forceinline__ void gemm_lds(const char* ht, const f16x8* bfrag,
    int row, int quad, float (*zred)[16][17], int wv, int r16){
  const int swz = (row & 7) << 4;
  const int rbase = row << 11;
  f32x4 a = {0.f,0.f,0.f,0.f};
  #pragma unroll
  for (int g4 = 0; g4 < 4; ++g4){
    f16x8 fr[8];
    #pragma unroll
    for (int kk = 0; kk < 8; ++kk)
      fr[kk] = *(const f16x8*)(ht + (rbase + (((g4<<9) + (kk<<6) + (quad<<4)) ^ swz)));
    #pragma unroll
    for (int kk = 0; kk < 8; ++kk) a = MFMA_F16(fr[kk], bfrag[g4*8 + kk], a);
  }
  #pragma unroll
  for (int reg = 0; reg < 4; ++reg) zred[wv][quad*4 + reg][r16] = a[reg];
}

// ---------------------------------------------------------------------------
__global__ __launch_bounds__(256) void k_transpose_f16(const float* __restrict__ src,
    f16* __restrict__ dst, int K, int N, int dstStride, int dstOff){
  const int n0 = blockIdx.x*32, k0 = blockIdx.y*32, tid = threadIdx.x;
  __shared__ float tl[32][33];
  #pragma unroll
  for (int rep = 0; rep < 4; ++rep){
    int e = rep*256 + tid; int i = e >> 5, j = e & 31;
    int k = k0 + i, n = n0 + j;
    tl[i][j] = (k < K && n < N) ? src[(size_t)k*N + n] : 0.f;
  }
  __syncthreads();
  #pragma unroll
  for (int rep = 0; rep < 4; ++rep){
    int e = rep*256 + tid; int i2 = e & 31, j2 = e >> 5;
    int n = n0 + j2, k = k0 + i2;
    if (k < K && n < N) dst[(size_t)n*dstStride + dstOff + k] = (f16)tl[i2][j2];
  }
}

// ---------------------------------------------------------------------------
__global__ __launch_bounds__(256) void k_prenet(const float* __restrict__ dec,
    const float* __restrict__ w1, const float* __restrict__ w2, f16* __restrict__ cellin){
  const int t = blockIdx.x, tid = threadIdx.x;
  __shared__ float sin_[32][81];
  __shared__ f16   w1T[256][88];
  __shared__ float x1s[32][260];
  __shared__ f16   w2c[256][72];
  __shared__ f16   xo[32][256];
  for (int e = tid; e < 32*80; e += 256){
    int i = e/80, m = e - i*80;
    sin_[i][m] = (t == 0) ? 0.f : dec[(size_t)i*61440 + (size_t)m*768 + (t-1)];
  }
  for (int e = tid; e < 80*256; e += 256){ int m = e >> 8, j = e & 255; w1T[j][m] = (f16)w1[e]; }
  __syncthreads();
  const int j = tid;
  for (int i = 0; i < 32; ++i){
    float a = 0.f;
    #pragma unroll
    for (int m8 = 0; m8 < 10; ++m8){
      f16x8 wvv = *(const f16x8*)&w1T[j][m8*8];
      #pragma unroll
      for (int l = 0; l < 8; ++l) a += (float)wvv[l] * sin_[i][m8*8 + l];
    }
    x1s[i][j] = fmaxf(a, 0.f);
  }
  __syncthreads();
  float acc2[32];
  #pragma unroll
  for (int i = 0; i < 32; ++i) acc2[i] = 0.f;
  for (int c = 0; c < 4; ++c){
    for (int e = tid; e < 64*256; e += 256){
      int kl = e >> 8, jj = e & 255;
      w2c[jj][kl] = (f16)w2[(size_t)(c*64 + kl)*256 + jj];
    }
    __syncthreads();
    f16x8 wv8[8];
    #pragma unroll
    for (int k8 = 0; k8 < 8; ++k8) wv8[k8] = *(const f16x8*)&w2c[j][k8*8];
    for (int i = 0; i < 32; ++i){
      float a = 0.f;
      #pragma unroll
      for (int k8 = 0; k8 < 8; ++k8)
        #pragma unroll
        for (int l = 0; l < 8; ++l) a += (float)wv8[k8][l]*x1s[i][c*64 + k8*8 + l];
      acc2[i] += a;
    }
    __syncthreads();
  }
  for (int i = 0; i < 32; ++i) xo[i][j] = (f16)fmaxf(acc2[i], 0.f);
  __syncthreads();
  for (int e = tid; e < 32*256; e += 256){
    int i = e >> 8, jj = e & 255;
    cellin[((size_t)t*32 + i)*800 + jj] = xo[i][jj];
  }
}

// ---------------------------------------------------------------------------
__global__ __launch_bounds__(256) void k_durfill(const float* __restrict__ dur, f16* __restrict__ cellin){
  const int t = blockIdx.x, tid = threadIdx.x;
  for (int e = tid; e < 32*544; e += 256){
    int b = e / 544, c = e - b*544;
    cellin[((size_t)t*32 + b)*800 + 256 + c] = (f16)dur[(size_t)b*417792 + (size_t)t*544 + c];
  }
}

// ---------------------------------------------------------------------------
__global__ __launch_bounds__(256) void k_ws_report(float* __restrict__ out, int n, float val){
  int i = blockIdx.x*256 + threadIdx.x;
  if (i < n) out[i] = val;
}

// ---------------------------------------------------------------------------
// Pipelined two-layer recurrence, 2 grid rounds per step per layer (was 3):
//  round A: z-stat partials (atomicAdd + counter);
//  round P: publish (c, sigmoid(o)) f16 + c-stat partials in ONE round.
// Consumers reconstruct h = so*tanh(LN(c)*gc+bc) themselves into an
// XOR-swizzled LDS h-tile (one conversion per block, shared by all GEMM
// waves; staging loads batched into a single vmcnt wait, overlapped with
// the stats read). Blocks 0..127 = layer 1, 128..255 = layer 2 (runs ~1
// step behind via double-buffered co-slots + CT_C consumption throttle).
// ---------------------------------------------------------------------------
__global__ __launch_bounds__(512, 1) void k_recurrence(
    const f16* __restrict__ cellin, const f16* __restrict__ wxT1,
    const f16* __restrict__ whT1, const f16* __restrict__ w2T,
    f16* __restrict__ H2all,
    f16* __restrict__ co1c, f16* __restrict__ co1s,
    f16* __restrict__ co2c, f16* __restrict__ co2s,
    float* __restrict__ sacc, unsigned* __restrict__ ctrs,
    const float* __restrict__ b1v,
    const float* __restrict__ g1, const float* __restrict__ bn1,
    const float* __restrict__ gc1v, const float* __restrict__ bc1v,
    const float* __restrict__ b2v,
    const float* __restrict__ g2, const float* __restrict__ bn2,
    const float* __restrict__ gc2v, const float* __restrict__ bc2v)
{
  const int tid = threadIdx.x, blk = blockIdx.x;
  const int lane = tid & 63, wv = tid >> 6;
  const int r16 = lane & 15, quad = lane >> 4;
  const int part = wv >> 2, pair = wv & 3, rt = pair >> 1, ct = pair & 1;
  const int g_b = ct*2 + (r16 >> 3), u_b = r16 & 7;   // B-frag col decode
  const int u_o = tid >> 5, rb = tid & 31;            // owners / conversion map
  const int zrow = tid >> 4, zc0 = tid & 15, zc1 = (tid & 15) + 16;
  const int zrt = zrow >> 4, zi = zrow & 15;
  const int arow = rt*16 + r16;                       // GEMM A-row per lane

  __shared__ __align__(16) char smem[155008];
  float (*zred)[16][17] = (float(*)[16][17])(smem);          //  8704
  float (*zfin)[33]     = (float(*)[33])(smem + 8704);       //  4224
  float* mst  = (float*)(smem + 12928);
  float* vst  = (float*)(smem + 13056);
  float* nm1s = (float*)(smem + 13184);   // -m*rs for c1
  float* rc1s = (float*)(smem + 13312);
  float* nm2s = (float*)(smem + 13440);   // -m*rs for c2
  float* rc2s = (float*)(smem + 13568);
  float (*csA)[32] = (float(*)[32])(smem + 13696);
  float (*csQ)[32] = (float(*)[32])(smem + 14720);
  char* bp = smem + 15744;                // branch-specific area

  f16x8 bfrag[32];

  if (blk < 128){
    // ======================= LAYER 1 =======================
    f16*  swx = (f16*)bp;                 // 51200 B
    char* htA = bp + 51200;               // 65536 B h-tile
    f16*  gA  = (f16*)(bp + 116736);      // gc1*2log2e
    f16*  bA  = (f16*)(bp + 118784);      // bc1*2log2e
    const int cls = blk & 15, ub0 = blk*8;
    const int colg = (g_b << 10) + ub0 + u_b;
    if (part == 0){
      #pragma unroll
      for (int c = 0; c < 32; ++c)
        bfrag[c] = *(const f16x8*)(whT1 + (size_t)colg*1024 + c*32 + quad*8);
    }
    for (int idx = tid; idx < 3200; idx += 512){
      int l = idx & 15, q = (idx >> 4) & 3, v = idx >> 6;
      int c = v % 25, ctx = v / 25;
      int gg = ctx*2 + (l >> 3), uu = l & 7;
      int cg = (gg << 10) + ub0 + uu;
      *(f16x8*)(swx + idx*8) = *(const f16x8*)(wxT1 + (size_t)cg*800 + c*32 + q*8);
    }
    for (int u = tid; u < 1024; u += 512){
      gA[u] = (f16)(gc1v[u] * LOG2E2);
      bA[u] = (f16)(bc1v[u] * LOG2E2);
    }
    float pg[4], pb[4];
    if (tid < 256){
      #pragma unroll
      for (int g = 0; g < 4; ++g){
        int cg = (g << 10) + ub0 + u_o;
        pg[g] = g1[cg]; pb[g] = bn1[cg];
      }
    }
    const float zb0 = b1v[((zc0 >> 3) << 10) + ub0 + (zc0 & 7)];
    const float zb1 = b1v[((zc1 >> 3) << 10) + ub0 + (zc1 & 7)];
    float c1 = 0.f;
    __syncthreads();
    // prologue: x-GEMM for t=0
    if (part == 1){
      f32x4 a = {0.f,0.f,0.f,0.f};
      const f16* ap = cellin + (size_t)(rt*16 + r16)*800 + quad*8;
      for (int c = 0; c < 25; ++c){
        f16x8 av = *(const f16x8*)(ap + c*32);
        f16x8 bx = *(const f16x8*)(swx + (size_t)(((ct*25 + c)*4 + quad)*16 + r16)*8);
        a = MFMA_F16(av, bx, a);
      }
      #pragma unroll
      for (int reg = 0; reg < 4; ++reg) zred[wv][quad*4 + reg][r16] = a[reg];
    }
    for (int t = 0; t < 768; ++t){
      f16x8 cf[8], sf[8];
      // --- phase 1: wait for publish of step t-1 ---
      if (t > 0) bar_poll(ctrs, CT_P1, tid, 8u*t);
      __syncthreads();
      // --- phase 2: issue co-loads; read c1-stat partials ---
      if (t > 0){
        const int k0 = u_o * 64;
        const f16* cp = co1c + (size_t)((t&1)^1)*32768 + (size_t)rb*1024 + k0;
        const f16* sp = co1s + (size_t)((t&1)^1)*32768 + (size_t)rb*1024 + k0;
        ld16_issue(cp, sp, cf, sf);
        if (tid < 32){
          float m, rs;
          ln_stats(sacc + (((size_t)(t-1)*4 + 1)*NCLS)*64 + 2*tid, 1.f/1024.f, m, rs);
          nm1s[tid] = -m*rs; rc1s[tid] = rs;
        }
      }
      __syncthreads();
      // --- phase 3: convert (c,so)->h into LDS tile, then h-GEMM ---
      if (t > 0){
        vm_wait_sb();
        cvt_store8(htA, rb, u_o*64, cf, sf, gA, bA, nm1s[rb], rc1s[rb]);
      }
      __syncthreads();
      if (part == 0){
        if (t > 0) gemm_lds(htA, bfrag, arow, quad, zred, wv, r16);
        else {
          #pragma unroll
          for (int reg = 0; reg < 4; ++reg) zred[wv][quad*4 + reg][r16] = 0.f;
        }
      }
      __syncthreads();
      // --- phase 4: z combine + z-stats round A1 + x-filler ---
      {
        float za  = zred[zrt*2    ][zi][zc0] + zred[4 + zrt*2    ][zi][zc0] + zb0;
        float zbv = zred[zrt*2 + 1][zi][zc0] + zred[4 + zrt*2 + 1][zi][zc0] + zb1;
        zfin[zrow][zc0] = za; zfin[zrow][zc1] = zbv;
        float s = za + zbv, q = za*za + zbv*zbv;
        s += __shfl_down(s, 8); q += __shfl_down(q, 8);
        s += __shfl_down(s, 4); q += __shfl_down(q, 4);
        s += __shfl_down(s, 2); q += __shfl_down(q, 2);
        s += __shfl_down(s, 1); q += __shfl_down(q, 1);
        if ((tid & 15) == 0){
          float* a_ = sacc + (((size_t)t*4 + 0)*NCLS + cls)*64;
          atomicAdd(a_ + 2*zrow, s); atomicAdd(a_ + 2*zrow + 1, q);
        }
      }
      vm_drain(); __syncthreads();
      if (tid == 0) bar_arrive(ctrs + (CT_A1*NCLS + cls)*16);
      if (part == 1 && t < 767){
        f32x4 a = {0.f,0.f,0.f,0.f};
        const f16* ap = cellin + (size_t)(t+1)*25600 + (size_t)(rt*16 + r16)*800 + quad*8;
        for (int c = 0; c < 25; ++c){
          f16x8 av = *(const f16x8*)(ap + c*32);
          f16x8 bx = *(const f16x8*)(swx + (size_t)(((ct*25 + c)*4 + quad)*16 + r16)*8);
          a = MFMA_F16(av, bx, a);
        }
        #pragma unroll
        for (int reg = 0; reg < 4; ++reg) zred[wv][quad*4 + reg][r16] = a[reg];
      }
      bar_poll(ctrs, CT_A1, tid, 8u*(t+1));
      __syncthreads();
      // --- phase 5: z-LN stats + consumption throttle ---
      if (tid < 32){
        float m, rs;
        ln_stats(sacc + (((size_t)t*4 + 0)*NCLS)*64 + 2*tid, 1.f/4096.f, m, rs);
        mst[tid] = m; vst[tid] = rs;
      } else if (t >= 2 && tid < 48){
        const unsigned* p = ctrs + (CT_C*NCLS + (tid - 32))*16;
        while (__hip_atomic_load(p, __ATOMIC_RELAXED, __HIP_MEMORY_SCOPE_AGENT) < 8u*(t-1))
          __builtin_amdgcn_s_sleep(1);
      }
      __syncthreads();
      // --- phase 6: gates -> c1, so; publish (c,so) ---
      if (tid < 256){
        const float m = mst[rb], rs = vst[rb];
        const float ziv = (zfin[rb][u_o]      - m)*rs*pg[0] + pb[0];
        const float zf  = (zfin[rb][8 + u_o]  - m)*rs*pg[1] + pb[1];
        const float zg  = (zfin[rb][16 + u_o] - m)*rs*pg[2] + pb[2];
        const float zo  = (zfin[rb][24 + u_o] - m)*rs*pg[3] + pb[3];
        c1 = sigf(zf)*c1 + sigf(ziv)*tanhf(zg);
        float so = sigf(zo);
        csA[u_o][rb] = c1; csQ[u_o][rb] = c1*c1;
        const size_t o = (size_t)(t&1)*32768 + (size_t)rb*1024 + ub0 + u_o;
        st_wt_f16(co1c + o, (f16)c1);
        st_wt_f16(co1s + o, (f16)so);
      }
      vm_drain(); __syncthreads();
      // --- phase 7: c1-stat partials + arrive publish ---
      if (tid < 32){
        float s = 0.f, q = 0.f;
        #pragma unroll
        for (int u = 0; u < 8; ++u){ s += csA[u][tid]; q += csQ[u][tid]; }
        float* a_ = sacc + (((size_t)t*4 + 1)*NCLS + cls)*64;
        atomicAdd(a_ + 2*tid, s); atomicAdd(a_ + 2*tid + 1, q);
      }
      vm_drain(); __syncthreads();
      if (tid == 0) bar_arrive(ctrs + (CT_P1*NCLS + cls)*16);
    }
  } else {
    // ======================= LAYER 2 =======================
    char* htH = bp;                       // own h2 tile, 65536
    char* htX = bp + 65536;               // h1 tile, 65536
    f16*  g2A = (f16*)(bp + 131072);
    f16*  b2A = (f16*)(bp + 133120);
    f16*  g1A = (f16*)(bp + 135168);
    f16*  b1A = (f16*)(bp + 137216);
    const int blk2 = blk - 128, cls = blk2 & 15, ub0 = blk2*8;
    const int colg = (g_b << 10) + ub0 + u_b;
    {
      const f16* wsrc = w2T + (size_t)colg*2048 + (part == 0 ? 1024 : 0);
      #pragma unroll
      for (int c = 0; c < 32; ++c)
        bfrag[c] = *(const f16x8*)(wsrc + c*32 + quad*8);
    }
    for (int u = tid; u < 1024; u += 512){
      g2A[u] = (f16)(gc2v[u] * LOG2E2);
      b2A[u] = (f16)(bc2v[u] * LOG2E2);
      g1A[u] = (f16)(gc1v[u] * LOG2E2);
      b1A[u] = (f16)(bc1v[u] * LOG2E2);
    }
    float pg[4], pb[4], gC = 0.f, bC = 0.f;
    if (tid < 256){
      #pragma unroll
      for (int g = 0; g < 4; ++g){
        int cg = (g << 10) + ub0 + u_o;
        pg[g] = g2[cg]; pb[g] = bn2[cg];
      }
      gC = gc2v[ub0 + u_o] * LOG2E2; bC = bc2v[ub0 + u_o] * LOG2E2;
    }
    const float zb0 = b2v[((zc0 >> 3) << 10) + ub0 + (zc0 & 7)];
    const float zb1 = b2v[((zc1 >> 3) << 10) + ub0 + (zc1 & 7)];
    float c2 = 0.f, so2 = 0.f;
    __syncthreads();
    const int cvrow = tid & 31;
    const int k0b = ((tid >> 5) & 7) * 128;
    for (int t = 0; t < 768; ++t){
      f16x8 cf[8], sf[8];
      const f16* cpc = co1c; const f16* cps = co1s;
      // --- phase 1: wait h1_t publish + own publish of t-1 ---
      bar_poll(ctrs, CT_P1, tid, 8u*(t+1));
      if (t > 0 && tid >= 16 && tid < 32){
        const unsigned* p = ctrs + (CT_P2*NCLS + (tid - 16))*16;
        while (__hip_atomic_load(p, __ATOMIC_RELAXED, __HIP_MEMORY_SCOPE_AGENT) < 8u*t)
          __builtin_amdgcn_s_sleep(1);
      }
      __syncthreads();
      // --- phase 2: issue first-half co-loads; read stat partials ---
      if (part == 1){
        cpc = co1c + (size_t)(t&1)*32768 + (size_t)cvrow*1024 + k0b;
        cps = co1s + (size_t)(t&1)*32768 + (size_t)cvrow*1024 + k0b;
        ld16_issue(cpc, cps, cf, sf);
      } else if (t > 0){
        cpc = co2c + (size_t)((t&1)^1)*32768 + (size_t)cvrow*1024 + k0b;
        cps = co2s + (size_t)((t&1)^1)*32768 + (size_t)cvrow*1024 + k0b;
        ld16_issue(cpc, cps, cf, sf);
      }
      if (tid < 32){
        float m, rs;
        ln_stats(sacc + (((size_t)t*4 + 1)*NCLS)*64 + 2*tid, 1.f/1024.f, m, rs);
        nm1s[tid] = -m*rs; rc1s[tid] = rs;
      } else if (t > 0 && tid >= 64 && tid < 96){
        float m, rs;
        ln_stats(sacc + (((size_t)(t-1)*4 + 3)*NCLS)*64 + 2*(tid-64), 1.f/1024.f, m, rs);
        nm2s[tid-64] = -m*rs; rc2s[tid-64] = rs;
      }
      __syncthreads();
      // --- phase 3: convert both operand tiles; GEMM ---
      if (part == 1){
        vm_wait_sb();
        cvt_store8(htX, cvrow, k0b,      cf, sf, g1A, b1A, nm1s[cvrow], rc1s[cvrow]);
        ld16_issue(cpc + 64, cps + 64, cf, sf);
        vm_wait_sb();
        cvt_store8(htX, cvrow, k0b + 64, cf, sf, g1A, b1A, nm1s[cvrow], rc1s[cvrow]);
      } else if (t > 0){
        vm_wait_sb();
        cvt_store8(htH, cvrow, k0b,      cf, sf, g2A, b2A, nm2s[cvrow], rc2s[cvrow]);
        ld16_issue(cpc + 64, cps + 64, cf, sf);
        vm_wait_sb();
        cvt_store8(htH, cvrow, k0b + 64, cf, sf, g2A, b2A, nm2s[cvrow], rc2s[cvrow]);
      }
      __syncthreads();
      if (part == 0 && t == 0){
        #pragma unroll
        for (int reg = 0; reg < 4; ++reg) zred[wv][quad*4 + reg][r16] = 0.f;
      } else {
        gemm_lds(part == 0 ? htH : htX, bfrag, arow, quad, zred, wv, r16);
      }
      __syncthreads();
      // --- phase 4: z2 combine + round A2 + lazy H2all write ---
      {
        float za  = zred[zrt*2    ][zi][zc0] + zred[4 + zrt*2    ][zi][zc0] + zb0;
        float zbv = zred[zrt*2 + 1][zi][zc0] + zred[4 + zrt*2 + 1][zi][zc0] + zb1;
        zfin[zrow][zc0] = za; zfin[zrow][zc1] = zbv;
        float s = za + zbv, q = za*za + zbv*zbv;
        s += __shfl_down(s, 8); q += __shfl_down(q, 8);
        s += __shfl_down(s, 4); q += __shfl_down(q, 4);
        s += __shfl_down(s, 2); q += __shfl_down(q, 2);
        s += __shfl_down(s, 1); q += __shfl_down(q, 1);
        if ((tid & 15) == 0){
          float* a_ = sacc + (((size_t)t*4 + 2)*NCLS + cls)*64;
          atomicAdd(a_ + 2*zrow, s); atomicAdd(a_ + 2*zrow + 1, q);
        }
      }
      vm_drain(); __syncthreads();
      if (tid == 0)  bar_arrive(ctrs + (CT_A2*NCLS + cls)*16);
      if (tid == 64) bar_arrive(ctrs + (CT_C*NCLS + cls)*16);   // h1_t consumed
      if (t >= 1 && tid < 256){
        // h2(t-1) from registers, now that its stats are known
        float e = exp2f(fmaf(fmaf(c2, rc2s[rb], nm2s[rb]), gC, bC));
        float h = so2 * fmaf(-2.f, __builtin_amdgcn_rcpf(e + 1.f), 1.f);
        st_wt_f16(H2all + (size_t)t*32768 + rb*1024 + ub0 + u_o, (f16)h);
      }
      bar_poll(ctrs, CT_A2, tid, 8u*(t+1));
      __syncthreads();
      // --- phase 5: z2-LN stats ---
      if (tid < 32){
        float m, rs;
        ln_stats(sacc + (((size_t)t*4 + 2)*NCLS)*64 + 2*tid, 1.f/4096.f, m, rs);
        mst[tid] = m; vst[tid] = rs;
      }
      __syncthreads();
      // --- phase 6: gates -> c2, so2; publish (c,so) ---
      if (tid < 256){
        const float m = mst[rb], rs = vst[rb];
        const float ziv = (zfin[rb][u_o]      - m)*rs*pg[0] + pb[0];
        const float zf  = (zfin[rb][8 + u_o]  - m)*rs*pg[1] + pb[1];
        const float zg  = (zfin[rb][16 + u_o] - m)*rs*pg[2] + pb[2];
        const float zo  = (zfin[rb][24 + u_o] - m)*rs*pg[3] + pb[3];
        c2 = sigf(zf)*c2 + sigf(ziv)*tanhf(zg);
        so2 = sigf(zo);
        csA[u_o][rb] = c2; csQ[u_o][rb] = c2*c2;
        const size_t o = (size_t)(t&1)*32768 + (size_t)rb*1024 + ub0 + u_o;
        st_wt_f16(co2c + o, (f16)c2);
        st_wt_f16(co2s + o, (f16)so2);
      }
      vm_drain(); __syncthreads();
      // --- phase 7: c2-stat partials + arrive publish ---
      if (tid < 32){
        float s = 0.f, q = 0.f;
        #pragma unroll
        for (int u = 0; u < 8; ++u){ s += csA[u][tid]; q += csQ[u][tid]; }
        float* a_ = sacc + (((size_t)t*4 + 3)*NCLS + cls)*64;
        atomicAdd(a_ + 2*tid, s); atomicAdd(a_ + 2*tid + 1, q);
      }
      vm_drain(); __syncthreads();
      if (tid == 0) bar_arrive(ctrs + (CT_P2*NCLS + cls)*16);
    }
    // --- epilogue: H2all for t=767 ---
    bar_poll(ctrs, CT_P2, tid, 8u*768);
    __syncthreads();
    if (tid < 32){
      float m, rs;
      ln_stats(sacc + (((size_t)767*4 + 3)*NCLS)*64 + 2*tid, 1.f/1024.f, m, rs);
      nm2s[tid] = -m*rs; rc2s[tid] = rs;
    }
    __syncthreads();
    if (tid < 256){
      float e = exp2f(fmaf(fmaf(c2, rc2s[rb], nm2s[rb]), gC, bC));
      float h = so2 * fmaf(-2.f, __builtin_amdgcn_rcpf(e + 1.f), 1.f);
      st_wt_f16(H2all + (size_t)768*32768 + rb*1024 + ub0 + u_o, (f16)h);
    }
    vm_drain();
  }
}

// ---------------------------------------------------------------------------
__global__ __launch_bounds__(256) void k_proj(const f16* __restrict__ H2all, const f16* __restrict__ cellin,
    const f16* __restrict__ projT, const float* __restrict__ projb, float* __restrict__ out){
  const int t = blockIdx.x, tid = threadIdx.x;
  const int lane = tid & 63, wv = tid >> 6;
  const int r16 = lane & 15, quad = lane >> 4;
  __shared__ float pred[4][32][84];
  f32x4 acc[2][5] = {};
  const f16* H2 = H2all + (size_t)(t+1)*32768;
  const f16* CI = cellin + (size_t)t*32*800;
  const int kbeg = wv*13;
  const int kend = (wv == 3) ? 49 : (kbeg + 13);
  for (int ks = kbeg; ks < kend; ++ks){
    const int k0 = ks*32 + quad*8;
    f16x8 a0, a1;
    if (ks < 32){
      a0 = *(const f16x8*)(H2 + r16*1024 + k0);
      a1 = *(const f16x8*)(H2 + (16+r16)*1024 + k0);
    } else {
      a0 = *(const f16x8*)(CI + r16*800 + 256 + (k0 - 1024));
      a1 = *(const f16x8*)(CI + (16+r16)*800 + 256 + (k0 - 1024));
    }
    f16x8 bf[5];
    #pragma unroll
    for (int nt = 0; nt < 5; ++nt)
      bf[nt] = *(const f16x8*)(projT + (size_t)(nt*16 + r16)*1568 + k0);
    #pragma unroll
    for (int nt = 0; nt < 5; ++nt){
      acc[0][nt] = MFMA_F16(a0, bf[nt], acc[0][nt]);
      acc[1][nt] = MFMA_F16(a1, bf[nt], acc[1][nt]);
    }
  }
  #pragma unroll
  for (int mt = 0; mt < 2; ++mt)
    #pragma unroll
    for (int nt = 0; nt < 5; ++nt)
      #pragma unroll
      for (int reg = 0; reg < 4; ++reg)
        pred[wv][mt*16 + quad*4 + reg][nt*16 + r16] = acc[mt][nt][reg];
  __syncthreads();
  for (int e = tid; e < 2560; e += 256){
    int m = e >> 5, b = e & 31;
    float v = pred[0][b][m] + pred[1][b][m] + pred[2][b][m] + pred[3][b][m] + projb[m];
    out[(size_t)b*61440 + (size_t)m*768 + t] = v;
  }
}

// ---------------------------------------------------------------------------
extern "C" void kernel_launch(void* const* d_in, const int* in_sizes, int n_in,
                              void* d_out, int out_size, void* d_ws, size_t ws_size,
                              hipStream_t stream)
{
  const float* duration = (const float*)d_in[0];
  const float* decoder  = (const float*)d_in[1];
  const float* pre_w1   = (const float*)d_in[3];
  const float* pre_w2   = (const float*)d_in[4];
  const float* rnn1_wx  = (const float*)d_in[5];
  const float* rnn1_wh  = (const float*)d_in[6];
  const float* rnn1_b   = (const float*)d_in[7];
  const float* rnn1_g   = (const float*)d_in[8];
  const float* rnn1_bn  = (const float*)d_in[9];
  const float* rnn1_gc  = (const float*)d_in[10];
  const float* rnn1_bc  = (const float*)d_in[11];
  const float* rnn2_wx  = (const float*)d_in[12];
  const float* rnn2_wh  = (const float*)d_in[13];
  const float* rnn2_b   = (const float*)d_in[14];
  const float* rnn2_g   = (const float*)d_in[15];
  const float* rnn2_bn  = (const float*)d_in[16];
  const float* rnn2_gc  = (const float*)d_in[17];
  const float* rnn2_bc  = (const float*)d_in[18];
  const float* proj_w   = (const float*)d_in[19];
  const float* proj_b   = (const float*)d_in[20];
  float* out = (float*)d_out;

  char* w = (char*)d_ws;
  f16* cellin = (f16*)w;      w += (size_t)24576*800*2;
  f16* wxT1   = (f16*)w;      w += (size_t)4096*800*2;
  f16* whT1   = (f16*)w;      w += (size_t)4096*1024*2;
  f16* w2T    = (f16*)w;      w += (size_t)4096*2048*2;
  f16* projT  = (f16*)w;      w += 262144;
  f16* H2all  = (f16*)w;      w += (size_t)769*32768*2;
  f16* co1c   = (f16*)w;      w += 131072;   // 2 slots x 32x1024 f16
  f16* co1s   = (f16*)w;      w += 131072;
  f16* co2c   = (f16*)w;      w += 131072;
  f16* co2s   = (f16*)w;      w += 131072;
  float* sacc = (float*)w;    w += (size_t)768*4*16*64*4;
  unsigned* ctrs = (unsigned*)w; w += 8192;
  const size_t need = (size_t)((char*)w - (char*)d_ws);
  if (ws_size < need){
    k_ws_report<<<(out_size + 255)/256, 256, 0, stream>>>(out, out_size, (float)(ws_size >> 20));
    return;
  }

  (void)hipMemsetAsync(sacc, 0, (size_t)768*4*16*64*4, stream);
  (void)hipMemsetAsync(ctrs, 0, 8192, stream);

  k_transpose_f16<<<dim3(4096/32, 25), 256, 0, stream>>>(rnn1_wx, wxT1, 800, 4096, 800, 0);
  k_transpose_f16<<<dim3(4096/32, 32), 256, 0, stream>>>(rnn1_wh, whT1, 1024, 4096, 1024, 0);
  k_transpose_f16<<<dim3(4096/32, 32), 256, 0, stream>>>(rnn2_wx, w2T, 1024, 4096, 2048, 0);
  k_transpose_f16<<<dim3(4096/32, 32), 256, 0, stream>>>(rnn2_wh, w2T, 1024, 4096, 2048, 1024);
  k_transpose_f16<<<dim3(3, 49), 256, 0, stream>>>(proj_w, projT, 1568, 80, 1568, 0);
  k_prenet<<<768, 256, 0, stream>>>(decoder, pre_w1, pre_w2, cellin);
  k_durfill<<<768, 256, 0, stream>>>(duration, cellin);
  k_recurrence<<<256, 512, 0, stream>>>(cellin, wxT1, whT1, w2T, H2all,
      co1c, co1s, co2c, co2s, sacc, ctrs,
      rnn1_b, rnn1_g, rnn1_bn, rnn1_gc, rnn1_bc,
      rnn2_b, rnn2_g, rnn2_bn, rnn2_gc, rnn2_bc);
  k_proj<<<768, 256, 0, stream>>>(H2all, cellin, projT, proj_b, out);
}

// Round 2
// 23057.179 us; speedup vs baseline: 1.2551x; 1.2551x over previous
//
#include <hip/hip_runtime.h>
#include <cstdint>
#include <cstddef>

typedef _Float16 f16;
typedef _Float16 f16x8 __attribute__((ext_vector_type(8)));
typedef float f32x4 __attribute__((ext_vector_type(4)));
typedef unsigned long long u64x2 __attribute__((ext_vector_type(2)));

#define MFMA_F16(a,b,c) __builtin_amdgcn_mfma_f32_16x16x32_f16((a),(b),(c),0,0,0)

#define NCLS 16
// counter sets (h publish rounds only; stat rounds use packed u64 atomics)
#define CT_H1 0
#define CT_H2 1
#define CT_C  2

#define PK_SCALE 67108864.0f            // 2^26
#define PK_INV   1.4901161193847656e-08f

__device__ __forceinline__ float sigf(float x){ return 1.f/(1.f + expf(-x)); }

__device__ __forceinline__ void st_wt_f16(f16* p, f16 v){
  asm volatile("global_store_short %0, %1, off sc0 sc1" :: "v"(p), "v"(v) : "memory");
}
__device__ __forceinline__ void vm_drain(){ asm volatile("s_waitcnt vmcnt(0)" ::: "memory"); }

template<int N> __device__ __forceinline__ void vm_waitN(){
  asm volatile("s_waitcnt vmcnt(%0)" :: "i"(N) : "memory");
  __builtin_amdgcn_sched_barrier(0);
}

__device__ __forceinline__ void bar_arrive(unsigned* c){
  __hip_atomic_fetch_add(c, 1u, __ATOMIC_RELAXED, __HIP_MEMORY_SCOPE_AGENT);
}
__device__ __forceinline__ void bar_poll(const unsigned* ctrs, int set, int tid, unsigned target){
  if (tid < NCLS){
    const unsigned* p = ctrs + (set*NCLS + tid)*16;
    while (__hip_atomic_load(p, __ATOMIC_RELAXED, __HIP_MEMORY_SCOPE_AGENT) < target)
      __builtin_amdgcn_s_sleep(1);
  }
}

// Pack a float stat partial into (fixed<<8)|count1.
__device__ __forceinline__ unsigned long long pk(float v){
  return ((unsigned long long)(long long)(v * PK_SCALE) << 8) + 1ull;
}

// Poll one row's packed (s,q) across 4 buckets (64B contiguous, coherent).
// Returns LN stats once both counts reach 128.
__device__ __forceinline__ void poll_stats(const unsigned long long* p, float invn,
                                           float& m, float& rs){
  u64x2 x0, x1, x2, x3;
  for (;;){
    asm volatile(
      "global_load_dwordx4 %0, %4, off sc0 sc1\n\t"
      "global_load_dwordx4 %1, %4, off offset:16 sc0 sc1\n\t"
      "global_load_dwordx4 %2, %4, off offset:32 sc0 sc1\n\t"
      "global_load_dwordx4 %3, %4, off offset:48 sc0 sc1\n\t"
      "s_waitcnt vmcnt(0)"
      : "=&v"(x0),"=&v"(x1),"=&v"(x2),"=&v"(x3)
      : "v"(p) : "memory");
    unsigned long long sp = x0.x + x1.x + x2.x + x3.x;
    unsigned long long qp = x0.y + x1.y + x2.y + x3.y;
    if (((sp & 255ull) == 128ull) && ((qp & 255ull) == 128ull)){
      float s = (float)((long long)(sp - 128ull) >> 8) * PK_INV;
      float q = (float)((long long)(qp - 128ull) >> 8) * PK_INV;
      m = s * invn; rs = rsqrtf(q*invn - m*m + 1e-5f);
      return;
    }
    __builtin_amdgcn_s_sleep(1);
  }
}

// Coherent batched ISSUE (no wait) of 8 consecutive 64B k-chunks of one row.
__device__ __forceinline__ void ld8_issue(const f16* p, f16x8* f){
  asm volatile(
    "global_load_dwordx4 %0, %8, off sc0 sc1\n\t"
    "global_load_dwordx4 %1, %8, off offset:64 sc0 sc1\n\t"
    "global_load_dwordx4 %2, %8, off offset:128 sc0 sc1\n\t"
    "global_load_dwordx4 %3, %8, off offset:192 sc0 sc1\n\t"
    "global_load_dwordx4 %4, %8, off offset:256 sc0 sc1\n\t"
    "global_load_dwordx4 %5, %8, off offset:320 sc0 sc1\n\t"
    "global_load_dwordx4 %6, %8, off offset:384 sc0 sc1\n\t"
    "global_load_dwordx4 %7, %8, off offset:448 sc0 sc1"
    : "=&v"(f[0]),"=&v"(f[1]),"=&v"(f[2]),"=&v"(f[3]),
      "=&v"(f[4]),"=&v"(f[5]),"=&v"(f[6]),"=&v"(f[7])
    : "v"(p) : "memory");
}

// 32-row x 32-col x K=1024 GEMM slice. A rows from coherent global (2 batches
// of 8 loads in flight, counted vmcnt waits); B frags from LDS tile laid out
// in consumption order [c:32][ct:2][r16:16][quad:4] * 16B.
__device__ __forceinline__ f32x4 gemm32(const f16* hp, const f16* bT, int bbase){
  f32x4 a = {0.f,0.f,0.f,0.f};
  f16x8 fA[8], fB[8];
  ld8_issue(hp,       fA);
  ld8_issue(hp + 256, fB);
  vm_waitN<8>();
  #pragma unroll
  for (int kk = 0; kk < 8; ++kk)
    a = MFMA_F16(fA[kk], *(const f16x8*)(bT + (size_t)(bbase + kk*128)*8), a);
  ld8_issue(hp + 512, fA);
  vm_waitN<8>();
  #pragma unroll
  for (int kk = 0; kk < 8; ++kk)
    a = MFMA_F16(fB[kk], *(const f16x8*)(bT + (size_t)(bbase + (8+kk)*128)*8), a);
  ld8_issue(hp + 768, fB);
  vm_waitN<8>();
  #pragma unroll
  for (int kk = 0; kk < 8; ++kk)
    a = MFMA_F16(fA[kk], *(const f16x8*)(bT + (size_t)(bbase + (16+kk)*128)*8), a);
  vm_waitN<0>();
  #pragma unroll
  for (int kk = 0; kk < 8; ++kk)
    a = MFMA_F16(fB[kk], *(const f16x8*)(bT + (size_t)(bbase + (24+kk)*128)*8), a);
  return a;
}

// ---------------------------------------------------------------------------
__global__ __launch_bounds__(256) void k_transpose_f16(const float* __restrict__ src,
    f16* __restrict__ dst, int K, int N, int dstStride, int dstOff){
  const int n0 = blockIdx.x*32, k0 = blockIdx.y*32, tid = threadIdx.x;
  __shared__ float tl[32][33];
  #pragma unroll
  for (int rep = 0; rep < 4; ++rep){
    int e = rep*256 + tid; int i = e >> 5, j = e & 31;
    int k = k0 + i, n = n0 + j;
    tl[i][j] = (k < K && n < N) ? src[(size_t)k*N + n] : 0.f;
  }
  __syncthreads();
  #pragma unroll
  for (int rep = 0; rep < 4; ++rep){
    int e = rep*256 + tid; int i2 = e & 31, j2 = e >> 5;
    int n = n0 + j2, k = k0 + i2;
    if (k < K && n < N) dst[(size_t)n*dstStride + dstOff + k] = (f16)tl[i2][j2];
  }
}

// ---------------------------------------------------------------------------
__global__ __launch_bounds__(256) void k_prenet(const float* __restrict__ dec,
    const float* __restrict__ w1, const float* __restrict__ w2, f16* __restrict__ cellin){
  const int t = blockIdx.x, tid = threadIdx.x;
  __shared__ float sin_[32][81];
  __shared__ f16   w1T[256][88];
  __shared__ float x1s[32][260];
  __shared__ f16   w2c[256][72];
  __shared__ f16   xo[32][256];
  for (int e = tid; e < 32*80; e += 256){
    int i = e/80, m = e - i*80;
    sin_[i][m] = (t == 0) ? 0.f : dec[(size_t)i*61440 + (size_t)m*768 + (t-1)];
  }
  for (int e = tid; e < 80*256; e += 256){ int m = e >> 8, j = e & 255; w1T[j][m] = (f16)w1[e]; }
  __syncthreads();
  const int j = tid;
  for (int i = 0; i < 32; ++i){
    float a = 0.f;
    #pragma unroll
    for (int m8 = 0; m8 < 10; ++m8){
      f16x8 wvv = *(const f16x8*)&w1T[j][m8*8];
      #pragma unroll
      for (int l = 0; l < 8; ++l) a += (float)wvv[l] * sin_[i][m8*8 + l];
    }
    x1s[i][j] = fmaxf(a, 0.f);
  }
  __syncthreads();
  float acc2[32];
  #pragma unroll
  for (int i = 0; i < 32; ++i) acc2[i] = 0.f;
  for (int c = 0; c < 4; ++c){
    for (int e = tid; e < 64*256; e += 256){
      int kl = e >> 8, jj = e & 255;
      w2c[jj][kl] = (f16)w2[(size_t)(c*64 + kl)*256 + jj];
    }
    __syncthreads();
    f16x8 wv8[8];
    #pragma unroll
    for (int k8 = 0; k8 < 8; ++k8) wv8[k8] = *(const f16x8*)&w2c[j][k8*8];
    for (int i = 0; i < 32; ++i){
      float a = 0.f;
      #pragma unroll
      for (int k8 = 0; k8 < 8; ++k8)
        #pragma unroll
        for (int l = 0; l < 8; ++l) a += (float)wv8[k8][l]*x1s[i][c*64 + k8*8 + l];
      acc2[i] += a;
    }
    __syncthreads();
  }
  for (int i = 0; i < 32; ++i) xo[i][j] = (f16)fmaxf(acc2[i], 0.f);
  __syncthreads();
  for (int e = tid; e < 32*256; e += 256){
    int i = e >> 8, jj = e & 255;
    cellin[((size_t)t*32 + i)*800 + jj] = xo[i][jj];
  }
}

// ---------------------------------------------------------------------------
__global__ __launch_bounds__(256) void k_durfill(const float* __restrict__ dur, f16* __restrict__ cellin){
  const int t = blockIdx.x, tid = threadIdx.x;
  for (int e = tid; e < 32*544; e += 256){
    int b = e / 544, c = e - b*544;
    cellin[((size_t)t*32 + b)*800 + 256 + c] = (f16)dur[(size_t)b*417792 + (size_t)t*544 + c];
  }
}

// ---------------------------------------------------------------------------
__global__ __launch_bounds__(256) void k_ws_report(float* __restrict__ out, int n, float val){
  int i = blockIdx.x*256 + threadIdx.x;
  if (i < n) out[i] = val;
}

// ---------------------------------------------------------------------------
// Pipelined two-layer recurrence. Blocks 0..127 = layer 1, 128..255 = layer 2
// (layer 2 runs ~1 step behind; double-buffered h1/h2 + CT_C throttle).
// Stat rounds use fused count|value u64 atomics (4 buckets x 32 blocks each):
// pollers spin directly on the packed data — no drain/counter/re-read chain.
// GEMM A-operand: 2x8 coherent loads in flight with counted vmcnt waits.
// GEMM B-operand: LDS tile in consumption order (loaded once at init).
// ---------------------------------------------------------------------------
__global__ __launch_bounds__(512, 1) void k_recurrence(
    const f16* __restrict__ cellin, const f16* __restrict__ wxT1,
    const f16* __restrict__ whT1, const f16* __restrict__ w2T,
    f16* __restrict__ H2all, f16* __restrict__ h1buf, f16* __restrict__ h2buf,
    unsigned long long* __restrict__ sacc64, unsigned* __restrict__ ctrs,
    const float* __restrict__ b1v,
    const float* __restrict__ g1, const float* __restrict__ bn1,
    const float* __restrict__ gc1v, const float* __restrict__ bc1v,
    const float* __restrict__ b2v,
    const float* __restrict__ g2, const float* __restrict__ bn2,
    const float* __restrict__ gc2v, const float* __restrict__ bc2v)
{
  const int tid = threadIdx.x, blk = blockIdx.x;
  const int lane = tid & 63, wv = tid >> 6;
  const int r16 = lane & 15, quad = lane >> 4;
  const int part = wv >> 2, pair = wv & 3, rt = pair >> 1, ct = pair & 1;
  const int u_o = tid >> 5, rb = tid & 31;            // gate owners (tid<256)
  const int zrow = tid >> 4, zc0 = tid & 15, zc1 = (tid & 15) + 16;
  const int zrt = zrow >> 4, zi = zrow & 15;
  const int arow = rt*16 + r16;                       // GEMM A-row per lane
  const int bbase = ct*64 + r16*4 + quad;             // B-frag index base

  __shared__ __align__(16) char smem[146304];
  float (*zred)[16][17] = (float(*)[16][17])(smem);          //  8704
  float (*zfin)[33]     = (float(*)[33])(smem + 8704);       //  4224
  float* mst  = (float*)(smem + 12928);                      //   128
  float* vst  = (float*)(smem + 13056);                      //   128
  float (*csA)[32] = (float(*)[32])(smem + 13184);           //  1024
  float (*csQ)[32] = (float(*)[32])(smem + 14208);           //  1024
  char* bp = smem + 15232;                                   // per-branch

  if (blk < 128){
    // ======================= LAYER 1 =======================
    f16* swx = (f16*)bp;               // 51200 B  x-weight slice
    f16* bT  = (f16*)(bp + 51200);     // 65536 B  wh1 B-tile (consumption order)
    const int cls = blk & 15, ub0 = blk*8, bkt = blk >> 5;
    // B-tile: [c:32][ctb:2][r:16][q:4] 16B frags of wh1 columns
    for (int e = tid; e < 4096; e += 512){
      int q = e & 3, r = (e >> 2) & 15, ctb = (e >> 6) & 1, c = e >> 7;
      int gb = ctb*2 + (r >> 3), ub = r & 7;
      int cg = (gb << 10) + ub0 + ub;
      *(f16x8*)(bT + (size_t)e*8) = *(const f16x8*)(whT1 + (size_t)cg*1024 + c*32 + q*8);
    }
    for (int idx = tid; idx < 3200; idx += 512){
      int l = idx & 15, q = (idx >> 4) & 3, v = idx >> 6;
      int c = v % 25, ctx = v / 25;
      int gg = ctx*2 + (l >> 3), uu = l & 7;
      int cg = (gg << 10) + ub0 + uu;
      *(f16x8*)(swx + idx*8) = *(const f16x8*)(wxT1 + (size_t)cg*800 + c*32 + q*8);
    }
    float pg[4], pb[4], gC = 0.f, bC = 0.f;
    if (tid < 256){
      #pragma unroll
      for (int g = 0; g < 4; ++g){
        int cg = (g << 10) + ub0 + u_o;
        pg[g] = g1[cg]; pb[g] = bn1[cg];
      }
      gC = gc1v[ub0 + u_o]; bC = bc1v[ub0 + u_o];
    }
    const float zb0 = b1v[((zc0 >> 3) << 10) + ub0 + (zc0 & 7)];
    const float zb1 = b1v[((zc1 >> 3) << 10) + ub0 + (zc1 & 7)];
    float c1 = 0.f, o1 = 0.f;
    __syncthreads();
    // prologue: x-GEMM for t=0
    if (part == 1){
      f32x4 a = {0.f,0.f,0.f,0.f};
      const f16* ap = cellin + (size_t)arow*800 + quad*8;
      for (int c = 0; c < 25; ++c){
        f16x8 av = *(const f16x8*)(ap + c*32);
        f16x8 bx = *(const f16x8*)(swx + (size_t)(((ct*25 + c)*4 + quad)*16 + r16)*8);
        a = MFMA_F16(av, bx, a);
      }
      #pragma unroll
      for (int reg = 0; reg < 4; ++reg) zred[wv][quad*4 + reg][r16] = a[reg];
    }
    for (int t = 0; t < 768; ++t){
      // --- phase A: wait h1_{t-1}, h-GEMM ---
      if (t > 0) bar_poll(ctrs, CT_H1, tid, 8u*t);
      __syncthreads();
      if (part == 0){
        if (t > 0){
          const f16* hp = h1buf + (size_t)((t+1)&1)*32768 + (size_t)arow*1024 + quad*8;
          f32x4 a = gemm32(hp, bT, bbase);
          #pragma unroll
          for (int reg = 0; reg < 4; ++reg) zred[wv][quad*4 + reg][r16] = a[reg];
        } else {
          #pragma unroll
          for (int reg = 0; reg < 4; ++reg) zred[wv][quad*4 + reg][r16] = 0.f;
        }
      }
      __syncthreads();
      // --- z combine + packed z-stat atomics ---
      {
        float za  = zred[zrt*2    ][zi][zc0] + zred[4 + zrt*2    ][zi][zc0] + zb0;
        float zbv = zred[zrt*2 + 1][zi][zc0] + zred[4 + zrt*2 + 1][zi][zc0] + zb1;
        zfin[zrow][zc0] = za; zfin[zrow][zc1] = zbv;
        float s = za + zbv, q = za*za + zbv*zbv;
        s += __shfl_down(s, 8); q += __shfl_down(q, 8);
        s += __shfl_down(s, 4); q += __shfl_down(q, 4);
        s += __shfl_down(s, 2); q += __shfl_down(q, 2);
        s += __shfl_down(s, 1); q += __shfl_down(q, 1);
        if ((tid & 15) == 0){
          unsigned long long* a_ = sacc64 + ((((size_t)t*4 + 0)*32 + zrow)*4 + bkt)*2;
          atomicAdd(a_,     pk(s));
          atomicAdd(a_ + 1, pk(q));
        }
      }
      __syncthreads();
      // --- x-filler for t+1 (part1) || z-stat poll (tid<32) || CT_C throttle ---
      if (part == 1 && t < 767){
        f32x4 a = {0.f,0.f,0.f,0.f};
        const f16* ap = cellin + (size_t)(t+1)*25600 + (size_t)arow*800 + quad*8;
        for (int c = 0; c < 25; ++c){
          f16x8 av = *(const f16x8*)(ap + c*32);
          f16x8 bx = *(const f16x8*)(swx + (size_t)(((ct*25 + c)*4 + quad)*16 + r16)*8);
          a = MFMA_F16(av, bx, a);
        }
        #pragma unroll
        for (int reg = 0; reg < 4; ++reg) zred[wv][quad*4 + reg][r16] = a[reg];
      }
      if (tid < 32){
        float m, rs;
        poll_stats(sacc64 + (((size_t)t*4 + 0)*32 + tid)*8, 1.f/4096.f, m, rs);
        mst[tid] = m; vst[tid] = rs;
      } else if (t >= 2 && tid < 48){
        const unsigned* p = ctrs + (CT_C*NCLS + (tid - 32))*16;
        while (__hip_atomic_load(p, __ATOMIC_RELAXED, __HIP_MEMORY_SCOPE_AGENT) < 8u*(t-1))
          __builtin_amdgcn_s_sleep(1);
      }
      __syncthreads();
      // --- gates -> c1 ---
      if (tid < 256){
        const float m = mst[rb], rs = vst[rb];
        const float ziv = (zfin[rb][u_o]      - m)*rs*pg[0] + pb[0];
        const float zf  = (zfin[rb][8 + u_o]  - m)*rs*pg[1] + pb[1];
        const float zg  = (zfin[rb][16 + u_o] - m)*rs*pg[2] + pb[2];
        const float zo  = (zfin[rb][24 + u_o] - m)*rs*pg[3] + pb[3];
        c1 = sigf(zf)*c1 + sigf(ziv)*tanhf(zg);
        o1 = sigf(zo);
        csA[u_o][rb] = c1; csQ[u_o][rb] = c1*c1;
      }
      __syncthreads();
      // --- packed c-stat atomics + poll (tid<32) ---
      if (tid < 32){
        float s = 0.f, q = 0.f;
        #pragma unroll
        for (int u = 0; u < 8; ++u){ s += csA[u][tid]; q += csQ[u][tid]; }
        unsigned long long* a_ = sacc64 + ((((size_t)t*4 + 1)*32 + tid)*4 + bkt)*2;
        atomicAdd(a_,     pk(s));
        atomicAdd(a_ + 1, pk(q));
        float m, rs;
        poll_stats(sacc64 + (((size_t)t*4 + 1)*32 + tid)*8, 1.f/1024.f, m, rs);
        mst[tid] = m; vst[tid] = rs;
      }
      __syncthreads();
      // --- h1 = sig(o)*tanh(LN(c1)), publish ---
      if (tid < 256){
        float rs = vst[rb];
        float arg = fmaf(fmaf(c1, rs, -mst[rb]*rs), gC, bC);
        float e = exp2f(arg * 2.885390081777927f);
        float h = o1 * fmaf(-2.f, __builtin_amdgcn_rcpf(e + 1.f), 1.f);
        st_wt_f16(h1buf + (size_t)(t&1)*32768 + rb*1024 + ub0 + u_o, (f16)h);
      }
      vm_drain(); __syncthreads();
      if (tid == 0) bar_arrive(ctrs + (CT_H1*NCLS + cls)*16);
    }
  } else {
    // ======================= LAYER 2 =======================
    f16* bT2 = (f16*)bp;               // 2 x 65536 B: [part][c][ctb][r][q]
    const int blk2 = blk - 128, cls = blk2 & 15, ub0 = blk2*8, bkt = blk2 >> 5;
    const int bbase2 = part*4096 + bbase;
    for (int e = tid; e < 8192; e += 512){
      int q = e & 3, r = (e >> 2) & 15, ctb = (e >> 6) & 1, c = (e >> 7) & 31, pp = e >> 12;
      int gb = ctb*2 + (r >> 3), ub = r & 7;
      int cg = (gb << 10) + ub0 + ub;
      *(f16x8*)(bT2 + (size_t)e*8) =
        *(const f16x8*)(w2T + (size_t)cg*2048 + (pp ? 0 : 1024) + c*32 + q*8);
    }
    float pg[4], pb[4], gC = 0.f, bC = 0.f;
    if (tid < 256){
      #pragma unroll
      for (int g = 0; g < 4; ++g){
        int cg = (g << 10) + ub0 + u_o;
        pg[g] = g2[cg]; pb[g] = bn2[cg];
      }
      gC = gc2v[ub0 + u_o]; bC = bc2v[ub0 + u_o];
    }
    const float zb0 = b2v[((zc0 >> 3) << 10) + ub0 + (zc0 & 7)];
    const float zb1 = b2v[((zc1 >> 3) << 10) + ub0 + (zc1 & 7)];
    float c2 = 0.f, o2 = 0.f;
    __syncthreads();
    for (int t = 0; t < 768; ++t){
      // --- phase A: wait h1_t publish + own h2_{t-1} publish ---
      bar_poll(ctrs, CT_H1, tid, 8u*(t+1));
      if (t > 0 && tid >= 16 && tid < 32){
        const unsigned* p = ctrs + (CT_H2*NCLS + (tid - 16))*16;
        while (__hip_atomic_load(p, __ATOMIC_RELAXED, __HIP_MEMORY_SCOPE_AGENT) < 8u*t)
          __builtin_amdgcn_s_sleep(1);
      }
      __syncthreads();
      // --- GEMM: part0 = h2_{t-1}@wh2, part1 = h1_t@wx2 ---
      if (part == 0 && t == 0){
        #pragma unroll
        for (int reg = 0; reg < 4; ++reg) zred[wv][quad*4 + reg][r16] = 0.f;
      } else {
        const f16* hp = (part == 0)
          ? h2buf + (size_t)((t+1)&1)*32768 + (size_t)arow*1024 + quad*8
          : h1buf + (size_t)(t&1)*32768     + (size_t)arow*1024 + quad*8;
        f32x4 a = gemm32(hp, bT2, bbase2);
        #pragma unroll
        for (int reg = 0; reg < 4; ++reg) zred[wv][quad*4 + reg][r16] = a[reg];
      }
      __syncthreads();
      if (tid == 64) bar_arrive(ctrs + (CT_C*NCLS + cls)*16);   // h1_t consumed
      // --- z2 combine + packed z2-stat atomics ---
      {
        float za  = zred[zrt*2    ][zi][zc0] + zred[4 + zrt*2    ][zi][zc0] + zb0;
        float zbv = zred[zrt*2 + 1][zi][zc0] + zred[4 + zrt*2 + 1][zi][zc0] + zb1;
        zfin[zrow][zc0] = za; zfin[zrow][zc1] = zbv;
        float s = za + zbv, q = za*za + zbv*zbv;
        s += __shfl_down(s, 8); q += __shfl_down(q, 8);
        s += __shfl_down(s, 4); q += __shfl_down(q, 4);
        s += __shfl_down(s, 2); q += __shfl_down(q, 2);
        s += __shfl_down(s, 1); q += __shfl_down(q, 1);
        if ((tid & 15) == 0){
          unsigned long long* a_ = sacc64 + ((((size_t)t*4 + 2)*32 + zrow)*4 + bkt)*2;
          atomicAdd(a_,     pk(s));
          atomicAdd(a_ + 1, pk(q));
        }
      }
      __syncthreads();
      if (tid < 32){
        float m, rs;
        poll_stats(sacc64 + (((size_t)t*4 + 2)*32 + tid)*8, 1.f/4096.f, m, rs);
        mst[tid] = m; vst[tid] = rs;
      }
      __syncthreads();
      // --- gates -> c2 ---
      if (tid < 256){
        const float m = mst[rb], rs = vst[rb];
        const float ziv = (zfin[rb][u_o]      - m)*rs*pg[0] + pb[0];
        const float zf  = (zfin[rb][8 + u_o]  - m)*rs*pg[1] + pb[1];
        const float zg  = (zfin[rb][16 + u_o] - m)*rs*pg[2] + pb[2];
        const float zo  = (zfin[rb][24 + u_o] - m)*rs*pg[3] + pb[3];
        c2 = sigf(zf)*c2 + sigf(ziv)*tanhf(zg);
        o2 = sigf(zo);
        csA[u_o][rb] = c2; csQ[u_o][rb] = c2*c2;
      }
      __syncthreads();
      // --- packed c2-stat atomics + poll ---
      if (tid < 32){
        float s = 0.f, q = 0.f;
        #pragma unroll
        for (int u = 0; u < 8; ++u){ s += csA[u][tid]; q += csQ[u][tid]; }
        unsigned long long* a_ = sacc64 + ((((size_t)t*4 + 3)*32 + tid)*4 + bkt)*2;
        atomicAdd(a_,     pk(s));
        atomicAdd(a_ + 1, pk(q));
        float m, rs;
        poll_stats(sacc64 + (((size_t)t*4 + 3)*32 + tid)*8, 1.f/1024.f, m, rs);
        mst[tid] = m; vst[tid] = rs;
      }
      __syncthreads();
      // --- h2 publish (+ H2all for projection) ---
      if (tid < 256){
        float rs = vst[rb];
        float arg = fmaf(fmaf(c2, rs, -mst[rb]*rs), gC, bC);
        float e = exp2f(arg * 2.885390081777927f);
        float h = o2 * fmaf(-2.f, __builtin_amdgcn_rcpf(e + 1.f), 1.f);
        st_wt_f16(h2buf + (size_t)(t&1)*32768 + rb*1024 + ub0 + u_o, (f16)h);
        st_wt_f16(H2all + (size_t)(t+1)*32768 + rb*1024 + ub0 + u_o, (f16)h);
      }
      vm_drain(); __syncthreads();
      if (tid == 0) bar_arrive(ctrs + (CT_H2*NCLS + cls)*16);
    }
  }
}

// ---------------------------------------------------------------------------
__global__ __launch_bounds__(256) void k_proj(const f16* __restrict__ H2all, const f16* __restrict__ cellin,
    const f16* __restrict__ projT, const float* __restrict__ projb, float* __restrict__ out){
  const int t = blockIdx.x, tid = threadIdx.x;
  const int lane = tid & 63, wv = tid >> 6;
  const int r16 = lane & 15, quad = lane >> 4;
  __shared__ float pred[4][32][84];
  f32x4 acc[2][5] = {};
  const f16* H2 = H2all + (size_t)(t+1)*32768;
  const f16* CI = cellin + (size_t)t*32*800;
  const int kbeg = wv*13;
  const int kend = (wv == 3) ? 49 : (kbeg + 13);
  for (int ks = kbeg; ks < kend; ++ks){
    const int k0 = ks*32 + quad*8;
    f16x8 a0, a1;
    if (ks < 32){
      a0 = *(const f16x8*)(H2 + r16*1024 + k0);
      a1 = *(const f16x8*)(H2 + (16+r16)*1024 + k0);
    } else {
      a0 = *(const f16x8*)(CI + r16*800 + 256 + (k0 - 1024));
      a1 = *(const f16x8*)(CI + (16+r16)*800 + 256 + (k0 - 1024));
    }
    f16x8 bf[5];
    #pragma unroll
    for (int nt = 0; nt < 5; ++nt)
      bf[nt] = *(const f16x8*)(projT + (size_t)(nt*16 + r16)*1568 + k0);
    #pragma unroll
    for (int nt = 0; nt < 5; ++nt){
      acc[0][nt] = MFMA_F16(a0, bf[nt], acc[0][nt]);
      acc[1][nt] = MFMA_F16(a1, bf[nt], acc[1][nt]);
    }
  }
  #pragma unroll
  for (int mt = 0; mt < 2; ++mt)
    #pragma unroll
    for (int nt = 0; nt < 5; ++nt)
      #pragma unroll
      for (int reg = 0; reg < 4; ++reg)
        pred[wv][mt*16 + quad*4 + reg][nt*16 + r16] = acc[mt][nt][reg];
  __syncthreads();
  for (int e = tid; e < 2560; e += 256){
    int m = e >> 5, b = e & 31;
    float v = pred[0][b][m] + pred[1][b][m] + pred[2][b][m] + pred[3][b][m] + projb[m];
    out[(size_t)b*61440 + (size_t)m*768 + t] = v;
  }
}

// ---------------------------------------------------------------------------
extern "C" void kernel_launch(void* const* d_in, const int* in_sizes, int n_in,
                              void* d_out, int out_size, void* d_ws, size_t ws_size,
                              hipStream_t stream)
{
  const float* duration = (const float*)d_in[0];
  const float* decoder  = (const float*)d_in[1];
  const float* pre_w1   = (const float*)d_in[3];
  const float* pre_w2   = (const float*)d_in[4];
  const float* rnn1_wx  = (const float*)d_in[5];
  const float* rnn1_wh  = (const float*)d_in[6];
  const float* rnn1_b   = (const float*)d_in[7];
  const float* rnn1_g   = (const float*)d_in[8];
  const float* rnn1_bn  = (const float*)d_in[9];
  const float* rnn1_gc  = (const float*)d_in[10];
  const float* rnn1_bc  = (const float*)d_in[11];
  const float* rnn2_wx  = (const float*)d_in[12];
  const float* rnn2_wh  = (const float*)d_in[13];
  const float* rnn2_b   = (const float*)d_in[14];
  const float* rnn2_g   = (const float*)d_in[15];
  const float* rnn2_bn  = (const float*)d_in[16];
  const float* rnn2_gc  = (const float*)d_in[17];
  const float* rnn2_bc  = (const float*)d_in[18];
  const float* proj_w   = (const float*)d_in[19];
  const float* proj_b   = (const float*)d_in[20];
  float* out = (float*)d_out;

  char* w = (char*)d_ws;
  f16* cellin = (f16*)w;      w += (size_t)24576*800*2;
  f16* wxT1   = (f16*)w;      w += (size_t)4096*800*2;
  f16* whT1   = (f16*)w;      w += (size_t)4096*1024*2;
  f16* w2T    = (f16*)w;      w += (size_t)4096*2048*2;
  f16* projT  = (f16*)w;      w += 262144;
  f16* H2all  = (f16*)w;      w += (size_t)769*32768*2;
  f16* h1buf  = (f16*)w;      w += 131072;   // 2 slots x 32x1024 f16
  f16* h2buf  = (f16*)w;      w += 131072;
  unsigned long long* sacc64 = (unsigned long long*)w; w += (size_t)768*4*32*4*2*8;
  unsigned* ctrs = (unsigned*)w; w += 8192;
  const size_t need = (size_t)((char*)w - (char*)d_ws);
  if (ws_size < need){
    k_ws_report<<<(out_size + 255)/256, 256, 0, stream>>>(out, out_size, (float)(ws_size >> 20));
    return;
  }

  (void)hipMemsetAsync(sacc64, 0, (size_t)768*4*32*4*2*8, stream);
  (void)hipMemsetAsync(ctrs, 0, 8192, stream);
  (void)hipMemsetAsync(h1buf, 0, 131072, stream);
  (void)hipMemsetAsync(h2buf, 0, 131072, stream);

  k_transpose_f16<<<dim3(4096/32, 25), 256, 0, stream>>>(rnn1_wx, wxT1, 800, 4096, 800, 0);
  k_transpose_f16<<<dim3(4096/32, 32), 256, 0, stream>>>(rnn1_wh, whT1, 1024, 4096, 1024, 0);
  k_transpose_f16<<<dim3(4096/32, 32), 256, 0, stream>>>(rnn2_wx, w2T, 1024, 4096, 2048, 0);
  k_transpose_f16<<<dim3(4096/32, 32), 256, 0, stream>>>(rnn2_wh, w2T, 1024, 4096, 2048, 1024);
  k_transpose_f16<<<dim3(3, 49), 256, 0, stream>>>(proj_w, projT, 1568, 80, 1568, 0);
  k_prenet<<<768, 256, 0, stream>>>(decoder, pre_w1, pre_w2, cellin);
  k_durfill<<<768, 256, 0, stream>>>(duration, cellin);
  k_recurrence<<<256, 512, 0, stream>>>(cellin, wxT1, whT1, w2T, H2all, h1buf, h2buf,
      sacc64, ctrs,
      rnn1_b, rnn1_g, rnn1_bn, rnn1_gc, rnn1_bc,
      rnn2_b, rnn2_g, rnn2_bn, rnn2_gc, rnn2_bc);
  k_proj<<<768, 256, 0, stream>>>(H2all, cellin, projT, proj_b, out);
}

// Round 3
// 15430.821 us; speedup vs baseline: 1.8754x; 1.4942x over previous
//
#include <hip/hip_runtime.h>
#include <cstdint>
#include <cstddef>

typedef _Float16 f16;
typedef _Float16 f16x8 __attribute__((ext_vector_type(8)));
typedef float f32x4 __attribute__((ext_vector_type(4)));
typedef float f32x2 __attribute__((ext_vector_type(2)));

#define MFMA_F16(a,b,c) __builtin_amdgcn_mfma_f32_16x16x32_f16((a),(b),(c),0,0,0)

#define NCLS 16
// counter sets
#define CT_A1 0
#define CT_B1 1
#define CT_H1 2
#define CT_A2 3
#define CT_B2 4
#define CT_H2 5
#define CT_C  6

__device__ __forceinline__ float sigf(float x){ return 1.f/(1.f + expf(-x)); }

__device__ __forceinline__ void st_wt_f16(f16* p, f16 v){
  asm volatile("global_store_short %0, %1, off sc0 sc1" :: "v"(p), "v"(v) : "memory");
}
__device__ __forceinline__ void vm_drain(){ asm volatile("s_waitcnt vmcnt(0)" ::: "memory"); }

template<int N> __device__ __forceinline__ void vm_waitN(){
  asm volatile("s_waitcnt vmcnt(%0)" :: "i"(N) : "memory");
  __builtin_amdgcn_sched_barrier(0);
}

__device__ __forceinline__ void bar_arrive(unsigned* c){
  __hip_atomic_fetch_add(c, 1u, __ATOMIC_RELAXED, __HIP_MEMORY_SCOPE_AGENT);
}
__device__ __forceinline__ void bar_poll(const unsigned* ctrs, int set, int tid, unsigned target){
  if (tid < NCLS){
    const unsigned* p = ctrs + (set*NCLS + tid)*16;
    while (__hip_atomic_load(p, __ATOMIC_RELAXED, __HIP_MEMORY_SCOPE_AGENT) < target)
      __builtin_amdgcn_s_sleep(1);
  }
}

// Coherent load of 16 class-partial (s,q) pairs + LN stats.
__device__ __forceinline__ void ln_stats(const float* p, float invn, float& m, float& rs){
  f32x2 v0,v1,v2,v3,v4,v5,v6,v7,v8,v9,v10,v11,v12,v13,v14,v15;
  asm volatile(
    "global_load_dwordx2 %0, %16, off sc0 sc1\n\t"
    "global_load_dwordx2 %1, %16, off offset:256 sc0 sc1\n\t"
    "global_load_dwordx2 %2, %16, off offset:512 sc0 sc1\n\t"
    "global_load_dwordx2 %3, %16, off offset:768 sc0 sc1\n\t"
    "global_load_dwordx2 %4, %16, off offset:1024 sc0 sc1\n\t"
    "global_load_dwordx2 %5, %16, off offset:1280 sc0 sc1\n\t"
    "global_load_dwordx2 %6, %16, off offset:1536 sc0 sc1\n\t"
    "global_load_dwordx2 %7, %16, off offset:1792 sc0 sc1\n\t"
    "global_load_dwordx2 %8, %16, off offset:2048 sc0 sc1\n\t"
    "global_load_dwordx2 %9, %16, off offset:2304 sc0 sc1\n\t"
    "global_load_dwordx2 %10, %16, off offset:2560 sc0 sc1\n\t"
    "global_load_dwordx2 %11, %16, off offset:2816 sc0 sc1\n\t"
    "global_load_dwordx2 %12, %16, off offset:3072 sc0 sc1\n\t"
    "global_load_dwordx2 %13, %16, off offset:3328 sc0 sc1\n\t"
    "global_load_dwordx2 %14, %16, off offset:3584 sc0 sc1\n\t"
    "global_load_dwordx2 %15, %16, off offset:3840 sc0 sc1\n\t"
    "s_waitcnt vmcnt(0)"
    : "=&v"(v0),"=&v"(v1),"=&v"(v2),"=&v"(v3),"=&v"(v4),"=&v"(v5),"=&v"(v6),"=&v"(v7),
      "=&v"(v8),"=&v"(v9),"=&v"(v10),"=&v"(v11),"=&v"(v12),"=&v"(v13),"=&v"(v14),"=&v"(v15)
    : "v"(p) : "memory");
  float s = v0.x+v1.x+v2.x+v3.x+v4.x+v5.x+v6.x+v7.x+v8.x+v9.x+v10.x+v11.x+v12.x+v13.x+v14.x+v15.x;
  float q = v0.y+v1.y+v2.y+v3.y+v4.y+v5.y+v6.y+v7.y+v8.y+v9.y+v10.y+v11.y+v12.y+v13.y+v14.y+v15.y;
  m = s*invn; rs = rsqrtf(q*invn - m*m + 1e-5f);
}

// Coherent batched ISSUE (no wait) of 8 consecutive 64B k-chunks of one row.
__device__ __forceinline__ void ld8_issue(const f16* p, f16x8* f){
  asm volatile(
    "global_load_dwordx4 %0, %8, off sc0 sc1\n\t"
    "global_load_dwordx4 %1, %8, off offset:64 sc0 sc1\n\t"
    "global_load_dwordx4 %2, %8, off offset:128 sc0 sc1\n\t"
    "global_load_dwordx4 %3, %8, off offset:192 sc0 sc1\n\t"
    "global_load_dwordx4 %4, %8, off offset:256 sc0 sc1\n\t"
    "global_load_dwordx4 %5, %8, off offset:320 sc0 sc1\n\t"
    "global_load_dwordx4 %6, %8, off offset:384 sc0 sc1\n\t"
    "global_load_dwordx4 %7, %8, off offset:448 sc0 sc1"
    : "=&v"(f[0]),"=&v"(f[1]),"=&v"(f[2]),"=&v"(f[3]),
      "=&v"(f[4]),"=&v"(f[5]),"=&v"(f[6]),"=&v"(f[7])
    : "v"(p) : "memory");
}

// 32-row x 32-col x K=1024 GEMM slice. A rows from coherent global, 2 batches
// of 8 loads in flight (counted vmcnt waits); B frags in registers.
__device__ __forceinline__ f32x4 gemm32r(const f16* hp, const f16x8* bfrag){
  f32x4 a = {0.f,0.f,0.f,0.f};
  f16x8 fA[8], fB[8];
  ld8_issue(hp,       fA);
  ld8_issue(hp + 256, fB);
  vm_waitN<8>();
  #pragma unroll
  for (int kk = 0; kk < 8; ++kk) a = MFMA_F16(fA[kk], bfrag[kk], a);
  ld8_issue(hp + 512, fA);
  vm_waitN<8>();
  #pragma unroll
  for (int kk = 0; kk < 8; ++kk) a = MFMA_F16(fB[kk], bfrag[8 + kk], a);
  ld8_issue(hp + 768, fB);
  vm_waitN<8>();
  #pragma unroll
  for (int kk = 0; kk < 8; ++kk) a = MFMA_F16(fA[kk], bfrag[16 + kk], a);
  vm_waitN<0>();
  #pragma unroll
  for (int kk = 0; kk < 8; ++kk) a = MFMA_F16(fB[kk], bfrag[24 + kk], a);
  return a;
}

// ---------------------------------------------------------------------------
__global__ __launch_bounds__(256) void k_transpose_f16(const float* __restrict__ src,
    f16* __restrict__ dst, int K, int N, int dstStride, int dstOff){
  const int n0 = blockIdx.x*32, k0 = blockIdx.y*32, tid = threadIdx.x;
  __shared__ float tl[32][33];
  #pragma unroll
  for (int rep = 0; rep < 4; ++rep){
    int e = rep*256 + tid; int i = e >> 5, j = e & 31;
    int k = k0 + i, n = n0 + j;
    tl[i][j] = (k < K && n < N) ? src[(size_t)k*N + n] : 0.f;
  }
  __syncthreads();
  #pragma unroll
  for (int rep = 0; rep < 4; ++rep){
    int e = rep*256 + tid; int i2 = e & 31, j2 = e >> 5;
    int n = n0 + j2, k = k0 + i2;
    if (k < K && n < N) dst[(size_t)n*dstStride + dstOff + k] = (f16)tl[i2][j2];
  }
}

// ---------------------------------------------------------------------------
__global__ __launch_bounds__(256) void k_prenet(const float* __restrict__ dec,
    const float* __restrict__ w1, const float* __restrict__ w2, f16* __restrict__ cellin){
  const int t = blockIdx.x, tid = threadIdx.x;
  __shared__ float sin_[32][81];
  __shared__ f16   w1T[256][88];
  __shared__ float x1s[32][260];
  __shared__ f16   w2c[256][72];
  __shared__ f16   xo[32][256];
  for (int e = tid; e < 32*80; e += 256){
    int i = e/80, m = e - i*80;
    sin_[i][m] = (t == 0) ? 0.f : dec[(size_t)i*61440 + (size_t)m*768 + (t-1)];
  }
  for (int e = tid; e < 80*256; e += 256){ int m = e >> 8, j = e & 255; w1T[j][m] = (f16)w1[e]; }
  __syncthreads();
  const int j = tid;
  for (int i = 0; i < 32; ++i){
    float a = 0.f;
    #pragma unroll
    for (int m8 = 0; m8 < 10; ++m8){
      f16x8 wvv = *(const f16x8*)&w1T[j][m8*8];
      #pragma unroll
      for (int l = 0; l < 8; ++l) a += (float)wvv[l] * sin_[i][m8*8 + l];
    }
    x1s[i][j] = fmaxf(a, 0.f);
  }
  __syncthreads();
  float acc2[32];
  #pragma unroll
  for (int i = 0; i < 32; ++i) acc2[i] = 0.f;
  for (int c = 0; c < 4; ++c){
    for (int e = tid; e < 64*256; e += 256){
      int kl = e >> 8, jj = e & 255;
      w2c[jj][kl] = (f16)w2[(size_t)(c*64 + kl)*256 + jj];
    }
    __syncthreads();
    f16x8 wv8[8];
    #pragma unroll
    for (int k8 = 0; k8 < 8; ++k8) wv8[k8] = *(const f16x8*)&w2c[j][k8*8];
    for (int i = 0; i < 32; ++i){
      float a = 0.f;
      #pragma unroll
      for (int k8 = 0; k8 < 8; ++k8)
        #pragma unroll
        for (int l = 0; l < 8; ++l) a += (float)wv8[k8][l]*x1s[i][c*64 + k8*8 + l];
      acc2[i] += a;
    }
    __syncthreads();
  }
  for (int i = 0; i < 32; ++i) xo[i][j] = (f16)fmaxf(acc2[i], 0.f);
  __syncthreads();
  for (int e = tid; e < 32*256; e += 256){
    int i = e >> 8, jj = e & 255;
    cellin[((size_t)t*32 + i)*800 + jj] = xo[i][jj];
  }
}

// ---------------------------------------------------------------------------
__global__ __launch_bounds__(256) void k_durfill(const float* __restrict__ dur, f16* __restrict__ cellin){
  const int t = blockIdx.x, tid = threadIdx.x;
  for (int e = tid; e < 32*544; e += 256){
    int b = e / 544, c = e - b*544;
    cellin[((size_t)t*32 + b)*800 + 256 + c] = (f16)dur[(size_t)b*417792 + (size_t)t*544 + c];
  }
}

// ---------------------------------------------------------------------------
__global__ __launch_bounds__(256) void k_ws_report(float* __restrict__ out, int n, float val){
  int i = blockIdx.x*256 + threadIdx.x;
  if (i < n) out[i] = val;
}

// ---------------------------------------------------------------------------
// Pipelined two-layer recurrence (round-0 structure). Blocks 0..127 = layer 1
// (8 h1-units each), blocks 128..255 = layer 2; layer 2 runs ~1 step behind
// via double-buffered h1 + consumption throttle. 3 device-scope rounds per
// layer-step (z-stats, c-stats, h-publish) with f32 atomics + counter lines.
// Single change vs round 0: h-GEMM A-loads are pipelined (2x8 in flight,
// counted vmcnt) instead of 4 serial vmcnt(0) batches.
// ---------------------------------------------------------------------------
__global__ __launch_bounds__(512, 1) void k_recurrence(
    const f16* __restrict__ cellin, const f16* __restrict__ wxT1,
    const f16* __restrict__ whT1, const f16* __restrict__ w2T,
    f16* __restrict__ H2all, f16* __restrict__ h1buf, f16* __restrict__ h2buf,
    float* __restrict__ sacc, unsigned* __restrict__ ctrs,
    const float* __restrict__ b1v,
    const float* __restrict__ g1, const float* __restrict__ bn1,
    const float* __restrict__ gc1v, const float* __restrict__ bc1v,
    const float* __restrict__ b2v,
    const float* __restrict__ g2, const float* __restrict__ bn2,
    const float* __restrict__ gc2v, const float* __restrict__ bc2v)
{
  const int tid = threadIdx.x, blk = blockIdx.x;
  const int lane = tid & 63, wv = tid >> 6;
  const int r16 = lane & 15, quad = lane >> 4;
  const int part = wv >> 2, pair = wv & 3, rt = pair >> 1, ct = pair & 1;
  const int g_b = ct*2 + (r16 >> 3), u_b = r16 & 7;   // B-frag col decode
  const int u_o = tid >> 5, rb = tid & 31;            // owners (tid<256)
  const int zrow = tid >> 4, zc0 = tid & 15, zc1 = (tid & 15) + 16;
  const int zrt = zrow >> 4, zi = zrow & 15;
  const int arow = rt*16 + r16;

  __shared__ f16   swx[3200*8];
  __shared__ float zred[8][16][17];
  __shared__ float zfin[32][33];
  __shared__ float mst[32], vst[32];
  __shared__ float csA[8][32], csQ[8][32];

  f16x8 bfrag[32];

  if (blk < 128){
    // ======================= LAYER 1 =======================
    const int cls = blk & 15, ub0 = blk*8;
    const int colg = (g_b << 10) + ub0 + u_b;
    if (part == 0){
      #pragma unroll
      for (int c = 0; c < 32; ++c)
        bfrag[c] = *(const f16x8*)(whT1 + (size_t)colg*1024 + c*32 + quad*8);
    }
    for (int idx = tid; idx < 3200; idx += 512){
      int l = idx & 15, q = (idx >> 4) & 3, v = idx >> 6;
      int c = v % 25, ctx = v / 25;
      int gg = ctx*2 + (l >> 3), uu = l & 7;
      int cg = (gg << 10) + ub0 + uu;
      *(f16x8*)(swx + idx*8) = *(const f16x8*)(wxT1 + (size_t)cg*800 + c*32 + q*8);
    }
    float pg[4], pb[4], gC = 0.f, bC = 0.f;
    if (tid < 256){
      #pragma unroll
      for (int g = 0; g < 4; ++g){
        int cg = (g << 10) + ub0 + u_o;
        pg[g] = g1[cg]; pb[g] = bn1[cg];
      }
      gC = gc1v[ub0 + u_o]; bC = bc1v[ub0 + u_o];
    }
    const float zb0 = b1v[((zc0 >> 3) << 10) + ub0 + (zc0 & 7)];
    const float zb1 = b1v[((zc1 >> 3) << 10) + ub0 + (zc1 & 7)];
    float c1 = 0.f, o1 = 0.f;
    __syncthreads();
    // prologue: x-GEMM for t=0
    if (part == 1){
      f32x4 a = {0.f,0.f,0.f,0.f};
      const f16* ap = cellin + (size_t)arow*800 + quad*8;
      for (int c = 0; c < 25; ++c){
        f16x8 av = *(const f16x8*)(ap + c*32);
        f16x8 bx = *(const f16x8*)(swx + (size_t)(((ct*25 + c)*4 + quad)*16 + r16)*8);
        a = MFMA_F16(av, bx, a);
      }
      #pragma unroll
      for (int reg = 0; reg < 4; ++reg) zred[wv][quad*4 + reg][r16] = a[reg];
    }
    for (int t = 0; t < 768; ++t){
      // --- A1: h1_{t-1} @ wh1 (waves 0-3); x-part already in zred[4..7] ---
      if (t > 0) bar_poll(ctrs, CT_H1, tid, 8u*t);
      __syncthreads();
      if (part == 0){
        if (t > 0){
          const f16* hp = h1buf + (size_t)((t+1)&1)*32768 + (size_t)arow*1024 + quad*8;
          f32x4 a = gemm32r(hp, bfrag);
          #pragma unroll
          for (int reg = 0; reg < 4; ++reg) zred[wv][quad*4 + reg][r16] = a[reg];
        } else {
          #pragma unroll
          for (int reg = 0; reg < 4; ++reg) zred[wv][quad*4 + reg][r16] = 0.f;
        }
      }
      __syncthreads();
      {
        float za  = zred[zrt*2    ][zi][zc0] + zred[4 + zrt*2    ][zi][zc0] + zb0;
        float zbv = zred[zrt*2 + 1][zi][zc0] + zred[4 + zrt*2 + 1][zi][zc0] + zb1;
        zfin[zrow][zc0] = za; zfin[zrow][zc1] = zbv;
        float s = za + zbv, q = za*za + zbv*zbv;
        s += __shfl_down(s, 8); q += __shfl_down(q, 8);
        s += __shfl_down(s, 4); q += __shfl_down(q, 4);
        s += __shfl_down(s, 2); q += __shfl_down(q, 2);
        s += __shfl_down(s, 1); q += __shfl_down(q, 1);
        if ((tid & 15) == 0){
          float* a_ = sacc + (((size_t)t*4 + 0)*NCLS + cls)*64;
          atomicAdd(a_ + 2*zrow, s); atomicAdd(a_ + 2*zrow + 1, q);
        }
      }
      vm_drain(); __syncthreads();
      if (tid == 0) bar_arrive(ctrs + (CT_A1*NCLS + cls)*16);
      // filler: x-GEMM for t+1 (hidden in hop wait)
      if (part == 1 && t < 767){
        f32x4 a = {0.f,0.f,0.f,0.f};
        const f16* ap = cellin + (size_t)(t+1)*25600 + (size_t)arow*800 + quad*8;
        for (int c = 0; c < 25; ++c){
          f16x8 av = *(const f16x8*)(ap + c*32);
          f16x8 bx = *(const f16x8*)(swx + (size_t)(((ct*25 + c)*4 + quad)*16 + r16)*8);
          a = MFMA_F16(av, bx, a);
        }
        #pragma unroll
        for (int reg = 0; reg < 4; ++reg) zred[wv][quad*4 + reg][r16] = a[reg];
      }
      bar_poll(ctrs, CT_A1, tid, 8u*(t+1));
      __syncthreads();
      // --- B1: LN1 -> gates -> c1 ---
      if (tid < 32){
        float m, rs;
        ln_stats(sacc + (((size_t)t*4 + 0)*NCLS)*64 + 2*tid, 1.f/4096.f, m, rs);
        mst[tid] = m; vst[tid] = rs;
      }
      __syncthreads();
      if (tid < 256){
        const float m = mst[rb], rs = vst[rb];
        const float ziv = (zfin[rb][u_o]      - m)*rs*pg[0] + pb[0];
        const float zf  = (zfin[rb][8 + u_o]  - m)*rs*pg[1] + pb[1];
        const float zg  = (zfin[rb][16 + u_o] - m)*rs*pg[2] + pb[2];
        const float zo  = (zfin[rb][24 + u_o] - m)*rs*pg[3] + pb[3];
        c1 = sigf(zf)*c1 + sigf(ziv)*tanhf(zg);
        o1 = sigf(zo);
        csA[u_o][rb] = c1; csQ[u_o][rb] = c1*c1;
      }
      __syncthreads();
      if (tid < 32){
        float s = 0.f, q = 0.f;
        #pragma unroll
        for (int u = 0; u < 8; ++u){ s += csA[u][tid]; q += csQ[u][tid]; }
        float* a_ = sacc + (((size_t)t*4 + 1)*NCLS + cls)*64;
        atomicAdd(a_ + 2*tid, s); atomicAdd(a_ + 2*tid + 1, q);
      }
      vm_drain(); __syncthreads();
      if (tid == 0) bar_arrive(ctrs + (CT_B1*NCLS + cls)*16);
      bar_poll(ctrs, CT_B1, tid, 8u*(t+1));
      __syncthreads();
      // --- B1': h1 = sig(o)*tanh(LN(c1)), publish ---
      if (tid < 32){
        float m, rs;
        ln_stats(sacc + (((size_t)t*4 + 1)*NCLS)*64 + 2*tid, 1.f/1024.f, m, rs);
        mst[tid] = m; vst[tid] = rs;
      } else if (t >= 2 && tid < 48){
        const unsigned* p = ctrs + (CT_C*NCLS + (tid - 32))*16;
        while (__hip_atomic_load(p, __ATOMIC_RELAXED, __HIP_MEMORY_SCOPE_AGENT) < 8u*(t-1))
          __builtin_amdgcn_s_sleep(1);
      }
      __syncthreads();
      if (tid < 256){
        float rs = vst[rb];
        float arg = fmaf(fmaf(c1, rs, -mst[rb]*rs), gC, bC);
        float e = exp2f(arg * 2.885390081777927f);
        float h = o1 * fmaf(-2.f, __builtin_amdgcn_rcpf(e + 1.f), 1.f);
        st_wt_f16(h1buf + (size_t)(t&1)*32768 + rb*1024 + ub0 + u_o, (f16)h);
      }
      vm_drain(); __syncthreads();
      if (tid == 0) bar_arrive(ctrs + (CT_H1*NCLS + cls)*16);
    }
  } else {
    // ======================= LAYER 2 =======================
    const int blk2 = blk - 128, cls = blk2 & 15, ub0 = blk2*8;
    const int colg = (g_b << 10) + ub0 + u_b;
    {
      const f16* wsrc = w2T + (size_t)colg*2048 + (part == 0 ? 1024 : 0);
      #pragma unroll
      for (int c = 0; c < 32; ++c)
        bfrag[c] = *(const f16x8*)(wsrc + c*32 + quad*8);
    }
    float pg[4], pb[4], gC = 0.f, bC = 0.f;
    if (tid < 256){
      #pragma unroll
      for (int g = 0; g < 4; ++g){
        int cg = (g << 10) + ub0 + u_o;
        pg[g] = g2[cg]; pb[g] = bn2[cg];
      }
      gC = gc2v[ub0 + u_o]; bC = bc2v[ub0 + u_o];
    }
    const float zb0 = b2v[((zc0 >> 3) << 10) + ub0 + (zc0 & 7)];
    const float zb1 = b2v[((zc1 >> 3) << 10) + ub0 + (zc1 & 7)];
    float c2 = 0.f, o2 = 0.f;
    __syncthreads();
    for (int t = 0; t < 768; ++t){
      // --- A2: z2 = h1_t @ w2x (waves 4-7) + h2_{t-1} @ w2h (waves 0-3) ---
      bar_poll(ctrs, CT_H1, tid, 8u*(t+1));
      if (t > 0 && tid >= 16 && tid < 32){
        const unsigned* p = ctrs + (CT_H2*NCLS + (tid - 16))*16;
        while (__hip_atomic_load(p, __ATOMIC_RELAXED, __HIP_MEMORY_SCOPE_AGENT) < 8u*t)
          __builtin_amdgcn_s_sleep(1);
      }
      __syncthreads();
      if (part == 0 && t == 0){
        #pragma unroll
        for (int reg = 0; reg < 4; ++reg) zred[wv][quad*4 + reg][r16] = 0.f;
      } else {
        const f16* hp = (part == 0)
          ? h2buf + (size_t)((t+1)&1)*32768 + (size_t)arow*1024 + quad*8
          : h1buf + (size_t)(t&1)*32768     + (size_t)arow*1024 + quad*8;
        f32x4 a = gemm32r(hp, bfrag);
        #pragma unroll
        for (int reg = 0; reg < 4; ++reg) zred[wv][quad*4 + reg][r16] = a[reg];
      }
      __syncthreads();
      {
        float za  = zred[zrt*2    ][zi][zc0] + zred[4 + zrt*2    ][zi][zc0] + zb0;
        float zbv = zred[zrt*2 + 1][zi][zc0] + zred[4 + zrt*2 + 1][zi][zc0] + zb1;
        zfin[zrow][zc0] = za; zfin[zrow][zc1] = zbv;
        float s = za + zbv, q = za*za + zbv*zbv;
        s += __shfl_down(s, 8); q += __shfl_down(q, 8);
        s += __shfl_down(s, 4); q += __shfl_down(q, 4);
        s += __shfl_down(s, 2); q += __shfl_down(q, 2);
        s += __shfl_down(s, 1); q += __shfl_down(q, 1);
        if ((tid & 15) == 0){
          float* a_ = sacc + (((size_t)t*4 + 2)*NCLS + cls)*64;
          atomicAdd(a_ + 2*zrow, s); atomicAdd(a_ + 2*zrow + 1, q);
        }
      }
      vm_drain(); __syncthreads();
      if (tid == 0)  bar_arrive(ctrs + (CT_A2*NCLS + cls)*16);
      if (tid == 64) bar_arrive(ctrs + (CT_C*NCLS + cls)*16);   // h1_t consumed
      bar_poll(ctrs, CT_A2, tid, 8u*(t+1));
      __syncthreads();
      // --- B2: LN2 -> gates -> c2 ---
      if (tid < 32){
        float m, rs;
        ln_stats(sacc + (((size_t)t*4 + 2)*NCLS)*64 + 2*tid, 1.f/4096.f, m, rs);
        mst[tid] = m; vst[tid] = rs;
      }
      __syncthreads();
      if (tid < 256){
        const float m = mst[rb], rs = vst[rb];
        const float ziv = (zfin[rb][u_o]      - m)*rs*pg[0] + pb[0];
        const float zf  = (zfin[rb][8 + u_o]  - m)*rs*pg[1] + pb[1];
        const float zg  = (zfin[rb][16 + u_o] - m)*rs*pg[2] + pb[2];
        const float zo  = (zfin[rb][24 + u_o] - m)*rs*pg[3] + pb[3];
        c2 = sigf(zf)*c2 + sigf(ziv)*tanhf(zg);
        o2 = sigf(zo);
        csA[u_o][rb] = c2; csQ[u_o][rb] = c2*c2;
      }
      __syncthreads();
      if (tid < 32){
        float s = 0.f, q = 0.f;
        #pragma unroll
        for (int u = 0; u < 8; ++u){ s += csA[u][tid]; q += csQ[u][tid]; }
        float* a_ = sacc + (((size_t)t*4 + 3)*NCLS + cls)*64;
        atomicAdd(a_ + 2*tid, s); atomicAdd(a_ + 2*tid + 1, q);
      }
      vm_drain(); __syncthreads();
      if (tid == 0) bar_arrive(ctrs + (CT_B2*NCLS + cls)*16);
      bar_poll(ctrs, CT_B2, tid, 8u*(t+1));
      __syncthreads();
      // --- B2': h2 publish (+ H2all for projection) ---
      if (tid < 32){
        float m, rs;
        ln_stats(sacc + (((size_t)t*4 + 3)*NCLS)*64 + 2*tid, 1.f/1024.f, m, rs);
        mst[tid] = m; vst[tid] = rs;
      }
      __syncthreads();
      if (tid < 256){
        float rs = vst[rb];
        float arg = fmaf(fmaf(c2, rs, -mst[rb]*rs), gC, bC);
        float e = exp2f(arg * 2.885390081777927f);
        float h = o2 * fmaf(-2.f, __builtin_amdgcn_rcpf(e + 1.f), 1.f);
        st_wt_f16(h2buf + (size_t)(t&1)*32768 + rb*1024 + ub0 + u_o, (f16)h);
        st_wt_f16(H2all + (size_t)(t+1)*32768 + rb*1024 + ub0 + u_o, (f16)h);
      }
      vm_drain(); __syncthreads();
      if (tid == 0) bar_arrive(ctrs + (CT_H2*NCLS + cls)*16);
    }
  }
}

// ---------------------------------------------------------------------------
__global__ __launch_bounds__(256) void k_proj(const f16* __restrict__ H2all, const f16* __restrict__ cellin,
    const f16* __restrict__ projT, const float* __restrict__ projb, float* __restrict__ out){
  const int t = blockIdx.x, tid = threadIdx.x;
  const int lane = tid & 63, wv = tid >> 6;
  const int r16 = lane & 15, quad = lane >> 4;
  __shared__ float pred[4][32][84];
  f32x4 acc[2][5] = {};
  const f16* H2 = H2all + (size_t)(t+1)*32768;
  const f16* CI = cellin + (size_t)t*32*800;
  const int kbeg = wv*13;
  const int kend = (wv == 3) ? 49 : (kbeg + 13);
  for (int ks = kbeg; ks < kend; ++ks){
    const int k0 = ks*32 + quad*8;
    f16x8 a0, a1;
    if (ks < 32){
      a0 = *(const f16x8*)(H2 + r16*1024 + k0);
      a1 = *(const f16x8*)(H2 + (16+r16)*1024 + k0);
    } else {
      a0 = *(const f16x8*)(CI + r16*800 + 256 + (k0 - 1024));
      a1 = *(const f16x8*)(CI + (16+r16)*800 + 256 + (k0 - 1024));
    }
    f16x8 bf[5];
    #pragma unroll
    for (int nt = 0; nt < 5; ++nt)
      bf[nt] = *(const f16x8*)(projT + (size_t)(nt*16 + r16)*1568 + k0);
    #pragma unroll
    for (int nt = 0; nt < 5; ++nt){
      acc[0][nt] = MFMA_F16(a0, bf[nt], acc[0][nt]);
      acc[1][nt] = MFMA_F16(a1, bf[nt], acc[1][nt]);
    }
  }
  #pragma unroll
  for (int mt = 0; mt < 2; ++mt)
    #pragma unroll
    for (int nt = 0; nt < 5; ++nt)
      #pragma unroll
      for (int reg = 0; reg < 4; ++reg)
        pred[wv][mt*16 + quad*4 + reg][nt*16 + r16] = acc[mt][nt][reg];
  __syncthreads();
  for (int e = tid; e < 2560; e += 256){
    int m = e >> 5, b = e & 31;
    float v = pred[0][b][m] + pred[1][b][m] + pred[2][b][m] + pred[3][b][m] + projb[m];
    out[(size_t)b*61440 + (size_t)m*768 + t] = v;
  }
}

// ---------------------------------------------------------------------------
extern "C" void kernel_launch(void* const* d_in, const int* in_sizes, int n_in,
                              void* d_out, int out_size, void* d_ws, size_t ws_size,
                              hipStream_t stream)
{
  const float* duration = (const float*)d_in[0];
  const float* decoder  = (const float*)d_in[1];
  const float* pre_w1   = (const float*)d_in[3];
  const float* pre_w2   = (const float*)d_in[4];
  const float* rnn1_wx  = (const float*)d_in[5];
  const float* rnn1_wh  = (const float*)d_in[6];
  const float* rnn1_b   = (const float*)d_in[7];
  const float* rnn1_g   = (const float*)d_in[8];
  const float* rnn1_bn  = (const float*)d_in[9];
  const float* rnn1_gc  = (const float*)d_in[10];
  const float* rnn1_bc  = (const float*)d_in[11];
  const float* rnn2_wx  = (const float*)d_in[12];
  const float* rnn2_wh  = (const float*)d_in[13];
  const float* rnn2_b   = (const float*)d_in[14];
  const float* rnn2_g   = (const float*)d_in[15];
  const float* rnn2_bn  = (const float*)d_in[16];
  const float* rnn2_gc  = (const float*)d_in[17];
  const float* rnn2_bc  = (const float*)d_in[18];
  const float* proj_w   = (const float*)d_in[19];
  const float* proj_b   = (const float*)d_in[20];
  float* out = (float*)d_out;

  char* w = (char*)d_ws;
  f16* cellin = (f16*)w;      w += (size_t)24576*800*2;
  f16* wxT1   = (f16*)w;      w += (size_t)4096*800*2;
  f16* whT1   = (f16*)w;      w += (size_t)4096*1024*2;
  f16* w2T    = (f16*)w;      w += (size_t)4096*2048*2;
  f16* projT  = (f16*)w;      w += 262144;
  f16* H2all  = (f16*)w;      w += (size_t)769*32768*2;
  f16* h1buf  = (f16*)w;      w += 131072;   // 2 slots x 32x1024 f16
  f16* h2buf  = (f16*)w;      w += 131072;
  float* sacc = (float*)w;    w += (size_t)768*4*16*64*4;
  unsigned* ctrs = (unsigned*)w; w += 8192;
  const size_t need = (size_t)((char*)w - (char*)d_ws);
  if (ws_size < need){
    k_ws_report<<<(out_size + 255)/256, 256, 0, stream>>>(out, out_size, (float)(ws_size >> 20));
    return;
  }

  (void)hipMemsetAsync(sacc, 0, (size_t)768*4*16*64*4, stream);
  (void)hipMemsetAsync(ctrs, 0, 8192, stream);
  (void)hipMemsetAsync(h1buf, 0, 131072, stream);
  (void)hipMemsetAsync(h2buf, 0, 131072, stream);

  k_transpose_f16<<<dim3(4096/32, 25), 256, 0, stream>>>(rnn1_wx, wxT1, 800, 4096, 800, 0);
  k_transpose_f16<<<dim3(4096/32, 32), 256, 0, stream>>>(rnn1_wh, whT1, 1024, 4096, 1024, 0);
  k_transpose_f16<<<dim3(4096/32, 32), 256, 0, stream>>>(rnn2_wx, w2T, 1024, 4096, 2048, 0);
  k_transpose_f16<<<dim3(4096/32, 32), 256, 0, stream>>>(rnn2_wh, w2T, 1024, 4096, 2048, 1024);
  k_transpose_f16<<<dim3(3, 49), 256, 0, stream>>>(proj_w, projT, 1568, 80, 1568, 0);
  k_prenet<<<768, 256, 0, stream>>>(decoder, pre_w1, pre_w2, cellin);
  k_durfill<<<768, 256, 0, stream>>>(duration, cellin);
  k_recurrence<<<256, 512, 0, stream>>>(cellin, wxT1, whT1, w2T, H2all, h1buf, h2buf, sacc, ctrs,
      rnn1_b, rnn1_g, rnn1_bn, rnn1_gc, rnn1_bc,
      rnn2_b, rnn2_g, rnn2_bn, rnn2_gc, rnn2_bc);
  k_proj<<<768, 256, 0, stream>>>(H2all, cellin, projT, proj_b, out);
}

// Round 4
// 14245.856 us; speedup vs baseline: 2.0314x; 1.0832x over previous
//
#include <hip/hip_runtime.h>
#include <cstdint>
#include <cstddef>

typedef _Float16 f16;
typedef _Float16 f16x8 __attribute__((ext_vector_type(8)));
typedef float f32x4 __attribute__((ext_vector_type(4)));
typedef unsigned long long u64;
typedef unsigned long long u64x2 __attribute__((ext_vector_type(2)));

#define MFMA_F16(a,b,c) __builtin_amdgcn_mfma_f32_16x16x32_f16((a),(b),(c),0,0,0)

#define NCLS 16
// counter sets
#define CT_A1 0
#define CT_B1 1
#define CT_H1 2
#define CT_A2 3
#define CT_B2 4
#define CT_H2 5
#define CT_C  6

// fixed-point packing for (s,q) stat partials in one u64:
// hi dword = s @ 2^18 (range +-8192, res 3.8e-6); lo dword = q @ 2^12
// (range 2^20 ~= 1.05e6, res 2.4e-4). q-sums carry into s only if
// sum(q_fixed) >= 2^32 per u64 (4 contributing blocks, margin > 100x).
#define S_FIX 262144.f
#define S_INV 3.814697265625e-06f
#define Q_FIX 4096.f
#define Q_INV 2.44140625e-04f

__device__ __forceinline__ float sigf(float x){ return 1.f/(1.f + expf(-x)); }

__device__ __forceinline__ u64 pk_sq(float s, float q){
  long long si = (long long)rintf(s * S_FIX);
  unsigned  qi = (unsigned)rintf(q * Q_FIX);
  return ((u64)si << 32) | (u64)qi;
}

__device__ __forceinline__ void st_wt_f16(f16* p, f16 v){
  asm volatile("global_store_short %0, %1, off sc0 sc1" :: "v"(p), "v"(v) : "memory");
}
__device__ __forceinline__ void vm_drain(){ asm volatile("s_waitcnt vmcnt(0)" ::: "memory"); }

template<int N> __device__ __forceinline__ void vm_waitN(){
  asm volatile("s_waitcnt vmcnt(%0)" :: "i"(N) : "memory");
  __builtin_amdgcn_sched_barrier(0);
}

__device__ __forceinline__ void bar_arrive(unsigned* c){
  __hip_atomic_fetch_add(c, 1u, __ATOMIC_RELAXED, __HIP_MEMORY_SCOPE_AGENT);
}
__device__ __forceinline__ void bar_poll(const unsigned* ctrs, int set, int tid, unsigned target){
  if (tid < NCLS){
    const unsigned* p = ctrs + (set*NCLS + tid)*16;
    while (__hip_atomic_load(p, __ATOMIC_RELAXED, __HIP_MEMORY_SCOPE_AGENT) < target)
      __builtin_amdgcn_s_sleep(1);
  }
}

// Coherent read of one row's 32 packed partials (256B contiguous) + LN stats.
__device__ __forceinline__ void ln_read32(const u64* p, float invn, float& m, float& rs){
  u64x2 v0,v1,v2,v3,v4,v5,v6,v7,v8,v9,v10,v11,v12,v13,v14,v15;
  asm volatile(
    "global_load_dwordx4 %0, %16, off sc0 sc1\n\t"
    "global_load_dwordx4 %1, %16, off offset:16 sc0 sc1\n\t"
    "global_load_dwordx4 %2, %16, off offset:32 sc0 sc1\n\t"
    "global_load_dwordx4 %3, %16, off offset:48 sc0 sc1\n\t"
    "global_load_dwordx4 %4, %16, off offset:64 sc0 sc1\n\t"
    "global_load_dwordx4 %5, %16, off offset:80 sc0 sc1\n\t"
    "global_load_dwordx4 %6, %16, off offset:96 sc0 sc1\n\t"
    "global_load_dwordx4 %7, %16, off offset:112 sc0 sc1\n\t"
    "global_load_dwordx4 %8, %16, off offset:128 sc0 sc1\n\t"
    "global_load_dwordx4 %9, %16, off offset:144 sc0 sc1\n\t"
    "global_load_dwordx4 %10, %16, off offset:160 sc0 sc1\n\t"
    "global_load_dwordx4 %11, %16, off offset:176 sc0 sc1\n\t"
    "global_load_dwordx4 %12, %16, off offset:192 sc0 sc1\n\t"
    "global_load_dwordx4 %13, %16, off offset:208 sc0 sc1\n\t"
    "global_load_dwordx4 %14, %16, off offset:224 sc0 sc1\n\t"
    "global_load_dwordx4 %15, %16, off offset:240 sc0 sc1\n\t"
    "s_waitcnt vmcnt(0)"
    : "=&v"(v0),"=&v"(v1),"=&v"(v2),"=&v"(v3),"=&v"(v4),"=&v"(v5),"=&v"(v6),"=&v"(v7),
      "=&v"(v8),"=&v"(v9),"=&v"(v10),"=&v"(v11),"=&v"(v12),"=&v"(v13),"=&v"(v14),"=&v"(v15)
    : "v"(p) : "memory");
  int s = 0, q = 0;
#define ACC2(vv) s += (int)(unsigned)((vv).x >> 32) + (int)(unsigned)((vv).y >> 32); \
                 q += (int)(unsigned)((vv).x)       + (int)(unsigned)((vv).y);
  ACC2(v0) ACC2(v1) ACC2(v2) ACC2(v3) ACC2(v4) ACC2(v5) ACC2(v6) ACC2(v7)
  ACC2(v8) ACC2(v9) ACC2(v10) ACC2(v11) ACC2(v12) ACC2(v13) ACC2(v14) ACC2(v15)
#undef ACC2
  m = (float)s * (S_INV) * invn;
  float msq = (float)q * (Q_INV) * invn;
  rs = rsqrtf(msq - m*m + 1e-5f);
}

// Coherent batched ISSUE (no wait) of 8 consecutive 64B k-chunks of one row.
__device__ __forceinline__ void ld8_issue(const f16* p, f16x8* f){
  asm volatile(
    "global_load_dwordx4 %0, %8, off sc0 sc1\n\t"
    "global_load_dwordx4 %1, %8, off offset:64 sc0 sc1\n\t"
    "global_load_dwordx4 %2, %8, off offset:128 sc0 sc1\n\t"
    "global_load_dwordx4 %3, %8, off offset:192 sc0 sc1\n\t"
    "global_load_dwordx4 %4, %8, off offset:256 sc0 sc1\n\t"
    "global_load_dwordx4 %5, %8, off offset:320 sc0 sc1\n\t"
    "global_load_dwordx4 %6, %8, off offset:384 sc0 sc1\n\t"
    "global_load_dwordx4 %7, %8, off offset:448 sc0 sc1"
    : "=&v"(f[0]),"=&v"(f[1]),"=&v"(f[2]),"=&v"(f[3]),
      "=&v"(f[4]),"=&v"(f[5]),"=&v"(f[6]),"=&v"(f[7])
    : "v"(p) : "memory");
}

// 32-row x 32-col x K=1024 GEMM slice. A rows from coherent global, 2 batches
// of 8 loads in flight (counted vmcnt waits); B frags in registers.
__device__ __forceinline__ f32x4 gemm32r(const f16* hp, const f16x8* bfrag){
  f32x4 a = {0.f,0.f,0.f,0.f};
  f16x8 fA[8], fB[8];
  ld8_issue(hp,       fA);
  ld8_issue(hp + 256, fB);
  vm_waitN<8>();
  #pragma unroll
  for (int kk = 0; kk < 8; ++kk) a = MFMA_F16(fA[kk], bfrag[kk], a);
  ld8_issue(hp + 512, fA);
  vm_waitN<8>();
  #pragma unroll
  for (int kk = 0; kk < 8; ++kk) a = MFMA_F16(fB[kk], bfrag[8 + kk], a);
  ld8_issue(hp + 768, fB);
  vm_waitN<8>();
  #pragma unroll
  for (int kk = 0; kk < 8; ++kk) a = MFMA_F16(fA[kk], bfrag[16 + kk], a);
  vm_waitN<0>();
  #pragma unroll
  for (int kk = 0; kk < 8; ++kk) a = MFMA_F16(fB[kk], bfrag[24 + kk], a);
  return a;
}

// ---------------------------------------------------------------------------
__global__ __launch_bounds__(256) void k_transpose_f16(const float* __restrict__ src,
    f16* __restrict__ dst, int K, int N, int dstStride, int dstOff){
  const int n0 = blockIdx.x*32, k0 = blockIdx.y*32, tid = threadIdx.x;
  __shared__ float tl[32][33];
  #pragma unroll
  for (int rep = 0; rep < 4; ++rep){
    int e = rep*256 + tid; int i = e >> 5, j = e & 31;
    int k = k0 + i, n = n0 + j;
    tl[i][j] = (k < K && n < N) ? src[(size_t)k*N + n] : 0.f;
  }
  __syncthreads();
  #pragma unroll
  for (int rep = 0; rep < 4; ++rep){
    int e = rep*256 + tid; int i2 = e & 31, j2 = e >> 5;
    int n = n0 + j2, k = k0 + i2;
    if (k < K && n < N) dst[(size_t)n*dstStride + dstOff + k] = (f16)tl[i2][j2];
  }
}

// ---------------------------------------------------------------------------
__global__ __launch_bounds__(256) void k_prenet(const float* __restrict__ dec,
    const float* __restrict__ w1, const float* __restrict__ w2, f16* __restrict__ cellin){
  const int t = blockIdx.x, tid = threadIdx.x;
  __shared__ float sin_[32][81];
  __shared__ f16   w1T[256][88];
  __shared__ float x1s[32][260];
  __shared__ f16   w2c[256][72];
  __shared__ f16   xo[32][256];
  for (int e = tid; e < 32*80; e += 256){
    int i = e/80, m = e - i*80;
    sin_[i][m] = (t == 0) ? 0.f : dec[(size_t)i*61440 + (size_t)m*768 + (t-1)];
  }
  for (int e = tid; e < 80*256; e += 256){ int m = e >> 8, j = e & 255; w1T[j][m] = (f16)w1[e]; }
  __syncthreads();
  const int j = tid;
  for (int i = 0; i < 32; ++i){
    float a = 0.f;
    #pragma unroll
    for (int m8 = 0; m8 < 10; ++m8){
      f16x8 wvv = *(const f16x8*)&w1T[j][m8*8];
      #pragma unroll
      for (int l = 0; l < 8; ++l) a += (float)wvv[l] * sin_[i][m8*8 + l];
    }
    x1s[i][j] = fmaxf(a, 0.f);
  }
  __syncthreads();
  float acc2[32];
  #pragma unroll
  for (int i = 0; i < 32; ++i) acc2[i] = 0.f;
  for (int c = 0; c < 4; ++c){
    for (int e = tid; e < 64*256; e += 256){
      int kl = e >> 8, jj = e & 255;
      w2c[jj][kl] = (f16)w2[(size_t)(c*64 + kl)*256 + jj];
    }
    __syncthreads();
    f16x8 wv8[8];
    #pragma unroll
    for (int k8 = 0; k8 < 8; ++k8) wv8[k8] = *(const f16x8*)&w2c[j][k8*8];
    for (int i = 0; i < 32; ++i){
      float a = 0.f;
      #pragma unroll
      for (int k8 = 0; k8 < 8; ++k8)
        #pragma unroll
        for (int l = 0; l < 8; ++l) a += (float)wv8[k8][l]*x1s[i][c*64 + k8*8 + l];
      acc2[i] += a;
    }
    __syncthreads();
  }
  for (int i = 0; i < 32; ++i) xo[i][j] = (f16)fmaxf(acc2[i], 0.f);
  __syncthreads();
  for (int e = tid; e < 32*256; e += 256){
    int i = e >> 8, jj = e & 255;
    cellin[((size_t)t*32 + i)*800 + jj] = xo[i][jj];
  }
}

// ---------------------------------------------------------------------------
__global__ __launch_bounds__(256) void k_durfill(const float* __restrict__ dur, f16* __restrict__ cellin){
  const int t = blockIdx.x, tid = threadIdx.x;
  for (int e = tid; e < 32*544; e += 256){
    int b = e / 544, c = e - b*544;
    cellin[((size_t)t*32 + b)*800 + 256 + c] = (f16)dur[(size_t)b*417792 + (size_t)t*544 + c];
  }
}

// ---------------------------------------------------------------------------
__global__ __launch_bounds__(256) void k_ws_report(float* __restrict__ out, int n, float val){
  int i = blockIdx.x*256 + threadIdx.x;
  if (i < n) out[i] = val;
}

// ---------------------------------------------------------------------------
// Pipelined two-layer recurrence (round-0 structure). Blocks 0..127 = layer 1
// (8 h1-units each), blocks 128..255 = layer 2; layer 2 runs ~1 step behind
// via double-buffered h1 + consumption throttle. 3 device-scope rounds per
// layer-step (z-stats, c-stats, h-publish) with counter lines.
// Stat partials: ONE u64 fixed-point atomic per row per block (s hi / q lo),
// row-major layout sacc64[round][row][cls32] so each u64 takes only 4 adds
// and each reader's row is one contiguous 256B burst (16 dwordx4, 1 RTT).
// ---------------------------------------------------------------------------
__global__ __launch_bounds__(512, 1) void k_recurrence(
    const f16* __restrict__ cellin, const f16* __restrict__ wxT1,
    const f16* __restrict__ whT1, const f16* __restrict__ w2T,
    f16* __restrict__ H2all, f16* __restrict__ h1buf, f16* __restrict__ h2buf,
    u64* __restrict__ sacc64, unsigned* __restrict__ ctrs,
    const float* __restrict__ b1v,
    const float* __restrict__ g1, const float* __restrict__ bn1,
    const float* __restrict__ gc1v, const float* __restrict__ bc1v,
    const float* __restrict__ b2v,
    const float* __restrict__ g2, const float* __restrict__ bn2,
    const float* __restrict__ gc2v, const float* __restrict__ bc2v)
{
  const int tid = threadIdx.x, blk = blockIdx.x;
  const int lane = tid & 63, wv = tid >> 6;
  const int r16 = lane & 15, quad = lane >> 4;
  const int part = wv >> 2, pair = wv & 3, rt = pair >> 1, ct = pair & 1;
  const int g_b = ct*2 + (r16 >> 3), u_b = r16 & 7;   // B-frag col decode
  const int u_o = tid >> 5, rb = tid & 31;            // owners (tid<256)
  const int zrow = tid >> 4, zc0 = tid & 15, zc1 = (tid & 15) + 16;
  const int zrt = zrow >> 4, zi = zrow & 15;
  const int arow = rt*16 + r16;

  __shared__ f16   swx[3200*8];
  __shared__ float zred[8][16][17];
  __shared__ float zfin[32][33];
  __shared__ float mst[32], vst[32];
  __shared__ float csA[8][32], csQ[8][32];

  f16x8 bfrag[32];

  if (blk < 128){
    // ======================= LAYER 1 =======================
    const int cls = blk & 15, cls32 = blk & 31, ub0 = blk*8;
    const int colg = (g_b << 10) + ub0 + u_b;
    if (part == 0){
      #pragma unroll
      for (int c = 0; c < 32; ++c)
        bfrag[c] = *(const f16x8*)(whT1 + (size_t)colg*1024 + c*32 + quad*8);
    }
    for (int idx = tid; idx < 3200; idx += 512){
      int l = idx & 15, q = (idx >> 4) & 3, v = idx >> 6;
      int c = v % 25, ctx = v / 25;
      int gg = ctx*2 + (l >> 3), uu = l & 7;
      int cg = (gg << 10) + ub0 + uu;
      *(f16x8*)(swx + idx*8) = *(const f16x8*)(wxT1 + (size_t)cg*800 + c*32 + q*8);
    }
    float pg[4], pb[4], gC = 0.f, bC = 0.f;
    if (tid < 256){
      #pragma unroll
      for (int g = 0; g < 4; ++g){
        int cg = (g << 10) + ub0 + u_o;
        pg[g] = g1[cg]; pb[g] = bn1[cg];
      }
      gC = gc1v[ub0 + u_o]; bC = bc1v[ub0 + u_o];
    }
    const float zb0 = b1v[((zc0 >> 3) << 10) + ub0 + (zc0 & 7)];
    const float zb1 = b1v[((zc1 >> 3) << 10) + ub0 + (zc1 & 7)];
    float c1 = 0.f, o1 = 0.f;
    __syncthreads();
    // prologue: x-GEMM for t=0
    if (part == 1){
      f32x4 a = {0.f,0.f,0.f,0.f};
      const f16* ap = cellin + (size_t)arow*800 + quad*8;
      for (int c = 0; c < 25; ++c){
        f16x8 av = *(const f16x8*)(ap + c*32);
        f16x8 bx = *(const f16x8*)(swx + (size_t)(((ct*25 + c)*4 + quad)*16 + r16)*8);
        a = MFMA_F16(av, bx, a);
      }
      #pragma unroll
      for (int reg = 0; reg < 4; ++reg) zred[wv][quad*4 + reg][r16] = a[reg];
    }
    for (int t = 0; t < 768; ++t){
      // --- A1: h1_{t-1} @ wh1 (waves 0-3); x-part already in zred[4..7] ---
      if (t > 0) bar_poll(ctrs, CT_H1, tid, 8u*t);
      __syncthreads();
      if (part == 0){
        if (t > 0){
          const f16* hp = h1buf + (size_t)((t+1)&1)*32768 + (size_t)arow*1024 + quad*8;
          f32x4 a = gemm32r(hp, bfrag);
          #pragma unroll
          for (int reg = 0; reg < 4; ++reg) zred[wv][quad*4 + reg][r16] = a[reg];
        } else {
          #pragma unroll
          for (int reg = 0; reg < 4; ++reg) zred[wv][quad*4 + reg][r16] = 0.f;
        }
      }
      __syncthreads();
      {
        float za  = zred[zrt*2    ][zi][zc0] + zred[4 + zrt*2    ][zi][zc0] + zb0;
        float zbv = zred[zrt*2 + 1][zi][zc0] + zred[4 + zrt*2 + 1][zi][zc0] + zb1;
        zfin[zrow][zc0] = za; zfin[zrow][zc1] = zbv;
        float s = za + zbv, q = za*za + zbv*zbv;
        s += __shfl_down(s, 8); q += __shfl_down(q, 8);
        s += __shfl_down(s, 4); q += __shfl_down(q, 4);
        s += __shfl_down(s, 2); q += __shfl_down(q, 2);
        s += __shfl_down(s, 1); q += __shfl_down(q, 1);
        if ((tid & 15) == 0)
          atomicAdd(sacc64 + (((size_t)t*4 + 0)*32 + zrow)*32 + cls32, pk_sq(s, q));
      }
      vm_drain(); __syncthreads();
      if (tid == 0) bar_arrive(ctrs + (CT_A1*NCLS + cls)*16);
      // filler: x-GEMM for t+1 (hidden in hop wait)
      if (part == 1 && t < 767){
        f32x4 a = {0.f,0.f,0.f,0.f};
        const f16* ap = cellin + (size_t)(t+1)*25600 + (size_t)arow*800 + quad*8;
        for (int c = 0; c < 25; ++c){
          f16x8 av = *(const f16x8*)(ap + c*32);
          f16x8 bx = *(const f16x8*)(swx + (size_t)(((ct*25 + c)*4 + quad)*16 + r16)*8);
          a = MFMA_F16(av, bx, a);
        }
        #pragma unroll
        for (int reg = 0; reg < 4; ++reg) zred[wv][quad*4 + reg][r16] = a[reg];
      }
      bar_poll(ctrs, CT_A1, tid, 8u*(t+1));
      __syncthreads();
      // --- B1: LN1 -> gates -> c1 ---
      if (tid < 32){
        float m, rs;
        ln_read32(sacc64 + (((size_t)t*4 + 0)*32 + tid)*32, 1.f/4096.f, m, rs);
        mst[tid] = m; vst[tid] = rs;
      }
      __syncthreads();
      if (tid < 256){
        const float m = mst[rb], rs = vst[rb];
        const float ziv = (zfin[rb][u_o]      - m)*rs*pg[0] + pb[0];
        const float zf  = (zfin[rb][8 + u_o]  - m)*rs*pg[1] + pb[1];
        const float zg  = (zfin[rb][16 + u_o] - m)*rs*pg[2] + pb[2];
        const float zo  = (zfin[rb][24 + u_o] - m)*rs*pg[3] + pb[3];
        c1 = sigf(zf)*c1 + sigf(ziv)*tanhf(zg);
        o1 = sigf(zo);
        csA[u_o][rb] = c1; csQ[u_o][rb] = c1*c1;
      }
      __syncthreads();
      if (tid < 32){
        float s = 0.f, q = 0.f;
        #pragma unroll
        for (int u = 0; u < 8; ++u){ s += csA[u][tid]; q += csQ[u][tid]; }
        atomicAdd(sacc64 + (((size_t)t*4 + 1)*32 + tid)*32 + cls32, pk_sq(s, q));
      }
      vm_drain();                              // producers + arriver all wave 0
      if (tid == 0) bar_arrive(ctrs + (CT_B1*NCLS + cls)*16);
      bar_poll(ctrs, CT_B1, tid, 8u*(t+1));
      __syncthreads();
      // --- B1': h1 = sig(o)*tanh(LN(c1)), publish ---
      if (tid < 32){
        float m, rs;
        ln_read32(sacc64 + (((size_t)t*4 + 1)*32 + tid)*32, 1.f/1024.f, m, rs);
        mst[tid] = m; vst[tid] = rs;
      } else if (t >= 2 && tid < 48){
        const unsigned* p = ctrs + (CT_C*NCLS + (tid - 32))*16;
        while (__hip_atomic_load(p, __ATOMIC_RELAXED, __HIP_MEMORY_SCOPE_AGENT) < 8u*(t-1))
          __builtin_amdgcn_s_sleep(1);
      }
      __syncthreads();
      if (tid < 256){
        float rs = vst[rb];
        float arg = fmaf(fmaf(c1, rs, -mst[rb]*rs), gC, bC);
        float e = exp2f(arg * 2.885390081777927f);
        float h = o1 * fmaf(-2.f, __builtin_amdgcn_rcpf(e + 1.f), 1.f);
        st_wt_f16(h1buf + (size_t)(t&1)*32768 + rb*1024 + ub0 + u_o, (f16)h);
      }
      vm_drain(); __syncthreads();
      if (tid == 0) bar_arrive(ctrs + (CT_H1*NCLS + cls)*16);
    }
  } else {
    // ======================= LAYER 2 =======================
    const int blk2 = blk - 128, cls = blk2 & 15, cls32 = blk2 & 31, ub0 = blk2*8;
    const int colg = (g_b << 10) + ub0 + u_b;
    {
      const f16* wsrc = w2T + (size_t)colg*2048 + (part == 0 ? 1024 : 0);
      #pragma unroll
      for (int c = 0; c < 32; ++c)
        bfrag[c] = *(const f16x8*)(wsrc + c*32 + quad*8);
    }
    float pg[4], pb[4], gC = 0.f, bC = 0.f;
    if (tid < 256){
      #pragma unroll
      for (int g = 0; g < 4; ++g){
        int cg = (g << 10) + ub0 + u_o;
        pg[g] = g2[cg]; pb[g] = bn2[cg];
      }
      gC = gc2v[ub0 + u_o]; bC = bc2v[ub0 + u_o];
    }
    const float zb0 = b2v[((zc0 >> 3) << 10) + ub0 + (zc0 & 7)];
    const float zb1 = b2v[((zc1 >> 3) << 10) + ub0 + (zc1 & 7)];
    float c2 = 0.f, o2 = 0.f;
    __syncthreads();
    for (int t = 0; t < 768; ++t){
      // --- A2: z2 = h1_t @ w2x (waves 4-7) + h2_{t-1} @ w2h (waves 0-3) ---
      bar_poll(ctrs, CT_H1, tid, 8u*(t+1));
      if (t > 0 && tid >= 16 && tid < 32){
        const unsigned* p = ctrs + (CT_H2*NCLS + (tid - 16))*16;
        while (__hip_atomic_load(p, __ATOMIC_RELAXED, __HIP_MEMORY_SCOPE_AGENT) < 8u*t)
          __builtin_amdgcn_s_sleep(1);
      }
      __syncthreads();
      if (part == 0 && t == 0){
        #pragma unroll
        for (int reg = 0; reg < 4; ++reg) zred[wv][quad*4 + reg][r16] = 0.f;
      } else {
        const f16* hp = (part == 0)
          ? h2buf + (size_t)((t+1)&1)*32768 + (size_t)arow*1024 + quad*8
          : h1buf + (size_t)(t&1)*32768     + (size_t)arow*1024 + quad*8;
        f32x4 a = gemm32r(hp, bfrag);
        #pragma unroll
        for (int reg = 0; reg < 4; ++reg) zred[wv][quad*4 + reg][r16] = a[reg];
      }
      __syncthreads();
      {
        float za  = zred[zrt*2    ][zi][zc0] + zred[4 + zrt*2    ][zi][zc0] + zb0;
        float zbv = zred[zrt*2 + 1][zi][zc0] + zred[4 + zrt*2 + 1][zi][zc0] + zb1;
        zfin[zrow][zc0] = za; zfin[zrow][zc1] = zbv;
        float s = za + zbv, q = za*za + zbv*zbv;
        s += __shfl_down(s, 8); q += __shfl_down(q, 8);
        s += __shfl_down(s, 4); q += __shfl_down(q, 4);
        s += __shfl_down(s, 2); q += __shfl_down(q, 2);
        s += __shfl_down(s, 1); q += __shfl_down(q, 1);
        if ((tid & 15) == 0)
          atomicAdd(sacc64 + (((size_t)t*4 + 2)*32 + zrow)*32 + cls32, pk_sq(s, q));
      }
      vm_drain(); __syncthreads();
      if (tid == 0)  bar_arrive(ctrs + (CT_A2*NCLS + cls)*16);
      if (tid == 64) bar_arrive(ctrs + (CT_C*NCLS + cls)*16);   // h1_t consumed
      bar_poll(ctrs, CT_A2, tid, 8u*(t+1));
      __syncthreads();
      // --- B2: LN2 -> gates -> c2 ---
      if (tid < 32){
        float m, rs;
        ln_read32(sacc64 + (((size_t)t*4 + 2)*32 + tid)*32, 1.f/4096.f, m, rs);
        mst[tid] = m; vst[tid] = rs;
      }
      __syncthreads();
      if (tid < 256){
        const float m = mst[rb], rs = vst[rb];
        const float ziv = (zfin[rb][u_o]      - m)*rs*pg[0] + pb[0];
        const float zf  = (zfin[rb][8 + u_o]  - m)*rs*pg[1] + pb[1];
        const float zg  = (zfin[rb][16 + u_o] - m)*rs*pg[2] + pb[2];
        const float zo  = (zfin[rb][24 + u_o] - m)*rs*pg[3] + pb[3];
        c2 = sigf(zf)*c2 + sigf(ziv)*tanhf(zg);
        o2 = sigf(zo);
        csA[u_o][rb] = c2; csQ[u_o][rb] = c2*c2;
      }
      __syncthreads();
      if (tid < 32){
        float s = 0.f, q = 0.f;
        #pragma unroll
        for (int u = 0; u < 8; ++u){ s += csA[u][tid]; q += csQ[u][tid]; }
        atomicAdd(sacc64 + (((size_t)t*4 + 3)*32 + tid)*32 + cls32, pk_sq(s, q));
      }
      vm_drain();                              // producers + arriver all wave 0
      if (tid == 0) bar_arrive(ctrs + (CT_B2*NCLS + cls)*16);
      bar_poll(ctrs, CT_B2, tid, 8u*(t+1));
      __syncthreads();
      // --- B2': h2 publish (+ H2all for projection) ---
      if (tid < 32){
        float m, rs;
        ln_read32(sacc64 + (((size_t)t*4 + 3)*32 + tid)*32, 1.f/1024.f, m, rs);
        mst[tid] = m; vst[tid] = rs;
      }
      __syncthreads();
      if (tid < 256){
        float rs = vst[rb];
        float arg = fmaf(fmaf(c2, rs, -mst[rb]*rs), gC, bC);
        float e = exp2f(arg * 2.885390081777927f);
        float h = o2 * fmaf(-2.f, __builtin_amdgcn_rcpf(e + 1.f), 1.f);
        st_wt_f16(h2buf + (size_t)(t&1)*32768 + rb*1024 + ub0 + u_o, (f16)h);
        st_wt_f16(H2all + (size_t)(t+1)*32768 + rb*1024 + ub0 + u_o, (f16)h);
      }
      vm_drain(); __syncthreads();
      if (tid == 0) bar_arrive(ctrs + (CT_H2*NCLS + cls)*16);
    }
  }
}

// ---------------------------------------------------------------------------
__global__ __launch_bounds__(256) void k_proj(const f16* __restrict__ H2all, const f16* __restrict__ cellin,
    const f16* __restrict__ projT, const float* __restrict__ projb, float* __restrict__ out){
  const int t = blockIdx.x, tid = threadIdx.x;
  const int lane = tid & 63, wv = tid >> 6;
  const int r16 = lane & 15, quad = lane >> 4;
  __shared__ float pred[4][32][84];
  f32x4 acc[2][5] = {};
  const f16* H2 = H2all + (size_t)(t+1)*32768;
  const f16* CI = cellin + (size_t)t*32*800;
  const int kbeg = wv*13;
  const int kend = (wv == 3) ? 49 : (kbeg + 13);
  for (int ks = kbeg; ks < kend; ++ks){
    const int k0 = ks*32 + quad*8;
    f16x8 a0, a1;
    if (ks < 32){
      a0 = *(const f16x8*)(H2 + r16*1024 + k0);
      a1 = *(const f16x8*)(H2 + (16+r16)*1024 + k0);
    } else {
      a0 = *(const f16x8*)(CI + r16*800 + 256 + (k0 - 1024));
      a1 = *(const f16x8*)(CI + (16+r16)*800 + 256 + (k0 - 1024));
    }
    f16x8 bf[5];
    #pragma unroll
    for (int nt = 0; nt < 5; ++nt)
      bf[nt] = *(const f16x8*)(projT + (size_t)(nt*16 + r16)*1568 + k0);
    #pragma unroll
    for (int nt = 0; nt < 5; ++nt){
      acc[0][nt] = MFMA_F16(a0, bf[nt], acc[0][nt]);
      acc[1][nt] = MFMA_F16(a1, bf[nt], acc[1][nt]);
    }
  }
  #pragma unroll
  for (int mt = 0; mt < 2; ++mt)
    #pragma unroll
    for (int nt = 0; nt < 5; ++nt)
      #pragma unroll
      for (int reg = 0; reg < 4; ++reg)
        pred[wv][mt*16 + quad*4 + reg][nt*16 + r16] = acc[mt][nt][reg];
  __syncthreads();
  for (int e = tid; e < 2560; e += 256){
    int m = e >> 5, b = e & 31;
    float v = pred[0][b][m] + pred[1][b][m] + pred[2][b][m] + pred[3][b][m] + projb[m];
    out[(size_t)b*61440 + (size_t)m*768 + t] = v;
  }
}

// ---------------------------------------------------------------------------
extern "C" void kernel_launch(void* const* d_in, const int* in_sizes, int n_in,
                              void* d_out, int out_size, void* d_ws, size_t ws_size,
                              hipStream_t stream)
{
  const float* duration = (const float*)d_in[0];
  const float* decoder  = (const float*)d_in[1];
  const float* pre_w1   = (const float*)d_in[3];
  const float* pre_w2   = (const float*)d_in[4];
  const float* rnn1_wx  = (const float*)d_in[5];
  const float* rnn1_wh  = (const float*)d_in[6];
  const float* rnn1_b   = (const float*)d_in[7];
  const float* rnn1_g   = (const float*)d_in[8];
  const float* rnn1_bn  = (const float*)d_in[9];
  const float* rnn1_gc  = (const float*)d_in[10];
  const float* rnn1_bc  = (const float*)d_in[11];
  const float* rnn2_wx  = (const float*)d_in[12];
  const float* rnn2_wh  = (const float*)d_in[13];
  const float* rnn2_b   = (const float*)d_in[14];
  const float* rnn2_g   = (const float*)d_in[15];
  const float* rnn2_bn  = (const float*)d_in[16];
  const float* rnn2_gc  = (const float*)d_in[17];
  const float* rnn2_bc  = (const float*)d_in[18];
  const float* proj_w   = (const float*)d_in[19];
  const float* proj_b   = (const float*)d_in[20];
  float* out = (float*)d_out;

  char* w = (char*)d_ws;
  f16* cellin = (f16*)w;      w += (size_t)24576*800*2;
  f16* wxT1   = (f16*)w;      w += (size_t)4096*800*2;
  f16* whT1   = (f16*)w;      w += (size_t)4096*1024*2;
  f16* w2T    = (f16*)w;      w += (size_t)4096*2048*2;
  f16* projT  = (f16*)w;      w += 262144;
  f16* H2all  = (f16*)w;      w += (size_t)769*32768*2;
  f16* h1buf  = (f16*)w;      w += 131072;   // 2 slots x 32x1024 f16
  f16* h2buf  = (f16*)w;      w += 131072;
  u64* sacc64 = (u64*)w;      w += (size_t)768*4*32*32*8;
  unsigned* ctrs = (unsigned*)w; w += 8192;
  const size_t need = (size_t)((char*)w - (char*)d_ws);
  if (ws_size < need){
    k_ws_report<<<(out_size + 255)/256, 256, 0, stream>>>(out, out_size, (float)(ws_size >> 20));
    return;
  }

  (void)hipMemsetAsync(sacc64, 0, (size_t)768*4*32*32*8, stream);
  (void)hipMemsetAsync(ctrs, 0, 8192, stream);
  (void)hipMemsetAsync(h1buf, 0, 131072, stream);
  (void)hipMemsetAsync(h2buf, 0, 131072, stream);

  k_transpose_f16<<<dim3(4096/32, 25), 256, 0, stream>>>(rnn1_wx, wxT1, 800, 4096, 800, 0);
  k_transpose_f16<<<dim3(4096/32, 32), 256, 0, stream>>>(rnn1_wh, whT1, 1024, 4096, 1024, 0);
  k_transpose_f16<<<dim3(4096/32, 32), 256, 0, stream>>>(rnn2_wx, w2T, 1024, 4096, 2048, 0);
  k_transpose_f16<<<dim3(4096/32, 32), 256, 0, stream>>>(rnn2_wh, w2T, 1024, 4096, 2048, 1024);
  k_transpose_f16<<<dim3(3, 49), 256, 0, stream>>>(proj_w, projT, 1568, 80, 1568, 0);
  k_prenet<<<768, 256, 0, stream>>>(decoder, pre_w1, pre_w2, cellin);
  k_durfill<<<768, 256, 0, stream>>>(duration, cellin);
  k_recurrence<<<256, 512, 0, stream>>>(cellin, wxT1, whT1, w2T, H2all, h1buf, h2buf, sacc64, ctrs,
      rnn1_b, rnn1_g, rnn1_bn, rnn1_gc, rnn1_bc,
      rnn2_b, rnn2_g, rnn2_bn, rnn2_gc, rnn2_bc);
  k_proj<<<768, 256, 0, stream>>>(H2all, cellin, projT, proj_b, out);
}

// Round 6
// 10913.936 us; speedup vs baseline: 2.6516x; 1.3053x over previous
//
#include <hip/hip_runtime.h>
#include <cstdint>
#include <cstddef>

typedef _Float16 f16;
typedef _Float16 f16x8 __attribute__((ext_vector_type(8)));
typedef float f32x4 __attribute__((ext_vector_type(4)));

#define MFMA_F16(a,b,c) __builtin_amdgcn_mfma_f32_16x16x32_f16((a),(b),(c),0,0,0)

#define NCLS 16
// counter sets
#define CT_A1 0   // layer1 z tiles written   (8 arrivals/class/step)
#define CT_H1 1   // layer1 h published       (2 arrivals/class/step)
#define CT_A2 2   // layer2 z tiles written   (8/class/step)
#define CT_H2 3   // layer2 h published       (2/class/step)
#define CT_C  4   // layer2 consumed h1(t)    (8/class/step)

__device__ __forceinline__ float sigf(float x){ return 1.f/(1.f + expf(-x)); }

__device__ __forceinline__ void st_wt_f32(float* p, float v){
  asm volatile("global_store_dword %0, %1, off sc0 sc1" :: "v"(p), "v"(v) : "memory");
}
__device__ __forceinline__ void st_wt_u32(f16* p, unsigned v){
  asm volatile("global_store_dword %0, %1, off sc0 sc1" :: "v"(p), "v"(v) : "memory");
}
__device__ __forceinline__ void vm_drain(){ asm volatile("s_waitcnt vmcnt(0)" ::: "memory"); }

template<int N> __device__ __forceinline__ void vm_waitN(){
  asm volatile("s_waitcnt vmcnt(%0)" :: "i"(N) : "memory");
  __builtin_amdgcn_sched_barrier(0);
}

__device__ __forceinline__ void bar_arrive(unsigned* c){
  __hip_atomic_fetch_add(c, 1u, __ATOMIC_RELAXED, __HIP_MEMORY_SCOPE_AGENT);
}
__device__ __forceinline__ void spin_ge(const unsigned* p, unsigned target){
  while (__hip_atomic_load(p, __ATOMIC_RELAXED, __HIP_MEMORY_SCOPE_AGENT) < target)
    __builtin_amdgcn_s_sleep(1);
}

// Coherent read of 8 consecutive f32 (one 32B slice of a z row).
__device__ __forceinline__ void ld_8f32(const float* p, f32x4& a, f32x4& b){
  asm volatile(
    "global_load_dwordx4 %0, %2, off sc0 sc1\n\t"
    "global_load_dwordx4 %1, %2, off offset:16 sc0 sc1\n\t"
    "s_waitcnt vmcnt(0)"
    : "=&v"(a), "=&v"(b) : "v"(p) : "memory");
}

// Coherent batched ISSUE (no wait) of 8 consecutive 64B k-chunks of one row.
__device__ __forceinline__ void ld8_issue(const f16* p, f16x8* f){
  asm volatile(
    "global_load_dwordx4 %0, %8, off sc0 sc1\n\t"
    "global_load_dwordx4 %1, %8, off offset:64 sc0 sc1\n\t"
    "global_load_dwordx4 %2, %8, off offset:128 sc0 sc1\n\t"
    "global_load_dwordx4 %3, %8, off offset:192 sc0 sc1\n\t"
    "global_load_dwordx4 %4, %8, off offset:256 sc0 sc1\n\t"
    "global_load_dwordx4 %5, %8, off offset:320 sc0 sc1\n\t"
    "global_load_dwordx4 %6, %8, off offset:384 sc0 sc1\n\t"
    "global_load_dwordx4 %7, %8, off offset:448 sc0 sc1"
    : "=&v"(f[0]),"=&v"(f[1]),"=&v"(f[2]),"=&v"(f[3]),
      "=&v"(f[4]),"=&v"(f[5]),"=&v"(f[6]),"=&v"(f[7])
    : "v"(p) : "memory");
}

// 32-row x 32-col x K=1024 GEMM slice. A rows from coherent global, 2 batches
// of 8 loads in flight (counted vmcnt waits); B frags in registers.
__device__ __forceinline__ f32x4 gemm32r(const f16* hp, const f16x8* bfrag){
  f32x4 a = {0.f,0.f,0.f,0.f};
  f16x8 fA[8], fB[8];
  ld8_issue(hp,       fA);
  ld8_issue(hp + 256, fB);
  vm_waitN<8>();
  #pragma unroll
  for (int kk = 0; kk < 8; ++kk) a = MFMA_F16(fA[kk], bfrag[kk], a);
  ld8_issue(hp + 512, fA);
  vm_waitN<8>();
  #pragma unroll
  for (int kk = 0; kk < 8; ++kk) a = MFMA_F16(fB[kk], bfrag[8 + kk], a);
  ld8_issue(hp + 768, fB);
  vm_waitN<8>();
  #pragma unroll
  for (int kk = 0; kk < 8; ++kk) a = MFMA_F16(fA[kk], bfrag[16 + kk], a);
  vm_waitN<0>();
  #pragma unroll
  for (int kk = 0; kk < 8; ++kk) a = MFMA_F16(fB[kk], bfrag[24 + kk], a);
  return a;
}

// ---------------------------------------------------------------------------
__global__ __launch_bounds__(256) void k_transpose_f16(const float* __restrict__ src,
    f16* __restrict__ dst, int K, int N, int dstStride, int dstOff){
  const int n0 = blockIdx.x*32, k0 = blockIdx.y*32, tid = threadIdx.x;
  __shared__ float tl[32][33];
  #pragma unroll
  for (int rep = 0; rep < 4; ++rep){
    int e = rep*256 + tid; int i = e >> 5, j = e & 31;
    int k = k0 + i, n = n0 + j;
    tl[i][j] = (k < K && n < N) ? src[(size_t)k*N + n] : 0.f;
  }
  __syncthreads();
  #pragma unroll
  for (int rep = 0; rep < 4; ++rep){
    int e = rep*256 + tid; int i2 = e & 31, j2 = e >> 5;
    int n = n0 + j2, k = k0 + i2;
    if (k < K && n < N) dst[(size_t)n*dstStride + dstOff + k] = (f16)tl[i2][j2];
  }
}

// ---------------------------------------------------------------------------
__global__ __launch_bounds__(256) void k_prenet(const float* __restrict__ dec,
    const float* __restrict__ w1, const float* __restrict__ w2, f16* __restrict__ cellin){
  const int t = blockIdx.x, tid = threadIdx.x;
  __shared__ float sin_[32][81];
  __shared__ f16   w1T[256][88];
  __shared__ float x1s[32][260];
  __shared__ f16   w2c[256][72];
  __shared__ f16   xo[32][256];
  for (int e = tid; e < 32*80; e += 256){
    int i = e/80, m = e - i*80;
    sin_[i][m] = (t == 0) ? 0.f : dec[(size_t)i*61440 + (size_t)m*768 + (t-1)];
  }
  for (int e = tid; e < 80*256; e += 256){ int m = e >> 8, j = e & 255; w1T[j][m] = (f16)w1[e]; }
  __syncthreads();
  const int j = tid;
  for (int i = 0; i < 32; ++i){
    float a = 0.f;
    #pragma unroll
    for (int m8 = 0; m8 < 10; ++m8){
      f16x8 wvv = *(const f16x8*)&w1T[j][m8*8];
      #pragma unroll
      for (int l = 0; l < 8; ++l) a += (float)wvv[l] * sin_[i][m8*8 + l];
    }
    x1s[i][j] = fmaxf(a, 0.f);
  }
  __syncthreads();
  float acc2[32];
  #pragma unroll
  for (int i = 0; i < 32; ++i) acc2[i] = 0.f;
  for (int c = 0; c < 4; ++c){
    for (int e = tid; e < 64*256; e += 256){
      int kl = e >> 8, jj = e & 255;
      w2c[jj][kl] = (f16)w2[(size_t)(c*64 + kl)*256 + jj];
    }
    __syncthreads();
    f16x8 wv8[8];
    #pragma unroll
    for (int k8 = 0; k8 < 8; ++k8) wv8[k8] = *(const f16x8*)&w2c[j][k8*8];
    for (int i = 0; i < 32; ++i){
      float a = 0.f;
      #pragma unroll
      for (int k8 = 0; k8 < 8; ++k8)
        #pragma unroll
        for (int l = 0; l < 8; ++l) a += (float)wv8[k8][l]*x1s[i][c*64 + k8*8 + l];
      acc2[i] += a;
    }
    __syncthreads();
  }
  for (int i = 0; i < 32; ++i) xo[i][j] = (f16)fmaxf(acc2[i], 0.f);
  __syncthreads();
  for (int e = tid; e < 32*256; e += 256){
    int i = e >> 8, jj = e & 255;
    cellin[((size_t)t*32 + i)*800 + jj] = xo[i][jj];
  }
}

// ---------------------------------------------------------------------------
__global__ __launch_bounds__(256) void k_durfill(const float* __restrict__ dur, f16* __restrict__ cellin){
  const int t = blockIdx.x, tid = threadIdx.x;
  for (int e = tid; e < 32*544; e += 256){
    int b = e / 544, c = e - b*544;
    cellin[((size_t)t*32 + b)*800 + 256 + c] = (f16)dur[(size_t)b*417792 + (size_t)t*544 + c];
  }
}

// ---------------------------------------------------------------------------
__global__ __launch_bounds__(256) void k_ws_report(float* __restrict__ out, int n, float val){
  int i = blockIdx.x*256 + threadIdx.x;
  if (i < n) out[i] = val;
}

// ---------------------------------------------------------------------------
// Batch-owner recurrence. Blocks 0..127 = layer-1 GEMM (8 units each),
// blocks 128..255 = layer-2 GEMM; blocks 0..31 / 128..159 additionally OWN
// batch row b = blk (/ blk-128): they read the full 4096-gate z row, do
// LN(z) -> gates -> c -> LN(c) -> h entirely block-locally (c in registers),
// and publish h. 2 device rounds per layer-step (z-ready, h-ready); no stat
// atomics. x-filler GEMM runs on part-1 waves concurrently with the h-GEMM
// via double-buffered zredX.
// Audited deadlock-free: dependency lattice is monotone with 2-step pipeline
// lag; all buffer reuse gated by CT_H1/CT_H2/CT_C transitive waits.
// ---------------------------------------------------------------------------
__global__ __launch_bounds__(512, 1) void k_recurrence(
    const f16* __restrict__ cellin, const f16* __restrict__ wxT1,
    const f16* __restrict__ whT1, const f16* __restrict__ w2T,
    f16* __restrict__ H2all, f16* __restrict__ h1buf, f16* __restrict__ h2buf,
    float* __restrict__ zbuf1, float* __restrict__ zbuf2,
    unsigned* __restrict__ ctrs,
    const float* __restrict__ b1v,
    const float* __restrict__ g1, const float* __restrict__ bn1,
    const float* __restrict__ gc1v, const float* __restrict__ bc1v,
    const float* __restrict__ b2v,
    const float* __restrict__ g2, const float* __restrict__ bn2,
    const float* __restrict__ gc2v, const float* __restrict__ bc2v)
{
  const int tid = threadIdx.x, blk = blockIdx.x;
  const int lane = tid & 63, wv = tid >> 6;
  const int r16 = lane & 15, quad = lane >> 4;
  const int part = wv >> 2, pair = wv & 3, rt = pair >> 1, ct = pair & 1;
  const int g_b = ct*2 + (r16 >> 3), u_b = r16 & 7;   // B-frag col decode
  const int zrow = tid >> 4, zc0 = tid & 15, zc1 = (tid & 15) + 16;
  const int zrt = zrow >> 4, zi = zrow & 15;
  const int arow = rt*16 + r16;

  __shared__ f16   swx[3200*8];
  __shared__ float zredA[8][16][17];
  __shared__ float zredX[2][4][16][17];
  __shared__ float zs[4096];
  __shared__ float wredS1[8], wredQ1[8], wredS2[8], wredQ2[8];

  f16x8 bfrag[32];

  if (blk < 128){
    // ======================= LAYER 1 =======================
    const int cls = blk & 15, ub0 = blk*8;
    const int colg = (g_b << 10) + ub0 + u_b;
    if (part == 0){
      #pragma unroll
      for (int c = 0; c < 32; ++c)
        bfrag[c] = *(const f16x8*)(whT1 + (size_t)colg*1024 + c*32 + quad*8);
    }
    for (int idx = tid; idx < 3200; idx += 512){
      int l = idx & 15, q = (idx >> 4) & 3, v = idx >> 6;
      int c = v % 25, ctx = v / 25;
      int gg = ctx*2 + (l >> 3), uu = l & 7;
      int cg = (gg << 10) + ub0 + uu;
      *(f16x8*)(swx + idx*8) = *(const f16x8*)(wxT1 + (size_t)cg*800 + c*32 + q*8);
    }
    const float zb0 = b1v[((zc0 >> 3) << 10) + ub0 + (zc0 & 7)];
    const float zb1 = b1v[((zc1 >> 3) << 10) + ub0 + (zc1 & 7)];
    // owner (batch row = blk) per-unit params, 2 units per thread
    float pgv[4][2], pbv[4][2], gcv[2], bcv[2], cst[2] = {0.f, 0.f};
    if (blk < 32){
      #pragma unroll
      for (int k = 0; k < 2; ++k){
        const int u = 2*tid + k;
        #pragma unroll
        for (int g = 0; g < 4; ++g){
          pgv[g][k] = g1[(g << 10) + u]; pbv[g][k] = bn1[(g << 10) + u];
        }
        gcv[k] = gc1v[u]; bcv[k] = bc1v[u];
      }
    }
    __syncthreads();
    // prologue: x-GEMM for t=0 into zredX slot 0
    if (part == 1){
      f32x4 a = {0.f,0.f,0.f,0.f};
      const f16* ap = cellin + (size_t)arow*800 + quad*8;
      for (int c = 0; c < 25; ++c){
        f16x8 av = *(const f16x8*)(ap + c*32);
        f16x8 bx = *(const f16x8*)(swx + (size_t)(((ct*25 + c)*4 + quad)*16 + r16)*8);
        a = MFMA_F16(av, bx, a);
      }
      #pragma unroll
      for (int reg = 0; reg < 4; ++reg) zredX[0][wv-4][quad*4 + reg][r16] = a[reg];
    }
    for (int t = 0; t < 768; ++t){
      // --- wait h1(t-1); GEMM phase: part0 h-GEMM || part1 x-filler(t+1) ---
      if (t > 0 && tid < 16) spin_ge(ctrs + (CT_H1*NCLS + tid)*16, 2u*t);
      __syncthreads();
      if (part == 0){
        if (t > 0){
          const f16* hp = h1buf + (size_t)((t+1)&1)*32768 + (size_t)arow*1024 + quad*8;
          f32x4 a = gemm32r(hp, bfrag);
          #pragma unroll
          for (int reg = 0; reg < 4; ++reg) zredA[wv][quad*4 + reg][r16] = a[reg];
        } else {
          #pragma unroll
          for (int reg = 0; reg < 4; ++reg) zredA[wv][quad*4 + reg][r16] = 0.f;
        }
      } else if (t < 767){
        f32x4 a = {0.f,0.f,0.f,0.f};
        const f16* ap = cellin + (size_t)(t+1)*25600 + (size_t)arow*800 + quad*8;
        for (int c = 0; c < 25; ++c){
          f16x8 av = *(const f16x8*)(ap + c*32);
          f16x8 bx = *(const f16x8*)(swx + (size_t)(((ct*25 + c)*4 + quad)*16 + r16)*8);
          a = MFMA_F16(av, bx, a);
        }
        #pragma unroll
        for (int reg = 0; reg < 4; ++reg) zredX[(t+1)&1][wv-4][quad*4 + reg][r16] = a[reg];
      }
      __syncthreads();
      // --- combine + biased z write to zbuf1 ---
      {
        const int xs = t & 1;
        float za  = zredA[zrt*2    ][zi][zc0] + zredX[xs][zrt*2    ][zi][zc0] + zb0;
        float zbv = zredA[zrt*2 + 1][zi][zc0] + zredX[xs][zrt*2 + 1][zi][zc0] + zb1;
        float* zp = zbuf1 + (size_t)zrow*4096;
        st_wt_f32(zp + ((zc0 >> 3) << 10) + ub0 + (zc0 & 7), za);
        st_wt_f32(zp + ((zc1 >> 3) << 10) + ub0 + (zc1 & 7), zbv);
      }
      vm_drain(); __syncthreads();
      if (tid == 0) bar_arrive(ctrs + (CT_A1*NCLS + cls)*16);
      // --- owner gate phase (blocks 0..31) ---
      if (blk < 32){
        if (tid < 16) spin_ge(ctrs + (CT_A1*NCLS + tid)*16, 8u*(t+1));
        else if (t >= 2 && tid < 32) spin_ge(ctrs + (CT_C*NCLS + (tid-16))*16, 8u*(t-1));
        __syncthreads();
        f32x4 va, vb;
        ld_8f32(zbuf1 + (size_t)blk*4096 + tid*8, va, vb);
        *(f32x4*)(zs + tid*8)     = va;
        *(f32x4*)(zs + tid*8 + 4) = vb;
        float s = va.x+va.y+va.z+va.w + vb.x+vb.y+vb.z+vb.w;
        float q = va.x*va.x+va.y*va.y+va.z*va.z+va.w*va.w
                + vb.x*vb.x+vb.y*vb.y+vb.z*vb.z+vb.w*vb.w;
        s += __shfl_down(s, 32); q += __shfl_down(q, 32);
        s += __shfl_down(s, 16); q += __shfl_down(q, 16);
        s += __shfl_down(s, 8);  q += __shfl_down(q, 8);
        s += __shfl_down(s, 4);  q += __shfl_down(q, 4);
        s += __shfl_down(s, 2);  q += __shfl_down(q, 2);
        s += __shfl_down(s, 1);  q += __shfl_down(q, 1);
        if (lane == 0){ wredS1[wv] = s; wredQ1[wv] = q; }
        __syncthreads();
        float S = 0.f, Q = 0.f;
        #pragma unroll
        for (int w = 0; w < 8; ++w){ S += wredS1[w]; Q += wredQ1[w]; }
        const float m1 = S * (1.f/4096.f);
        const float rs1 = rsqrtf(Q*(1.f/4096.f) - m1*m1 + 1e-5f);
        float oo[2];
        #pragma unroll
        for (int k = 0; k < 2; ++k){
          const int u = 2*tid + k;
          const float ziv = (zs[u]        - m1)*rs1*pgv[0][k] + pbv[0][k];
          const float zf  = (zs[1024 + u] - m1)*rs1*pgv[1][k] + pbv[1][k];
          const float zg  = (zs[2048 + u] - m1)*rs1*pgv[2][k] + pbv[2][k];
          const float zo  = (zs[3072 + u] - m1)*rs1*pgv[3][k] + pbv[3][k];
          cst[k] = sigf(zf)*cst[k] + sigf(ziv)*tanhf(zg);
          oo[k] = sigf(zo);
        }
        float s2 = cst[0] + cst[1], q2 = cst[0]*cst[0] + cst[1]*cst[1];
        s2 += __shfl_down(s2, 32); q2 += __shfl_down(q2, 32);
        s2 += __shfl_down(s2, 16); q2 += __shfl_down(q2, 16);
        s2 += __shfl_down(s2, 8);  q2 += __shfl_down(q2, 8);
        s2 += __shfl_down(s2, 4);  q2 += __shfl_down(q2, 4);
        s2 += __shfl_down(s2, 2);  q2 += __shfl_down(q2, 2);
        s2 += __shfl_down(s2, 1);  q2 += __shfl_down(q2, 1);
        if (lane == 0){ wredS2[wv] = s2; wredQ2[wv] = q2; }
        __syncthreads();
        float S2 = 0.f, Q2 = 0.f;
        #pragma unroll
        for (int w = 0; w < 8; ++w){ S2 += wredS2[w]; Q2 += wredQ2[w]; }
        const float m2 = S2 * (1.f/1024.f);
        const float rs2 = rsqrtf(Q2*(1.f/1024.f) - m2*m2 + 1e-5f);
        union { f16 f[2]; unsigned u32v; } pk;
        #pragma unroll
        for (int k = 0; k < 2; ++k){
          float arg = fmaf(fmaf(cst[k], rs2, -m2*rs2), gcv[k], bcv[k]);
          float e = exp2f(arg * 2.885390081777927f);
          pk.f[k] = (f16)(oo[k] * fmaf(-2.f, __builtin_amdgcn_rcpf(e + 1.f), 1.f));
        }
        st_wt_u32(h1buf + (size_t)(t&1)*32768 + blk*1024 + 2*tid, pk.u32v);
        vm_drain(); __syncthreads();
        if (tid == 0) bar_arrive(ctrs + (CT_H1*NCLS + (blk & 15))*16);
      }
    }
  } else {
    // ======================= LAYER 2 =======================
    const int blk2 = blk - 128, cls = blk2 & 15, ub0 = blk2*8;
    const int colg = (g_b << 10) + ub0 + u_b;
    {
      const f16* wsrc = w2T + (size_t)colg*2048 + (part == 0 ? 1024 : 0);
      #pragma unroll
      for (int c = 0; c < 32; ++c)
        bfrag[c] = *(const f16x8*)(wsrc + c*32 + quad*8);
    }
    const float zb0 = b2v[((zc0 >> 3) << 10) + ub0 + (zc0 & 7)];
    const float zb1 = b2v[((zc1 >> 3) << 10) + ub0 + (zc1 & 7)];
    float pgv[4][2], pbv[4][2], gcv[2], bcv[2], cst[2] = {0.f, 0.f};
    if (blk2 < 32){
      #pragma unroll
      for (int k = 0; k < 2; ++k){
        const int u = 2*tid + k;
        #pragma unroll
        for (int g = 0; g < 4; ++g){
          pgv[g][k] = g2[(g << 10) + u]; pbv[g][k] = bn2[(g << 10) + u];
        }
        gcv[k] = gc2v[u]; bcv[k] = bc2v[u];
      }
    }
    __syncthreads();
    for (int t = 0; t < 768; ++t){
      // --- wait h1(t) (part1 operand) and h2(t-1) (part0 operand) ---
      if (tid < 16) spin_ge(ctrs + (CT_H1*NCLS + tid)*16, 2u*(t+1));
      else if (t > 0 && tid < 32) spin_ge(ctrs + (CT_H2*NCLS + (tid-16))*16, 2u*t);
      __syncthreads();
      if (part == 0 && t == 0){
        #pragma unroll
        for (int reg = 0; reg < 4; ++reg) zredA[wv][quad*4 + reg][r16] = 0.f;
      } else {
        const f16* hp = (part == 0)
          ? h2buf + (size_t)((t+1)&1)*32768 + (size_t)arow*1024 + quad*8
          : h1buf + (size_t)(t&1)*32768     + (size_t)arow*1024 + quad*8;
        f32x4 a = gemm32r(hp, bfrag);
        #pragma unroll
        for (int reg = 0; reg < 4; ++reg) zredA[wv][quad*4 + reg][r16] = a[reg];
      }
      __syncthreads();
      if (tid == 64) bar_arrive(ctrs + (CT_C*NCLS + cls)*16);   // h1(t) consumed
      // --- combine + biased z2 write to zbuf2 ---
      {
        float za  = zredA[zrt*2    ][zi][zc0] + zredA[4 + zrt*2    ][zi][zc0] + zb0;
        float zbv = zredA[zrt*2 + 1][zi][zc0] + zredA[4 + zrt*2 + 1][zi][zc0] + zb1;
        float* zp = zbuf2 + (size_t)zrow*4096;
        st_wt_f32(zp + ((zc0 >> 3) << 10) + ub0 + (zc0 & 7), za);
        st_wt_f32(zp + ((zc1 >> 3) << 10) + ub0 + (zc1 & 7), zbv);
      }
      vm_drain(); __syncthreads();
      if (tid == 0) bar_arrive(ctrs + (CT_A2*NCLS + cls)*16);
      // --- owner gate phase (blocks 128..159, batch row blk2) ---
      if (blk2 < 32){
        if (tid < 16) spin_ge(ctrs + (CT_A2*NCLS + tid)*16, 8u*(t+1));
        __syncthreads();
        f32x4 va, vb;
        ld_8f32(zbuf2 + (size_t)blk2*4096 + tid*8, va, vb);
        *(f32x4*)(zs + tid*8)     = va;
        *(f32x4*)(zs + tid*8 + 4) = vb;
        float s = va.x+va.y+va.z+va.w + vb.x+vb.y+vb.z+vb.w;
        float q = va.x*va.x+va.y*va.y+va.z*va.z+va.w*va.w
                + vb.x*vb.x+vb.y*vb.y+vb.z*vb.z+vb.w*vb.w;
        s += __shfl_down(s, 32); q += __shfl_down(q, 32);
        s += __shfl_down(s, 16); q += __shfl_down(q, 16);
        s += __shfl_down(s, 8);  q += __shfl_down(q, 8);
        s += __shfl_down(s, 4);  q += __shfl_down(q, 4);
        s += __shfl_down(s, 2);  q += __shfl_down(q, 2);
        s += __shfl_down(s, 1);  q += __shfl_down(q, 1);
        if (lane == 0){ wredS1[wv] = s; wredQ1[wv] = q; }
        __syncthreads();
        float S = 0.f, Q = 0.f;
        #pragma unroll
        for (int w = 0; w < 8; ++w){ S += wredS1[w]; Q += wredQ1[w]; }
        const float m1 = S * (1.f/4096.f);
        const float rs1 = rsqrtf(Q*(1.f/4096.f) - m1*m1 + 1e-5f);
        float oo[2];
        #pragma unroll
        for (int k = 0; k < 2; ++k){
          const int u = 2*tid + k;
          const float ziv = (zs[u]        - m1)*rs1*pgv[0][k] + pbv[0][k];
          const float zf  = (zs[1024 + u] - m1)*rs1*pgv[1][k] + pbv[1][k];
          const float zg  = (zs[2048 + u] - m1)*rs1*pgv[2][k] + pbv[2][k];
          const float zo  = (zs[3072 + u] - m1)*rs1*pgv[3][k] + pbv[3][k];
          cst[k] = sigf(zf)*cst[k] + sigf(ziv)*tanhf(zg);
          oo[k] = sigf(zo);
        }
        float s2 = cst[0] + cst[1], q2 = cst[0]*cst[0] + cst[1]*cst[1];
        s2 += __shfl_down(s2, 32); q2 += __shfl_down(q2, 32);
        s2 += __shfl_down(s2, 16); q2 += __shfl_down(q2, 16);
        s2 += __shfl_down(s2, 8);  q2 += __shfl_down(q2, 8);
        s2 += __shfl_down(s2, 4);  q2 += __shfl_down(q2, 4);
        s2 += __shfl_down(s2, 2);  q2 += __shfl_down(q2, 2);
        s2 += __shfl_down(s2, 1);  q2 += __shfl_down(q2, 1);
        if (lane == 0){ wredS2[wv] = s2; wredQ2[wv] = q2; }
        __syncthreads();
        float S2 = 0.f, Q2 = 0.f;
        #pragma unroll
        for (int w = 0; w < 8; ++w){ S2 += wredS2[w]; Q2 += wredQ2[w]; }
        const float m2 = S2 * (1.f/1024.f);
        const float rs2 = rsqrtf(Q2*(1.f/1024.f) - m2*m2 + 1e-5f);
        union { f16 f[2]; unsigned u32v; } pk;
        #pragma unroll
        for (int k = 0; k < 2; ++k){
          float arg = fmaf(fmaf(cst[k], rs2, -m2*rs2), gcv[k], bcv[k]);
          float e = exp2f(arg * 2.885390081777927f);
          pk.f[k] = (f16)(oo[k] * fmaf(-2.f, __builtin_amdgcn_rcpf(e + 1.f), 1.f));
        }
        st_wt_u32(h2buf + (size_t)(t&1)*32768 + blk2*1024 + 2*tid, pk.u32v);
        st_wt_u32(H2all + (size_t)(t+1)*32768 + blk2*1024 + 2*tid, pk.u32v);
        vm_drain(); __syncthreads();
        if (tid == 0) bar_arrive(ctrs + (CT_H2*NCLS + (blk2 & 15))*16);
      }
    }
  }
}

// ---------------------------------------------------------------------------
__global__ __launch_bounds__(256) void k_proj(const f16* __restrict__ H2all, const f16* __restrict__ cellin,
    const f16* __restrict__ projT, const float* __restrict__ projb, float* __restrict__ out){
  const int t = blockIdx.x, tid = threadIdx.x;
  const int lane = tid & 63, wv = tid >> 6;
  const int r16 = lane & 15, quad = lane >> 4;
  __shared__ float pred[4][32][84];
  f32x4 acc[2][5] = {};
  const f16* H2 = H2all + (size_t)(t+1)*32768;
  const f16* CI = cellin + (size_t)t*32*800;
  const int kbeg = wv*13;
  const int kend = (wv == 3) ? 49 : (kbeg + 13);
  for (int ks = kbeg; ks < kend; ++ks){
    const int k0 = ks*32 + quad*8;
    f16x8 a0, a1;
    if (ks < 32){
      a0 = *(const f16x8*)(H2 + r16*1024 + k0);
      a1 = *(const f16x8*)(H2 + (16+r16)*1024 + k0);
    } else {
      a0 = *(const f16x8*)(CI + r16*800 + 256 + (k0 - 1024));
      a1 = *(const f16x8*)(CI + (16+r16)*800 + 256 + (k0 - 1024));
    }
    f16x8 bf[5];
    #pragma unroll
    for (int nt = 0; nt < 5; ++nt)
      bf[nt] = *(const f16x8*)(projT + (size_t)(nt*16 + r16)*1568 + k0);
    #pragma unroll
    for (int nt = 0; nt < 5; ++nt){
      acc[0][nt] = MFMA_F16(a0, bf[nt], acc[0][nt]);
      acc[1][nt] = MFMA_F16(a1, bf[nt], acc[1][nt]);
    }
  }
  #pragma unroll
  for (int mt = 0; mt < 2; ++mt)
    #pragma unroll
    for (int nt = 0; nt < 5; ++nt)
      #pragma unroll
      for (int reg = 0; reg < 4; ++reg)
        pred[wv][mt*16 + quad*4 + reg][nt*16 + r16] = acc[mt][nt][reg];
  __syncthreads();
  for (int e = tid; e < 2560; e += 256){
    int m = e >> 5, b = e & 31;
    float v = pred[0][b][m] + pred[1][b][m] + pred[2][b][m] + pred[3][b][m] + projb[m];
    out[(size_t)b*61440 + (size_t)m*768 + t] = v;
  }
}

// ---------------------------------------------------------------------------
extern "C" void kernel_launch(void* const* d_in, const int* in_sizes, int n_in,
                              void* d_out, int out_size, void* d_ws, size_t ws_size,
                              hipStream_t stream)
{
  const float* duration = (const float*)d_in[0];
  const float* decoder  = (const float*)d_in[1];
  const float* pre_w1   = (const float*)d_in[3];
  const float* pre_w2   = (const float*)d_in[4];
  const float* rnn1_wx  = (const float*)d_in[5];
  const float* rnn1_wh  = (const float*)d_in[6];
  const float* rnn1_b   = (const float*)d_in[7];
  const float* rnn1_g   = (const float*)d_in[8];
  const float* rnn1_bn  = (const float*)d_in[9];
  const float* rnn1_gc  = (const float*)d_in[10];
  const float* rnn1_bc  = (const float*)d_in[11];
  const float* rnn2_wx  = (const float*)d_in[12];
  const float* rnn2_wh  = (const float*)d_in[13];
  const float* rnn2_b   = (const float*)d_in[14];
  const float* rnn2_g   = (const float*)d_in[15];
  const float* rnn2_bn  = (const float*)d_in[16];
  const float* rnn2_gc  = (const float*)d_in[17];
  const float* rnn2_bc  = (const float*)d_in[18];
  const float* proj_w   = (const float*)d_in[19];
  const float* proj_b   = (const float*)d_in[20];
  float* out = (float*)d_out;

  char* w = (char*)d_ws;
  f16* cellin = (f16*)w;      w += (size_t)24576*800*2;
  f16* wxT1   = (f16*)w;      w += (size_t)4096*800*2;
  f16* whT1   = (f16*)w;      w += (size_t)4096*1024*2;
  f16* w2T    = (f16*)w;      w += (size_t)4096*2048*2;
  f16* projT  = (f16*)w;      w += 262144;
  f16* H2all  = (f16*)w;      w += (size_t)769*32768*2;
  f16* h1buf  = (f16*)w;      w += 131072;   // 2 slots x 32x1024 f16
  f16* h2buf  = (f16*)w;      w += 131072;
  float* zbuf1 = (float*)w;   w += (size_t)32*4096*4;
  float* zbuf2 = (float*)w;   w += (size_t)32*4096*4;
  unsigned* ctrs = (unsigned*)w; w += 8192;
  const size_t need = (size_t)((char*)w - (char*)d_ws);
  if (ws_size < need){
    k_ws_report<<<(out_size + 255)/256, 256, 0, stream>>>(out, out_size, (float)(ws_size >> 20));
    return;
  }

  (void)hipMemsetAsync(ctrs, 0, 8192, stream);
  (void)hipMemsetAsync(h1buf, 0, 131072, stream);
  (void)hipMemsetAsync(h2buf, 0, 131072, stream);

  k_transpose_f16<<<dim3(4096/32, 25), 256, 0, stream>>>(rnn1_wx, wxT1, 800, 4096, 800, 0);
  k_transpose_f16<<<dim3(4096/32, 32), 256, 0, stream>>>(rnn1_wh, whT1, 1024, 4096, 1024, 0);
  k_transpose_f16<<<dim3(4096/32, 32), 256, 0, stream>>>(rnn2_wx, w2T, 1024, 4096, 2048, 0);
  k_transpose_f16<<<dim3(4096/32, 32), 256, 0, stream>>>(rnn2_wh, w2T, 1024, 4096, 2048, 1024);
  k_transpose_f16<<<dim3(3, 49), 256, 0, stream>>>(proj_w, projT, 1568, 80, 1568, 0);
  k_prenet<<<768, 256, 0, stream>>>(decoder, pre_w1, pre_w2, cellin);
  k_durfill<<<768, 256, 0, stream>>>(duration, cellin);
  k_recurrence<<<256, 512, 0, stream>>>(cellin, wxT1, whT1, w2T, H2all, h1buf, h2buf,
      zbuf1, zbuf2, ctrs,
      rnn1_b, rnn1_g, rnn1_bn, rnn1_gc, rnn1_bc,
      rnn2_b, rnn2_g, rnn2_bn, rnn2_gc, rnn2_bc);
  k_proj<<<768, 256, 0, stream>>>(H2all, cellin, projT, proj_b, out);
}

// Round 7
// 10224.699 us; speedup vs baseline: 2.8303x; 1.0674x over previous
//
#include <hip/hip_runtime.h>
#include <cstdint>
#include <cstddef>

typedef _Float16 f16;
typedef _Float16 f16x8 __attribute__((ext_vector_type(8)));
typedef float f32x4 __attribute__((ext_vector_type(4)));

#define MFMA_F16(a,b,c) __builtin_amdgcn_mfma_f32_16x16x32_f16((a),(b),(c),0,0,0)

#define LOG2E  1.4426950408889634f
#define LOG2E2 2.885390081777927f

// fast sigmoid/tanh via exp2 + rcp (same numeric family as the proven h path)
__device__ __forceinline__ float sigf(float x){
  return __builtin_amdgcn_rcpf(1.f + exp2f(-x * LOG2E));
}
__device__ __forceinline__ float tanhfast(float x){
  float e = exp2f(x * LOG2E2);
  return fmaf(-2.f, __builtin_amdgcn_rcpf(e + 1.f), 1.f);
}

__device__ __forceinline__ void st_wt_f32(float* p, float v){
  asm volatile("global_store_dword %0, %1, off sc0 sc1" :: "v"(p), "v"(v) : "memory");
}
__device__ __forceinline__ void st_wt_u32(f16* p, unsigned v){
  asm volatile("global_store_dword %0, %1, off sc0 sc1" :: "v"(p), "v"(v) : "memory");
}
__device__ __forceinline__ void st_tag(unsigned* p, unsigned v){
  asm volatile("global_store_dword %0, %1, off sc0 sc1" :: "v"(p), "v"(v) : "memory");
}
__device__ __forceinline__ void tag_wait(const unsigned* p, unsigned target){
  for (;;){
    unsigned v;
    asm volatile("global_load_dword %0, %1, off sc0 sc1\n\ts_waitcnt vmcnt(0)"
                 : "=v"(v) : "v"(p) : "memory");
    if (v >= target) return;
    __builtin_amdgcn_s_sleep(1);
  }
}
__device__ __forceinline__ void vm_drain(){ asm volatile("s_waitcnt vmcnt(0)" ::: "memory"); }

template<int N> __device__ __forceinline__ void vm_waitN(){
  asm volatile("s_waitcnt vmcnt(%0)" :: "i"(N) : "memory");
  __builtin_amdgcn_sched_barrier(0);
}

// Coherent read of 8 consecutive f32 (one 32B slice of a z row).
__device__ __forceinline__ void ld_8f32(const float* p, f32x4& a, f32x4& b){
  asm volatile(
    "global_load_dwordx4 %0, %2, off sc0 sc1\n\t"
    "global_load_dwordx4 %1, %2, off offset:16 sc0 sc1\n\t"
    "s_waitcnt vmcnt(0)"
    : "=&v"(a), "=&v"(b) : "v"(p) : "memory");
}

// Coherent batched ISSUE (no wait) of 8 consecutive 64B k-chunks of one row.
__device__ __forceinline__ void ld8_issue(const f16* p, f16x8* f){
  asm volatile(
    "global_load_dwordx4 %0, %8, off sc0 sc1\n\t"
    "global_load_dwordx4 %1, %8, off offset:64 sc0 sc1\n\t"
    "global_load_dwordx4 %2, %8, off offset:128 sc0 sc1\n\t"
    "global_load_dwordx4 %3, %8, off offset:192 sc0 sc1\n\t"
    "global_load_dwordx4 %4, %8, off offset:256 sc0 sc1\n\t"
    "global_load_dwordx4 %5, %8, off offset:320 sc0 sc1\n\t"
    "global_load_dwordx4 %6, %8, off offset:384 sc0 sc1\n\t"
    "global_load_dwordx4 %7, %8, off offset:448 sc0 sc1"
    : "=&v"(f[0]),"=&v"(f[1]),"=&v"(f[2]),"=&v"(f[3]),
      "=&v"(f[4]),"=&v"(f[5]),"=&v"(f[6]),"=&v"(f[7])
    : "v"(p) : "memory");
}

// 32-row x 32-col x K=1024 GEMM slice. A rows from coherent global, 2 batches
// of 8 loads in flight (counted vmcnt waits); B frags in registers.
__device__ __forceinline__ f32x4 gemm32r(const f16* hp, const f16x8* bfrag){
  f32x4 a = {0.f,0.f,0.f,0.f};
  f16x8 fA[8], fB[8];
  ld8_issue(hp,       fA);
  ld8_issue(hp + 256, fB);
  vm_waitN<8>();
  #pragma unroll
  for (int kk = 0; kk < 8; ++kk) a = MFMA_F16(fA[kk], bfrag[kk], a);
  ld8_issue(hp + 512, fA);
  vm_waitN<8>();
  #pragma unroll
  for (int kk = 0; kk < 8; ++kk) a = MFMA_F16(fB[kk], bfrag[8 + kk], a);
  ld8_issue(hp + 768, fB);
  vm_waitN<8>();
  #pragma unroll
  for (int kk = 0; kk < 8; ++kk) a = MFMA_F16(fA[kk], bfrag[16 + kk], a);
  vm_waitN<0>();
  #pragma unroll
  for (int kk = 0; kk < 8; ++kk) a = MFMA_F16(fB[kk], bfrag[24 + kk], a);
  return a;
}

// ---------------------------------------------------------------------------
__global__ __launch_bounds__(256) void k_transpose_f16(const float* __restrict__ src,
    f16* __restrict__ dst, int K, int N, int dstStride, int dstOff){
  const int n0 = blockIdx.x*32, k0 = blockIdx.y*32, tid = threadIdx.x;
  __shared__ float tl[32][33];
  #pragma unroll
  for (int rep = 0; rep < 4; ++rep){
    int e = rep*256 + tid; int i = e >> 5, j = e & 31;
    int k = k0 + i, n = n0 + j;
    tl[i][j] = (k < K && n < N) ? src[(size_t)k*N + n] : 0.f;
  }
  __syncthreads();
  #pragma unroll
  for (int rep = 0; rep < 4; ++rep){
    int e = rep*256 + tid; int i2 = e & 31, j2 = e >> 5;
    int n = n0 + j2, k = k0 + i2;
    if (k < K && n < N) dst[(size_t)n*dstStride + dstOff + k] = (f16)tl[i2][j2];
  }
}

// ---------------------------------------------------------------------------
__global__ __launch_bounds__(256) void k_prenet(const float* __restrict__ dec,
    const float* __restrict__ w1, const float* __restrict__ w2, f16* __restrict__ cellin){
  const int t = blockIdx.x, tid = threadIdx.x;
  __shared__ float sin_[32][81];
  __shared__ f16   w1T[256][88];
  __shared__ float x1s[32][260];
  __shared__ f16   w2c[256][72];
  __shared__ f16   xo[32][256];
  for (int e = tid; e < 32*80; e += 256){
    int i = e/80, m = e - i*80;
    sin_[i][m] = (t == 0) ? 0.f : dec[(size_t)i*61440 + (size_t)m*768 + (t-1)];
  }
  for (int e = tid; e < 80*256; e += 256){ int m = e >> 8, j = e & 255; w1T[j][m] = (f16)w1[e]; }
  __syncthreads();
  const int j = tid;
  for (int i = 0; i < 32; ++i){
    float a = 0.f;
    #pragma unroll
    for (int m8 = 0; m8 < 10; ++m8){
      f16x8 wvv = *(const f16x8*)&w1T[j][m8*8];
      #pragma unroll
      for (int l = 0; l < 8; ++l) a += (float)wvv[l] * sin_[i][m8*8 + l];
    }
    x1s[i][j] = fmaxf(a, 0.f);
  }
  __syncthreads();
  float acc2[32];
  #pragma unroll
  for (int i = 0; i < 32; ++i) acc2[i] = 0.f;
  for (int c = 0; c < 4; ++c){
    for (int e = tid; e < 64*256; e += 256){
      int kl = e >> 8, jj = e & 255;
      w2c[jj][kl] = (f16)w2[(size_t)(c*64 + kl)*256 + jj];
    }
    __syncthreads();
    f16x8 wv8[8];
    #pragma unroll
    for (int k8 = 0; k8 < 8; ++k8) wv8[k8] = *(const f16x8*)&w2c[j][k8*8];
    for (int i = 0; i < 32; ++i){
      float a = 0.f;
      #pragma unroll
      for (int k8 = 0; k8 < 8; ++k8)
        #pragma unroll
        for (int l = 0; l < 8; ++l) a += (float)wv8[k8][l]*x1s[i][c*64 + k8*8 + l];
      acc2[i] += a;
    }
    __syncthreads();
  }
  for (int i = 0; i < 32; ++i) xo[i][j] = (f16)fmaxf(acc2[i], 0.f);
  __syncthreads();
  for (int e = tid; e < 32*256; e += 256){
    int i = e >> 8, jj = e & 255;
    cellin[((size_t)t*32 + i)*800 + jj] = xo[i][jj];
  }
}

// ---------------------------------------------------------------------------
__global__ __launch_bounds__(256) void k_durfill(const float* __restrict__ dur, f16* __restrict__ cellin){
  const int t = blockIdx.x, tid = threadIdx.x;
  for (int e = tid; e < 32*544; e += 256){
    int b = e / 544, c = e - b*544;
    cellin[((size_t)t*32 + b)*800 + 256 + c] = (f16)dur[(size_t)b*417792 + (size_t)t*544 + c];
  }
}

// ---------------------------------------------------------------------------
__global__ __launch_bounds__(256) void k_ws_report(float* __restrict__ out, int n, float val){
  int i = blockIdx.x*256 + threadIdx.x;
  if (i < n) out[i] = val;
}

// ---------------------------------------------------------------------------
// Batch-owner recurrence with per-block tag synchronization (no atomics).
// Blocks 0..127 = layer-1 GEMM (8 units each), 128..255 = layer-2 GEMM;
// blocks 0..31 / 128..159 additionally OWN batch row b: read the 4096-gate
// z row, do LN->gates->c->LN->h block-locally, publish h + tag.
// Tags: writer drains data stores, __syncthreads, tid0 plain-stores t+1 to
// its own 64B line; readers spin on the tag lines in parallel (1 thread per
// line). h1buf is 4-deep; L2 consumption tags (ctag) let L1 run 3 steps
// ahead. Dependency lattice monotone -> deadlock-free.
// ---------------------------------------------------------------------------
__global__ __launch_bounds__(512, 1) void k_recurrence(
    const f16* __restrict__ cellin, const f16* __restrict__ wxT1,
    const f16* __restrict__ whT1, const f16* __restrict__ w2T,
    f16* __restrict__ H2all, f16* __restrict__ h1buf, f16* __restrict__ h2buf,
    float* __restrict__ zbuf1, float* __restrict__ zbuf2,
    unsigned* __restrict__ tags,
    const float* __restrict__ b1v,
    const float* __restrict__ g1, const float* __restrict__ bn1,
    const float* __restrict__ gc1v, const float* __restrict__ bc1v,
    const float* __restrict__ b2v,
    const float* __restrict__ g2, const float* __restrict__ bn2,
    const float* __restrict__ gc2v, const float* __restrict__ bc2v)
{
  const int tid = threadIdx.x, blk = blockIdx.x;
  const int lane = tid & 63, wv = tid >> 6;
  const int r16 = lane & 15, quad = lane >> 4;
  const int part = wv >> 2, pair = wv & 3, rt = pair >> 1, ct = pair & 1;
  const int g_b = ct*2 + (r16 >> 3), u_b = r16 & 7;   // B-frag col decode
  const int zrow = tid >> 4, zc0 = tid & 15, zc1 = (tid & 15) + 16;
  const int zrt = zrow >> 4, zi = zrow & 15;
  const int arow = rt*16 + r16;

  unsigned* ztag1 = tags;            // 128 x 16 u32 (64B lines)
  unsigned* ztag2 = tags + 2048;     // 128 x 16
  unsigned* htag1 = tags + 4096;     //  32 x 16
  unsigned* htag2 = tags + 4608;     //  32 x 16
  unsigned* ctag  = tags + 5120;     // 128 x 16

  __shared__ f16   swx[3200*8];
  __shared__ float zredA[8][16][17];
  __shared__ float zredX[2][4][16][17];
  __shared__ float zs[4096];
  __shared__ float wredS1[8], wredQ1[8], wredS2[8], wredQ2[8];

  f16x8 bfrag[32];

  if (blk < 128){
    // ======================= LAYER 1 =======================
    const int ub0 = blk*8;
    const int colg = (g_b << 10) + ub0 + u_b;
    if (part == 0){
      #pragma unroll
      for (int c = 0; c < 32; ++c)
        bfrag[c] = *(const f16x8*)(whT1 + (size_t)colg*1024 + c*32 + quad*8);
    }
    for (int idx = tid; idx < 3200; idx += 512){
      int l = idx & 15, q = (idx >> 4) & 3, v = idx >> 6;
      int c = v % 25, ctx = v / 25;
      int gg = ctx*2 + (l >> 3), uu = l & 7;
      int cg = (gg << 10) + ub0 + uu;
      *(f16x8*)(swx + idx*8) = *(const f16x8*)(wxT1 + (size_t)cg*800 + c*32 + q*8);
    }
    const float zb0 = b1v[((zc0 >> 3) << 10) + ub0 + (zc0 & 7)];
    const float zb1 = b1v[((zc1 >> 3) << 10) + ub0 + (zc1 & 7)];
    // owner (batch row = blk) per-unit params, 2 units per thread
    float pgv[4][2], pbv[4][2], gcv[2], bcv[2], cst[2] = {0.f, 0.f};
    if (blk < 32){
      #pragma unroll
      for (int k = 0; k < 2; ++k){
        const int u = 2*tid + k;
        #pragma unroll
        for (int g = 0; g < 4; ++g){
          pgv[g][k] = g1[(g << 10) + u]; pbv[g][k] = bn1[(g << 10) + u];
        }
        gcv[k] = gc1v[u]; bcv[k] = bc1v[u];
      }
    }
    __syncthreads();
    // prologue: x-GEMM for t=0 into zredX slot 0
    if (part == 1){
      f32x4 a = {0.f,0.f,0.f,0.f};
      const f16* ap = cellin + (size_t)arow*800 + quad*8;
      for (int c = 0; c < 25; ++c){
        f16x8 av = *(const f16x8*)(ap + c*32);
        f16x8 bx = *(const f16x8*)(swx + (size_t)(((ct*25 + c)*4 + quad)*16 + r16)*8);
        a = MFMA_F16(av, bx, a);
      }
      #pragma unroll
      for (int reg = 0; reg < 4; ++reg) zredX[0][wv-4][quad*4 + reg][r16] = a[reg];
    }
    for (int t = 0; t < 768; ++t){
      // --- wait h1(t-1); GEMM phase: part0 h-GEMM || part1 x-filler(t+1) ---
      if (t > 0 && tid < 32) tag_wait(htag1 + tid*16, (unsigned)t);
      __syncthreads();
      if (part == 0){
        if (t > 0){
          const f16* hp = h1buf + (size_t)((t-1)&3)*32768 + (size_t)arow*1024 + quad*8;
          f32x4 a = gemm32r(hp, bfrag);
          #pragma unroll
          for (int reg = 0; reg < 4; ++reg) zredA[wv][quad*4 + reg][r16] = a[reg];
        } else {
          #pragma unroll
          for (int reg = 0; reg < 4; ++reg) zredA[wv][quad*4 + reg][r16] = 0.f;
        }
      } else if (t < 767){
        f32x4 a = {0.f,0.f,0.f,0.f};
        const f16* ap = cellin + (size_t)(t+1)*25600 + (size_t)arow*800 + quad*8;
        for (int c = 0; c < 25; ++c){
          f16x8 av = *(const f16x8*)(ap + c*32);
          f16x8 bx = *(const f16x8*)(swx + (size_t)(((ct*25 + c)*4 + quad)*16 + r16)*8);
          a = MFMA_F16(av, bx, a);
        }
        #pragma unroll
        for (int reg = 0; reg < 4; ++reg) zredX[(t+1)&1][wv-4][quad*4 + reg][r16] = a[reg];
      }
      __syncthreads();
      // --- combine + biased z write to zbuf1 ---
      {
        const int xs = t & 1;
        float za  = zredA[zrt*2    ][zi][zc0] + zredX[xs][zrt*2    ][zi][zc0] + zb0;
        float zbv = zredA[zrt*2 + 1][zi][zc0] + zredX[xs][zrt*2 + 1][zi][zc0] + zb1;
        float* zp = zbuf1 + (size_t)zrow*4096;
        st_wt_f32(zp + ((zc0 >> 3) << 10) + ub0 + (zc0 & 7), za);
        st_wt_f32(zp + ((zc1 >> 3) << 10) + ub0 + (zc1 & 7), zbv);
      }
      vm_drain(); __syncthreads();
      if (tid == 0) st_tag(ztag1 + blk*16, (unsigned)(t+1));
      // --- owner gate phase (blocks 0..31) ---
      if (blk < 32){
        if (tid < 128) tag_wait(ztag1 + tid*16, (unsigned)(t+1));
        else if (t >= 4 && tid < 256) tag_wait(ctag + (tid-128)*16, (unsigned)(t-3));
        __syncthreads();
        f32x4 va, vb;
        ld_8f32(zbuf1 + (size_t)blk*4096 + tid*8, va, vb);
        *(f32x4*)(zs + tid*8)     = va;
        *(f32x4*)(zs + tid*8 + 4) = vb;
        float s = va.x+va.y+va.z+va.w + vb.x+vb.y+vb.z+vb.w;
        float q = va.x*va.x+va.y*va.y+va.z*va.z+va.w*va.w
                + vb.x*vb.x+vb.y*vb.y+vb.z*vb.z+vb.w*vb.w;
        s += __shfl_down(s, 32); q += __shfl_down(q, 32);
        s += __shfl_down(s, 16); q += __shfl_down(q, 16);
        s += __shfl_down(s, 8);  q += __shfl_down(q, 8);
        s += __shfl_down(s, 4);  q += __shfl_down(q, 4);
        s += __shfl_down(s, 2);  q += __shfl_down(q, 2);
        s += __shfl_down(s, 1);  q += __shfl_down(q, 1);
        if (lane == 0){ wredS1[wv] = s; wredQ1[wv] = q; }
        __syncthreads();
        float S = 0.f, Q = 0.f;
        #pragma unroll
        for (int w = 0; w < 8; ++w){ S += wredS1[w]; Q += wredQ1[w]; }
        const float m1 = S * (1.f/4096.f);
        const float rs1 = rsqrtf(Q*(1.f/4096.f) - m1*m1 + 1e-5f);
        float oo[2];
        #pragma unroll
        for (int k = 0; k < 2; ++k){
          const int u = 2*tid + k;
          const float ziv = (zs[u]        - m1)*rs1*pgv[0][k] + pbv[0][k];
          const float zf  = (zs[1024 + u] - m1)*rs1*pgv[1][k] + pbv[1][k];
          const float zg  = (zs[2048 + u] - m1)*rs1*pgv[2][k] + pbv[2][k];
          const float zo  = (zs[3072 + u] - m1)*rs1*pgv[3][k] + pbv[3][k];
          cst[k] = sigf(zf)*cst[k] + sigf(ziv)*tanhfast(zg);
          oo[k] = sigf(zo);
        }
        float s2 = cst[0] + cst[1], q2 = cst[0]*cst[0] + cst[1]*cst[1];
        s2 += __shfl_down(s2, 32); q2 += __shfl_down(q2, 32);
        s2 += __shfl_down(s2, 16); q2 += __shfl_down(q2, 16);
        s2 += __shfl_down(s2, 8);  q2 += __shfl_down(q2, 8);
        s2 += __shfl_down(s2, 4);  q2 += __shfl_down(q2, 4);
        s2 += __shfl_down(s2, 2);  q2 += __shfl_down(q2, 2);
        s2 += __shfl_down(s2, 1);  q2 += __shfl_down(q2, 1);
        if (lane == 0){ wredS2[wv] = s2; wredQ2[wv] = q2; }
        __syncthreads();
        float S2 = 0.f, Q2 = 0.f;
        #pragma unroll
        for (int w = 0; w < 8; ++w){ S2 += wredS2[w]; Q2 += wredQ2[w]; }
        const float m2 = S2 * (1.f/1024.f);
        const float rs2 = rsqrtf(Q2*(1.f/1024.f) - m2*m2 + 1e-5f);
        union { f16 f[2]; unsigned u32v; } pk;
        #pragma unroll
        for (int k = 0; k < 2; ++k){
          float arg = fmaf(fmaf(cst[k], rs2, -m2*rs2), gcv[k], bcv[k]);
          float e = exp2f(arg * LOG2E2);
          pk.f[k] = (f16)(oo[k] * fmaf(-2.f, __builtin_amdgcn_rcpf(e + 1.f), 1.f));
        }
        st_wt_u32(h1buf + (size_t)(t&3)*32768 + blk*1024 + 2*tid, pk.u32v);
        vm_drain(); __syncthreads();
        if (tid == 0) st_tag(htag1 + blk*16, (unsigned)(t+1));
      }
    }
  } else {
    // ======================= LAYER 2 =======================
    const int blk2 = blk - 128, ub0 = blk2*8;
    const int colg = (g_b << 10) + ub0 + u_b;
    {
      const f16* wsrc = w2T + (size_t)colg*2048 + (part == 0 ? 1024 : 0);
      #pragma unroll
      for (int c = 0; c < 32; ++c)
        bfrag[c] = *(const f16x8*)(wsrc + c*32 + quad*8);
    }
    const float zb0 = b2v[((zc0 >> 3) << 10) + ub0 + (zc0 & 7)];
    const float zb1 = b2v[((zc1 >> 3) << 10) + ub0 + (zc1 & 7)];
    float pgv[4][2], pbv[4][2], gcv[2], bcv[2], cst[2] = {0.f, 0.f};
    if (blk2 < 32){
      #pragma unroll
      for (int k = 0; k < 2; ++k){
        const int u = 2*tid + k;
        #pragma unroll
        for (int g = 0; g < 4; ++g){
          pgv[g][k] = g2[(g << 10) + u]; pbv[g][k] = bn2[(g << 10) + u];
        }
        gcv[k] = gc2v[u]; bcv[k] = bc2v[u];
      }
    }
    __syncthreads();
    for (int t = 0; t < 768; ++t){
      // --- wait h1(t) (part1 operand) and h2(t-1) (part0 operand) ---
      if (tid < 32) tag_wait(htag1 + tid*16, (unsigned)(t+1));
      else if (t > 0 && tid < 64) tag_wait(htag2 + (tid-32)*16, (unsigned)t);
      __syncthreads();
      if (part == 0 && t == 0){
        #pragma unroll
        for (int reg = 0; reg < 4; ++reg) zredA[wv][quad*4 + reg][r16] = 0.f;
      } else {
        const f16* hp = (part == 0)
          ? h2buf + (size_t)((t+1)&1)*32768 + (size_t)arow*1024 + quad*8
          : h1buf + (size_t)(t&3)*32768     + (size_t)arow*1024 + quad*8;
        f32x4 a = gemm32r(hp, bfrag);
        #pragma unroll
        for (int reg = 0; reg < 4; ++reg) zredA[wv][quad*4 + reg][r16] = a[reg];
      }
      __syncthreads();
      if (tid == 0) st_tag(ctag + blk2*16, (unsigned)(t+1));   // h1(t) consumed
      // --- combine + biased z2 write to zbuf2 ---
      {
        float za  = zredA[zrt*2    ][zi][zc0] + zredA[4 + zrt*2    ][zi][zc0] + zb0;
        float zbv = zredA[zrt*2 + 1][zi][zc0] + zredA[4 + zrt*2 + 1][zi][zc0] + zb1;
        float* zp = zbuf2 + (size_t)zrow*4096;
        st_wt_f32(zp + ((zc0 >> 3) << 10) + ub0 + (zc0 & 7), za);
        st_wt_f32(zp + ((zc1 >> 3) << 10) + ub0 + (zc1 & 7), zbv);
      }
      vm_drain(); __syncthreads();
      if (tid == 0) st_tag(ztag2 + blk2*16, (unsigned)(t+1));
      // --- owner gate phase (blocks 128..159, batch row blk2) ---
      if (blk2 < 32){
        if (tid < 128) tag_wait(ztag2 + tid*16, (unsigned)(t+1));
        __syncthreads();
        f32x4 va, vb;
        ld_8f32(zbuf2 + (size_t)blk2*4096 + tid*8, va, vb);
        *(f32x4*)(zs + tid*8)     = va;
        *(f32x4*)(zs + tid*8 + 4) = vb;
        float s = va.x+va.y+va.z+va.w + vb.x+vb.y+vb.z+vb.w;
        float q = va.x*va.x+va.y*va.y+va.z*va.z+va.w*va.w
                + vb.x*vb.x+vb.y*vb.y+vb.z*vb.z+vb.w*vb.w;
        s += __shfl_down(s, 32); q += __shfl_down(q, 32);
        s += __shfl_down(s, 16); q += __shfl_down(q, 16);
        s += __shfl_down(s, 8);  q += __shfl_down(q, 8);
        s += __shfl_down(s, 4);  q += __shfl_down(q, 4);
        s += __shfl_down(s, 2);  q += __shfl_down(q, 2);
        s += __shfl_down(s, 1);  q += __shfl_down(q, 1);
        if (lane == 0){ wredS1[wv] = s; wredQ1[wv] = q; }
        __syncthreads();
        float S = 0.f, Q = 0.f;
        #pragma unroll
        for (int w = 0; w < 8; ++w){ S += wredS1[w]; Q += wredQ1[w]; }
        const float m1 = S * (1.f/4096.f);
        const float rs1 = rsqrtf(Q*(1.f/4096.f) - m1*m1 + 1e-5f);
        float oo[2];
        #pragma unroll
        for (int k = 0; k < 2; ++k){
          const int u = 2*tid + k;
          const float ziv = (zs[u]        - m1)*rs1*pgv[0][k] + pbv[0][k];
          const float zf  = (zs[1024 + u] - m1)*rs1*pgv[1][k] + pbv[1][k];
          const float zg  = (zs[2048 + u] - m1)*rs1*pgv[2][k] + pbv[2][k];
          const float zo  = (zs[3072 + u] - m1)*rs1*pgv[3][k] + pbv[3][k];
          cst[k] = sigf(zf)*cst[k] + sigf(ziv)*tanhfast(zg);
          oo[k] = sigf(zo);
        }
        float s2 = cst[0] + cst[1], q2 = cst[0]*cst[0] + cst[1]*cst[1];
        s2 += __shfl_down(s2, 32); q2 += __shfl_down(q2, 32);
        s2 += __shfl_down(s2, 16); q2 += __shfl_down(q2, 16);
        s2 += __shfl_down(s2, 8);  q2 += __shfl_down(q2, 8);
        s2 += __shfl_down(s2, 4);  q2 += __shfl_down(q2, 4);
        s2 += __shfl_down(s2, 2);  q2 += __shfl_down(q2, 2);
        s2 += __shfl_down(s2, 1);  q2 += __shfl_down(q2, 1);
        if (lane == 0){ wredS2[wv] = s2; wredQ2[wv] = q2; }
        __syncthreads();
        float S2 = 0.f, Q2 = 0.f;
        #pragma unroll
        for (int w = 0; w < 8; ++w){ S2 += wredS2[w]; Q2 += wredQ2[w]; }
        const float m2 = S2 * (1.f/1024.f);
        const float rs2 = rsqrtf(Q2*(1.f/1024.f) - m2*m2 + 1e-5f);
        union { f16 f[2]; unsigned u32v; } pk;
        #pragma unroll
        for (int k = 0; k < 2; ++k){
          float arg = fmaf(fmaf(cst[k], rs2, -m2*rs2), gcv[k], bcv[k]);
          float e = exp2f(arg * LOG2E2);
          pk.f[k] = (f16)(oo[k] * fmaf(-2.f, __builtin_amdgcn_rcpf(e + 1.f), 1.f));
        }
        st_wt_u32(h2buf + (size_t)(t&1)*32768 + blk2*1024 + 2*tid, pk.u32v);
        st_wt_u32(H2all + (size_t)(t+1)*32768 + blk2*1024 + 2*tid, pk.u32v);
        vm_drain(); __syncthreads();
        if (tid == 0) st_tag(htag2 + blk2*16, (unsigned)(t+1));
      }
    }
  }
}

// ---------------------------------------------------------------------------
__global__ __launch_bounds__(256) void k_proj(const f16* __restrict__ H2all, const f16* __restrict__ cellin,
    const f16* __restrict__ projT, const float* __restrict__ projb, float* __restrict__ out){
  const int t = blockIdx.x, tid = threadIdx.x;
  const int lane = tid & 63, wv = tid >> 6;
  const int r16 = lane & 15, quad = lane >> 4;
  __shared__ float pred[4][32][84];
  f32x4 acc[2][5] = {};
  const f16* H2 = H2all + (size_t)(t+1)*32768;
  const f16* CI = cellin + (size_t)t*32*800;
  const int kbeg = wv*13;
  const int kend = (wv == 3) ? 49 : (kbeg + 13);
  for (int ks = kbeg; ks < kend; ++ks){
    const int k0 = ks*32 + quad*8;
    f16x8 a0, a1;
    if (ks < 32){
      a0 = *(const f16x8*)(H2 + r16*1024 + k0);
      a1 = *(const f16x8*)(H2 + (16+r16)*1024 + k0);
    } else {
      a0 = *(const f16x8*)(CI + r16*800 + 256 + (k0 - 1024));
      a1 = *(const f16x8*)(CI + (16+r16)*800 + 256 + (k0 - 1024));
    }
    f16x8 bf[5];
    #pragma unroll
    for (int nt = 0; nt < 5; ++nt)
      bf[nt] = *(const f16x8*)(projT + (size_t)(nt*16 + r16)*1568 + k0);
    #pragma unroll
    for (int nt = 0; nt < 5; ++nt){
      acc[0][nt] = MFMA_F16(a0, bf[nt], acc[0][nt]);
      acc[1][nt] = MFMA_F16(a1, bf[nt], acc[1][nt]);
    }
  }
  #pragma unroll
  for (int mt = 0; mt < 2; ++mt)
    #pragma unroll
    for (int nt = 0; nt < 5; ++nt)
      #pragma unroll
      for (int reg = 0; reg < 4; ++reg)
        pred[wv][mt*16 + quad*4 + reg][nt*16 + r16] = acc[mt][nt][reg];
  __syncthreads();
  for (int e = tid; e < 2560; e += 256){
    int m = e >> 5, b = e & 31;
    float v = pred[0][b][m] + pred[1][b][m] + pred[2][b][m] + pred[3][b][m] + projb[m];
    out[(size_t)b*61440 + (size_t)m*768 + t] = v;
  }
}

// ---------------------------------------------------------------------------
extern "C" void kernel_launch(void* const* d_in, const int* in_sizes, int n_in,
                              void* d_out, int out_size, void* d_ws, size_t ws_size,
                              hipStream_t stream)
{
  const float* duration = (const float*)d_in[0];
  const float* decoder  = (const float*)d_in[1];
  const float* pre_w1   = (const float*)d_in[3];
  const float* pre_w2   = (const float*)d_in[4];
  const float* rnn1_wx  = (const float*)d_in[5];
  const float* rnn1_wh  = (const float*)d_in[6];
  const float* rnn1_b   = (const float*)d_in[7];
  const float* rnn1_g   = (const float*)d_in[8];
  const float* rnn1_bn  = (const float*)d_in[9];
  const float* rnn1_gc  = (const float*)d_in[10];
  const float* rnn1_bc  = (const float*)d_in[11];
  const float* rnn2_wx  = (const float*)d_in[12];
  const float* rnn2_wh  = (const float*)d_in[13];
  const float* rnn2_b   = (const float*)d_in[14];
  const float* rnn2_g   = (const float*)d_in[15];
  const float* rnn2_bn  = (const float*)d_in[16];
  const float* rnn2_gc  = (const float*)d_in[17];
  const float* rnn2_bc  = (const float*)d_in[18];
  const float* proj_w   = (const float*)d_in[19];
  const float* proj_b   = (const float*)d_in[20];
  float* out = (float*)d_out;

  char* w = (char*)d_ws;
  f16* cellin = (f16*)w;      w += (size_t)24576*800*2;
  f16* wxT1   = (f16*)w;      w += (size_t)4096*800*2;
  f16* whT1   = (f16*)w;      w += (size_t)4096*1024*2;
  f16* w2T    = (f16*)w;      w += (size_t)4096*2048*2;
  f16* projT  = (f16*)w;      w += 262144;
  f16* H2all  = (f16*)w;      w += (size_t)769*32768*2;
  f16* h1buf  = (f16*)w;      w += 262144;   // 4 slots x 32x1024 f16
  f16* h2buf  = (f16*)w;      w += 131072;   // 2 slots
  float* zbuf1 = (float*)w;   w += (size_t)32*4096*4;
  float* zbuf2 = (float*)w;   w += (size_t)32*4096*4;
  unsigned* tags = (unsigned*)w; w += 28672;
  const size_t need = (size_t)((char*)w - (char*)d_ws);
  if (ws_size < need){
    k_ws_report<<<(out_size + 255)/256, 256, 0, stream>>>(out, out_size, (float)(ws_size >> 20));
    return;
  }

  (void)hipMemsetAsync(tags, 0, 28672, stream);
  (void)hipMemsetAsync(h1buf, 0, 262144, stream);
  (void)hipMemsetAsync(h2buf, 0, 131072, stream);

  k_transpose_f16<<<dim3(4096/32, 25), 256, 0, stream>>>(rnn1_wx, wxT1, 800, 4096, 800, 0);
  k_transpose_f16<<<dim3(4096/32, 32), 256, 0, stream>>>(rnn1_wh, whT1, 1024, 4096, 1024, 0);
  k_transpose_f16<<<dim3(4096/32, 32), 256, 0, stream>>>(rnn2_wx, w2T, 1024, 4096, 2048, 0);
  k_transpose_f16<<<dim3(4096/32, 32), 256, 0, stream>>>(rnn2_wh, w2T, 1024, 4096, 2048, 1024);
  k_transpose_f16<<<dim3(3, 49), 256, 0, stream>>>(proj_w, projT, 1568, 80, 1568, 0);
  k_prenet<<<768, 256, 0, stream>>>(decoder, pre_w1, pre_w2, cellin);
  k_durfill<<<768, 256, 0, stream>>>(duration, cellin);
  k_recurrence<<<256, 512, 0, stream>>>(cellin, wxT1, whT1, w2T, H2all, h1buf, h2buf,
      zbuf1, zbuf2, tags,
      rnn1_b, rnn1_g, rnn1_bn, rnn1_gc, rnn1_bc,
      rnn2_b, rnn2_g, rnn2_bn, rnn2_gc, rnn2_bc);
  k_proj<<<768, 256, 0, stream>>>(H2all, cellin, projT, proj_b, out);
}

// Round 8
// 9726.495 us; speedup vs baseline: 2.9753x; 1.0512x over previous
//
#include <hip/hip_runtime.h>
#include <cstdint>
#include <cstddef>

typedef _Float16 f16;
typedef _Float16 f16x8 __attribute__((ext_vector_type(8)));
typedef float f32x4 __attribute__((ext_vector_type(4)));

#define MFMA_F16(a,b,c) __builtin_amdgcn_mfma_f32_16x16x32_f16((a),(b),(c),0,0,0)

#define LOG2E  1.4426950408889634f
#define LOG2E2 2.885390081777927f

// fast sigmoid/tanh via exp2 + rcp (same numeric family as the proven h path)
__device__ __forceinline__ float sigf(float x){
  return __builtin_amdgcn_rcpf(1.f + exp2f(-x * LOG2E));
}
__device__ __forceinline__ float tanhfast(float x){
  float e = exp2f(x * LOG2E2);
  return fmaf(-2.f, __builtin_amdgcn_rcpf(e + 1.f), 1.f);
}

__device__ __forceinline__ void st_wt_f32(float* p, float v){
  asm volatile("global_store_dword %0, %1, off sc0 sc1" :: "v"(p), "v"(v) : "memory");
}
__device__ __forceinline__ void st_wt_u32(f16* p, unsigned v){
  asm volatile("global_store_dword %0, %1, off sc0 sc1" :: "v"(p), "v"(v) : "memory");
}
__device__ __forceinline__ void st_tag(unsigned* p, unsigned v){
  asm volatile("global_store_dword %0, %1, off sc0 sc1" :: "v"(p), "v"(v) : "memory");
}
__device__ __forceinline__ void tag_wait(const unsigned* p, unsigned target){
  for (;;){
    unsigned v;
    asm volatile("global_load_dword %0, %1, off sc0 sc1\n\ts_waitcnt vmcnt(0)"
                 : "=v"(v) : "v"(p) : "memory");
    if (v >= target) return;
    __builtin_amdgcn_s_sleep(1);
  }
}
__device__ __forceinline__ void vm_drain(){ asm volatile("s_waitcnt vmcnt(0)" ::: "memory"); }

template<int N> __device__ __forceinline__ void vm_waitN(){
  asm volatile("s_waitcnt vmcnt(%0)" :: "i"(N) : "memory");
  __builtin_amdgcn_sched_barrier(0);
}

// Coherent read of 8 consecutive f32 (one 32B slice of a z row).
__device__ __forceinline__ void ld_8f32(const float* p, f32x4& a, f32x4& b){
  asm volatile(
    "global_load_dwordx4 %0, %2, off sc0 sc1\n\t"
    "global_load_dwordx4 %1, %2, off offset:16 sc0 sc1\n\t"
    "s_waitcnt vmcnt(0)"
    : "=&v"(a), "=&v"(b) : "v"(p) : "memory");
}

// Coherent batched ISSUE (no wait) of 8 consecutive 64B k-chunks of one row.
__device__ __forceinline__ void ld8_issue(const f16* p, f16x8* f){
  asm volatile(
    "global_load_dwordx4 %0, %8, off sc0 sc1\n\t"
    "global_load_dwordx4 %1, %8, off offset:64 sc0 sc1\n\t"
    "global_load_dwordx4 %2, %8, off offset:128 sc0 sc1\n\t"
    "global_load_dwordx4 %3, %8, off offset:192 sc0 sc1\n\t"
    "global_load_dwordx4 %4, %8, off offset:256 sc0 sc1\n\t"
    "global_load_dwordx4 %5, %8, off offset:320 sc0 sc1\n\t"
    "global_load_dwordx4 %6, %8, off offset:384 sc0 sc1\n\t"
    "global_load_dwordx4 %7, %8, off offset:448 sc0 sc1"
    : "=&v"(f[0]),"=&v"(f[1]),"=&v"(f[2]),"=&v"(f[3]),
      "=&v"(f[4]),"=&v"(f[5]),"=&v"(f[6]),"=&v"(f[7])
    : "v"(p) : "memory");
}

// 32-row x 32-col x K=1024 GEMM slice. A rows from coherent global, 2 batches
// of 8 loads in flight (counted vmcnt waits); B frags in registers.
__device__ __forceinline__ f32x4 gemm32r(const f16* hp, const f16x8* bfrag){
  f32x4 a = {0.f,0.f,0.f,0.f};
  f16x8 fA[8], fB[8];
  ld8_issue(hp,       fA);
  ld8_issue(hp + 256, fB);
  vm_waitN<8>();
  #pragma unroll
  for (int kk = 0; kk < 8; ++kk) a = MFMA_F16(fA[kk], bfrag[kk], a);
  ld8_issue(hp + 512, fA);
  vm_waitN<8>();
  #pragma unroll
  for (int kk = 0; kk < 8; ++kk) a = MFMA_F16(fB[kk], bfrag[8 + kk], a);
  ld8_issue(hp + 768, fB);
  vm_waitN<8>();
  #pragma unroll
  for (int kk = 0; kk < 8; ++kk) a = MFMA_F16(fA[kk], bfrag[16 + kk], a);
  vm_waitN<0>();
  #pragma unroll
  for (int kk = 0; kk < 8; ++kk) a = MFMA_F16(fB[kk], bfrag[24 + kk], a);
  return a;
}

// ---------------------------------------------------------------------------
__global__ __launch_bounds__(256) void k_transpose_f16(const float* __restrict__ src,
    f16* __restrict__ dst, int K, int N, int dstStride, int dstOff){
  const int n0 = blockIdx.x*32, k0 = blockIdx.y*32, tid = threadIdx.x;
  __shared__ float tl[32][33];
  #pragma unroll
  for (int rep = 0; rep < 4; ++rep){
    int e = rep*256 + tid; int i = e >> 5, j = e & 31;
    int k = k0 + i, n = n0 + j;
    tl[i][j] = (k < K && n < N) ? src[(size_t)k*N + n] : 0.f;
  }
  __syncthreads();
  #pragma unroll
  for (int rep = 0; rep < 4; ++rep){
    int e = rep*256 + tid; int i2 = e & 31, j2 = e >> 5;
    int n = n0 + j2, k = k0 + i2;
    if (k < K && n < N) dst[(size_t)n*dstStride + dstOff + k] = (f16)tl[i2][j2];
  }
}

// ---------------------------------------------------------------------------
__global__ __launch_bounds__(256) void k_prenet(const float* __restrict__ dec,
    const float* __restrict__ w1, const float* __restrict__ w2, f16* __restrict__ cellin){
  const int t = blockIdx.x, tid = threadIdx.x;
  __shared__ float sin_[32][81];
  __shared__ f16   w1T[256][88];
  __shared__ float x1s[32][260];
  __shared__ f16   w2c[256][72];
  __shared__ f16   xo[32][256];
  for (int e = tid; e < 32*80; e += 256){
    int i = e/80, m = e - i*80;
    sin_[i][m] = (t == 0) ? 0.f : dec[(size_t)i*61440 + (size_t)m*768 + (t-1)];
  }
  for (int e = tid; e < 80*256; e += 256){ int m = e >> 8, j = e & 255; w1T[j][m] = (f16)w1[e]; }
  __syncthreads();
  const int j = tid;
  for (int i = 0; i < 32; ++i){
    float a = 0.f;
    #pragma unroll
    for (int m8 = 0; m8 < 10; ++m8){
      f16x8 wvv = *(const f16x8*)&w1T[j][m8*8];
      #pragma unroll
      for (int l = 0; l < 8; ++l) a += (float)wvv[l] * sin_[i][m8*8 + l];
    }
    x1s[i][j] = fmaxf(a, 0.f);
  }
  __syncthreads();
  float acc2[32];
  #pragma unroll
  for (int i = 0; i < 32; ++i) acc2[i] = 0.f;
  for (int c = 0; c < 4; ++c){
    for (int e = tid; e < 64*256; e += 256){
      int kl = e >> 8, jj = e & 255;
      w2c[jj][kl] = (f16)w2[(size_t)(c*64 + kl)*256 + jj];
    }
    __syncthreads();
    f16x8 wv8[8];
    #pragma unroll
    for (int k8 = 0; k8 < 8; ++k8) wv8[k8] = *(const f16x8*)&w2c[j][k8*8];
    for (int i = 0; i < 32; ++i){
      float a = 0.f;
      #pragma unroll
      for (int k8 = 0; k8 < 8; ++k8)
        #pragma unroll
        for (int l = 0; l < 8; ++l) a += (float)wv8[k8][l]*x1s[i][c*64 + k8*8 + l];
      acc2[i] += a;
    }
    __syncthreads();
  }
  for (int i = 0; i < 32; ++i) xo[i][j] = (f16)fmaxf(acc2[i], 0.f);
  __syncthreads();
  for (int e = tid; e < 32*256; e += 256){
    int i = e >> 8, jj = e & 255;
    cellin[((size_t)t*32 + i)*800 + jj] = xo[i][jj];
  }
}

// ---------------------------------------------------------------------------
__global__ __launch_bounds__(256) void k_durfill(const float* __restrict__ dur, f16* __restrict__ cellin){
  const int t = blockIdx.x, tid = threadIdx.x;
  for (int e = tid; e < 32*544; e += 256){
    int b = e / 544, c = e - b*544;
    cellin[((size_t)t*32 + b)*800 + 256 + c] = (f16)dur[(size_t)b*417792 + (size_t)t*544 + c];
  }
}

// ---------------------------------------------------------------------------
__global__ __launch_bounds__(256) void k_ws_report(float* __restrict__ out, int n, float val){
  int i = blockIdx.x*256 + threadIdx.x;
  if (i < n) out[i] = val;
}

// ---------------------------------------------------------------------------
// Batch-owner recurrence with PER-CONSUMER-LANE tag gating.
// Every consumer touches exactly one producer's line:
//   GEMM lane (A-row arow)  <- h row arow  <- owner block arow's tag
//   owner thread tid (z slice tid*8..+8) <- GEMM block (tid&127)'s tag
// so each lane tag_waits its own producer then loads immediately; straggler
// detection overlaps with ready-data reads, and the block-wide max moves to
// the existing LDS-reduce barrier. Buffer reuse orderings preserved
// (zbuf(t+1) writes are behind owner's z(t) read via htag(t) -> GEMM(t+1)).
// ---------------------------------------------------------------------------
__global__ __launch_bounds__(512, 1) void k_recurrence(
    const f16* __restrict__ cellin, const f16* __restrict__ wxT1,
    const f16* __restrict__ whT1, const f16* __restrict__ w2T,
    f16* __restrict__ H2all, f16* __restrict__ h1buf, f16* __restrict__ h2buf,
    float* __restrict__ zbuf1, float* __restrict__ zbuf2,
    unsigned* __restrict__ tags,
    const float* __restrict__ b1v,
    const float* __restrict__ g1, const float* __restrict__ bn1,
    const float* __restrict__ gc1v, const float* __restrict__ bc1v,
    const float* __restrict__ b2v,
    const float* __restrict__ g2, const float* __restrict__ bn2,
    const float* __restrict__ gc2v, const float* __restrict__ bc2v)
{
  const int tid = threadIdx.x, blk = blockIdx.x;
  const int lane = tid & 63, wv = tid >> 6;
  const int r16 = lane & 15, quad = lane >> 4;
  const int part = wv >> 2, pair = wv & 3, rt = pair >> 1, ct = pair & 1;
  const int g_b = ct*2 + (r16 >> 3), u_b = r16 & 7;   // B-frag col decode
  const int zrow = tid >> 4, zc0 = tid & 15, zc1 = (tid & 15) + 16;
  const int zrt = zrow >> 4, zi = zrow & 15;
  const int arow = rt*16 + r16;

  unsigned* ztag1 = tags;            // 128 x 16 u32 (64B lines)
  unsigned* ztag2 = tags + 2048;     // 128 x 16
  unsigned* htag1 = tags + 4096;     //  32 x 16
  unsigned* htag2 = tags + 4608;     //  32 x 16
  unsigned* ctag  = tags + 5120;     // 128 x 16

  __shared__ f16   swx[3200*8];
  __shared__ float zredA[8][16][17];
  __shared__ float zredX[2][4][16][17];
  __shared__ float zs[4096];
  __shared__ float wredS1[8], wredQ1[8], wredS2[8], wredQ2[8];

  f16x8 bfrag[32];

  if (blk < 128){
    // ======================= LAYER 1 =======================
    const int ub0 = blk*8;
    const int colg = (g_b << 10) + ub0 + u_b;
    if (part == 0){
      #pragma unroll
      for (int c = 0; c < 32; ++c)
        bfrag[c] = *(const f16x8*)(whT1 + (size_t)colg*1024 + c*32 + quad*8);
    }
    for (int idx = tid; idx < 3200; idx += 512){
      int l = idx & 15, q = (idx >> 4) & 3, v = idx >> 6;
      int c = v % 25, ctx = v / 25;
      int gg = ctx*2 + (l >> 3), uu = l & 7;
      int cg = (gg << 10) + ub0 + uu;
      *(f16x8*)(swx + idx*8) = *(const f16x8*)(wxT1 + (size_t)cg*800 + c*32 + q*8);
    }
    const float zb0 = b1v[((zc0 >> 3) << 10) + ub0 + (zc0 & 7)];
    const float zb1 = b1v[((zc1 >> 3) << 10) + ub0 + (zc1 & 7)];
    // owner (batch row = blk) per-unit params, 2 units per thread
    float pgv[4][2], pbv[4][2], gcv[2], bcv[2], cst[2] = {0.f, 0.f};
    if (blk < 32){
      #pragma unroll
      for (int k = 0; k < 2; ++k){
        const int u = 2*tid + k;
        #pragma unroll
        for (int g = 0; g < 4; ++g){
          pgv[g][k] = g1[(g << 10) + u]; pbv[g][k] = bn1[(g << 10) + u];
        }
        gcv[k] = gc1v[u]; bcv[k] = bc1v[u];
      }
    }
    __syncthreads();
    // prologue: x-GEMM for t=0 into zredX slot 0
    if (part == 1){
      f32x4 a = {0.f,0.f,0.f,0.f};
      const f16* ap = cellin + (size_t)arow*800 + quad*8;
      for (int c = 0; c < 25; ++c){
        f16x8 av = *(const f16x8*)(ap + c*32);
        f16x8 bx = *(const f16x8*)(swx + (size_t)(((ct*25 + c)*4 + quad)*16 + r16)*8);
        a = MFMA_F16(av, bx, a);
      }
      #pragma unroll
      for (int reg = 0; reg < 4; ++reg) zredX[0][wv-4][quad*4 + reg][r16] = a[reg];
    }
    for (int t = 0; t < 768; ++t){
      // --- GEMM phase: part0 h-GEMM (per-lane h-row tag) || part1 x-filler ---
      if (part == 0){
        if (t > 0){
          tag_wait(htag1 + arow*16, (unsigned)t);
          const f16* hp = h1buf + (size_t)((t-1)&3)*32768 + (size_t)arow*1024 + quad*8;
          f32x4 a = gemm32r(hp, bfrag);
          #pragma unroll
          for (int reg = 0; reg < 4; ++reg) zredA[wv][quad*4 + reg][r16] = a[reg];
        } else {
          #pragma unroll
          for (int reg = 0; reg < 4; ++reg) zredA[wv][quad*4 + reg][r16] = 0.f;
        }
      } else if (t < 767){
        f32x4 a = {0.f,0.f,0.f,0.f};
        const f16* ap = cellin + (size_t)(t+1)*25600 + (size_t)arow*800 + quad*8;
        for (int c = 0; c < 25; ++c){
          f16x8 av = *(const f16x8*)(ap + c*32);
          f16x8 bx = *(const f16x8*)(swx + (size_t)(((ct*25 + c)*4 + quad)*16 + r16)*8);
          a = MFMA_F16(av, bx, a);
        }
        #pragma unroll
        for (int reg = 0; reg < 4; ++reg) zredX[(t+1)&1][wv-4][quad*4 + reg][r16] = a[reg];
      }
      __syncthreads();
      // --- combine + biased z write to zbuf1 ---
      {
        const int xs = t & 1;
        float za  = zredA[zrt*2    ][zi][zc0] + zredX[xs][zrt*2    ][zi][zc0] + zb0;
        float zbv = zredA[zrt*2 + 1][zi][zc0] + zredX[xs][zrt*2 + 1][zi][zc0] + zb1;
        float* zp = zbuf1 + (size_t)zrow*4096;
        st_wt_f32(zp + ((zc0 >> 3) << 10) + ub0 + (zc0 & 7), za);
        st_wt_f32(zp + ((zc1 >> 3) << 10) + ub0 + (zc1 & 7), zbv);
      }
      vm_drain(); __syncthreads();
      if (tid == 0) st_tag(ztag1 + blk*16, (unsigned)(t+1));
      // --- owner gate phase (blocks 0..31): per-slice z tag + load ---
      if (blk < 32){
        if (t >= 4 && tid >= 256 && tid < 384)
          tag_wait(ctag + (tid-256)*16, (unsigned)(t-3));
        tag_wait(ztag1 + (tid & 127)*16, (unsigned)(t+1));
        f32x4 va, vb;
        ld_8f32(zbuf1 + (size_t)blk*4096 + tid*8, va, vb);
        *(f32x4*)(zs + tid*8)     = va;
        *(f32x4*)(zs + tid*8 + 4) = vb;
        float s = va.x+va.y+va.z+va.w + vb.x+vb.y+vb.z+vb.w;
        float q = va.x*va.x+va.y*va.y+va.z*va.z+va.w*va.w
                + vb.x*vb.x+vb.y*vb.y+vb.z*vb.z+vb.w*vb.w;
        s += __shfl_down(s, 32); q += __shfl_down(q, 32);
        s += __shfl_down(s, 16); q += __shfl_down(q, 16);
        s += __shfl_down(s, 8);  q += __shfl_down(q, 8);
        s += __shfl_down(s, 4);  q += __shfl_down(q, 4);
        s += __shfl_down(s, 2);  q += __shfl_down(q, 2);
        s += __shfl_down(s, 1);  q += __shfl_down(q, 1);
        if (lane == 0){ wredS1[wv] = s; wredQ1[wv] = q; }
        __syncthreads();
        float S = 0.f, Q = 0.f;
        #pragma unroll
        for (int w = 0; w < 8; ++w){ S += wredS1[w]; Q += wredQ1[w]; }
        const float m1 = S * (1.f/4096.f);
        const float rs1 = rsqrtf(Q*(1.f/4096.f) - m1*m1 + 1e-5f);
        float oo[2];
        #pragma unroll
        for (int k = 0; k < 2; ++k){
          const int u = 2*tid + k;
          const float ziv = (zs[u]        - m1)*rs1*pgv[0][k] + pbv[0][k];
          const float zf  = (zs[1024 + u] - m1)*rs1*pgv[1][k] + pbv[1][k];
          const float zg  = (zs[2048 + u] - m1)*rs1*pgv[2][k] + pbv[2][k];
          const float zo  = (zs[3072 + u] - m1)*rs1*pgv[3][k] + pbv[3][k];
          cst[k] = sigf(zf)*cst[k] + sigf(ziv)*tanhfast(zg);
          oo[k] = sigf(zo);
        }
        float s2 = cst[0] + cst[1], q2 = cst[0]*cst[0] + cst[1]*cst[1];
        s2 += __shfl_down(s2, 32); q2 += __shfl_down(q2, 32);
        s2 += __shfl_down(s2, 16); q2 += __shfl_down(q2, 16);
        s2 += __shfl_down(s2, 8);  q2 += __shfl_down(q2, 8);
        s2 += __shfl_down(s2, 4);  q2 += __shfl_down(q2, 4);
        s2 += __shfl_down(s2, 2);  q2 += __shfl_down(q2, 2);
        s2 += __shfl_down(s2, 1);  q2 += __shfl_down(q2, 1);
        if (lane == 0){ wredS2[wv] = s2; wredQ2[wv] = q2; }
        __syncthreads();
        float S2 = 0.f, Q2 = 0.f;
        #pragma unroll
        for (int w = 0; w < 8; ++w){ S2 += wredS2[w]; Q2 += wredQ2[w]; }
        const float m2 = S2 * (1.f/1024.f);
        const float rs2 = rsqrtf(Q2*(1.f/1024.f) - m2*m2 + 1e-5f);
        union { f16 f[2]; unsigned u32v; } pk;
        #pragma unroll
        for (int k = 0; k < 2; ++k){
          float arg = fmaf(fmaf(cst[k], rs2, -m2*rs2), gcv[k], bcv[k]);
          float e = exp2f(arg * LOG2E2);
          pk.f[k] = (f16)(oo[k] * fmaf(-2.f, __builtin_amdgcn_rcpf(e + 1.f), 1.f));
        }
        st_wt_u32(h1buf + (size_t)(t&3)*32768 + blk*1024 + 2*tid, pk.u32v);
        vm_drain(); __syncthreads();
        if (tid == 0) st_tag(htag1 + blk*16, (unsigned)(t+1));
      }
    }
  } else {
    // ======================= LAYER 2 =======================
    const int blk2 = blk - 128, ub0 = blk2*8;
    const int colg = (g_b << 10) + ub0 + u_b;
    {
      const f16* wsrc = w2T + (size_t)colg*2048 + (part == 0 ? 1024 : 0);
      #pragma unroll
      for (int c = 0; c < 32; ++c)
        bfrag[c] = *(const f16x8*)(wsrc + c*32 + quad*8);
    }
    const float zb0 = b2v[((zc0 >> 3) << 10) + ub0 + (zc0 & 7)];
    const float zb1 = b2v[((zc1 >> 3) << 10) + ub0 + (zc1 & 7)];
    float pgv[4][2], pbv[4][2], gcv[2], bcv[2], cst[2] = {0.f, 0.f};
    if (blk2 < 32){
      #pragma unroll
      for (int k = 0; k < 2; ++k){
        const int u = 2*tid + k;
        #pragma unroll
        for (int g = 0; g < 4; ++g){
          pgv[g][k] = g2[(g << 10) + u]; pbv[g][k] = bn2[(g << 10) + u];
        }
        gcv[k] = gc2v[u]; bcv[k] = bc2v[u];
      }
    }
    __syncthreads();
    for (int t = 0; t < 768; ++t){
      // --- GEMM: part0 h2(t-1) row-gated; part1 h1(t) row-gated ---
      if (part == 0){
        if (t > 0){
          tag_wait(htag2 + arow*16, (unsigned)t);
          const f16* hp = h2buf + (size_t)((t+1)&1)*32768 + (size_t)arow*1024 + quad*8;
          f32x4 a = gemm32r(hp, bfrag);
          #pragma unroll
          for (int reg = 0; reg < 4; ++reg) zredA[wv][quad*4 + reg][r16] = a[reg];
        } else {
          #pragma unroll
          for (int reg = 0; reg < 4; ++reg) zredA[wv][quad*4 + reg][r16] = 0.f;
        }
      } else {
        tag_wait(htag1 + arow*16, (unsigned)(t+1));
        const f16* hp = h1buf + (size_t)(t&3)*32768 + (size_t)arow*1024 + quad*8;
        f32x4 a = gemm32r(hp, bfrag);
        #pragma unroll
        for (int reg = 0; reg < 4; ++reg) zredA[wv][quad*4 + reg][r16] = a[reg];
      }
      __syncthreads();
      if (tid == 0) st_tag(ctag + blk2*16, (unsigned)(t+1));   // h1(t) consumed
      // --- combine + biased z2 write to zbuf2 ---
      {
        float za  = zredA[zrt*2    ][zi][zc0] + zredA[4 + zrt*2    ][zi][zc0] + zb0;
        float zbv = zredA[zrt*2 + 1][zi][zc0] + zredA[4 + zrt*2 + 1][zi][zc0] + zb1;
        float* zp = zbuf2 + (size_t)zrow*4096;
        st_wt_f32(zp + ((zc0 >> 3) << 10) + ub0 + (zc0 & 7), za);
        st_wt_f32(zp + ((zc1 >> 3) << 10) + ub0 + (zc1 & 7), zbv);
      }
      vm_drain(); __syncthreads();
      if (tid == 0) st_tag(ztag2 + blk2*16, (unsigned)(t+1));
      // --- owner gate phase (blocks 128..159): per-slice z tag + load ---
      if (blk2 < 32){
        tag_wait(ztag2 + (tid & 127)*16, (unsigned)(t+1));
        f32x4 va, vb;
        ld_8f32(zbuf2 + (size_t)blk2*4096 + tid*8, va, vb);
        *(f32x4*)(zs + tid*8)     = va;
        *(f32x4*)(zs + tid*8 + 4) = vb;
        float s = va.x+va.y+va.z+va.w + vb.x+vb.y+vb.z+vb.w;
        float q = va.x*va.x+va.y*va.y+va.z*va.z+va.w*va.w
                + vb.x*vb.x+vb.y*vb.y+vb.z*vb.z+vb.w*vb.w;
        s += __shfl_down(s, 32); q += __shfl_down(q, 32);
        s += __shfl_down(s, 16); q += __shfl_down(q, 16);
        s += __shfl_down(s, 8);  q += __shfl_down(q, 8);
        s += __shfl_down(s, 4);  q += __shfl_down(q, 4);
        s += __shfl_down(s, 2);  q += __shfl_down(q, 2);
        s += __shfl_down(s, 1);  q += __shfl_down(q, 1);
        if (lane == 0){ wredS1[wv] = s; wredQ1[wv] = q; }
        __syncthreads();
        float S = 0.f, Q = 0.f;
        #pragma unroll
        for (int w = 0; w < 8; ++w){ S += wredS1[w]; Q += wredQ1[w]; }
        const float m1 = S * (1.f/4096.f);
        const float rs1 = rsqrtf(Q*(1.f/4096.f) - m1*m1 + 1e-5f);
        float oo[2];
        #pragma unroll
        for (int k = 0; k < 2; ++k){
          const int u = 2*tid + k;
          const float ziv = (zs[u]        - m1)*rs1*pgv[0][k] + pbv[0][k];
          const float zf  = (zs[1024 + u] - m1)*rs1*pgv[1][k] + pbv[1][k];
          const float zg  = (zs[2048 + u] - m1)*rs1*pgv[2][k] + pbv[2][k];
          const float zo  = (zs[3072 + u] - m1)*rs1*pgv[3][k] + pbv[3][k];
          cst[k] = sigf(zf)*cst[k] + sigf(ziv)*tanhfast(zg);
          oo[k] = sigf(zo);
        }
        float s2 = cst[0] + cst[1], q2 = cst[0]*cst[0] + cst[1]*cst[1];
        s2 += __shfl_down(s2, 32); q2 += __shfl_down(q2, 32);
        s2 += __shfl_down(s2, 16); q2 += __shfl_down(q2, 16);
        s2 += __shfl_down(s2, 8);  q2 += __shfl_down(q2, 8);
        s2 += __shfl_down(s2, 4);  q2 += __shfl_down(q2, 4);
        s2 += __shfl_down(s2, 2);  q2 += __shfl_down(q2, 2);
        s2 += __shfl_down(s2, 1);  q2 += __shfl_down(q2, 1);
        if (lane == 0){ wredS2[wv] = s2; wredQ2[wv] = q2; }
        __syncthreads();
        float S2 = 0.f, Q2 = 0.f;
        #pragma unroll
        for (int w = 0; w < 8; ++w){ S2 += wredS2[w]; Q2 += wredQ2[w]; }
        const float m2 = S2 * (1.f/1024.f);
        const float rs2 = rsqrtf(Q2*(1.f/1024.f) - m2*m2 + 1e-5f);
        union { f16 f[2]; unsigned u32v; } pk;
        #pragma unroll
        for (int k = 0; k < 2; ++k){
          float arg = fmaf(fmaf(cst[k], rs2, -m2*rs2), gcv[k], bcv[k]);
          float e = exp2f(arg * LOG2E2);
          pk.f[k] = (f16)(oo[k] * fmaf(-2.f, __builtin_amdgcn_rcpf(e + 1.f), 1.f));
        }
        st_wt_u32(h2buf + (size_t)(t&1)*32768 + blk2*1024 + 2*tid, pk.u32v);
        st_wt_u32(H2all + (size_t)(t+1)*32768 + blk2*1024 + 2*tid, pk.u32v);
        vm_drain(); __syncthreads();
        if (tid == 0) st_tag(htag2 + blk2*16, (unsigned)(t+1));
      }
    }
  }
}

// ---------------------------------------------------------------------------
__global__ __launch_bounds__(256) void k_proj(const f16* __restrict__ H2all, const f16* __restrict__ cellin,
    const f16* __restrict__ projT, const float* __restrict__ projb, float* __restrict__ out){
  const int t = blockIdx.x, tid = threadIdx.x;
  const int lane = tid & 63, wv = tid >> 6;
  const int r16 = lane & 15, quad = lane >> 4;
  __shared__ float pred[4][32][84];
  f32x4 acc[2][5] = {};
  const f16* H2 = H2all + (size_t)(t+1)*32768;
  const f16* CI = cellin + (size_t)t*32*800;
  const int kbeg = wv*13;
  const int kend = (wv == 3) ? 49 : (kbeg + 13);
  for (int ks = kbeg; ks < kend; ++ks){
    const int k0 = ks*32 + quad*8;
    f16x8 a0, a1;
    if (ks < 32){
      a0 = *(const f16x8*)(H2 + r16*1024 + k0);
      a1 = *(const f16x8*)(H2 + (16+r16)*1024 + k0);
    } else {
      a0 = *(const f16x8*)(CI + r16*800 + 256 + (k0 - 1024));
      a1 = *(const f16x8*)(CI + (16+r16)*800 + 256 + (k0 - 1024));
    }
    f16x8 bf[5];
    #pragma unroll
    for (int nt = 0; nt < 5; ++nt)
      bf[nt] = *(const f16x8*)(projT + (size_t)(nt*16 + r16)*1568 + k0);
    #pragma unroll
    for (int nt = 0; nt < 5; ++nt){
      acc[0][nt] = MFMA_F16(a0, bf[nt], acc[0][nt]);
      acc[1][nt] = MFMA_F16(a1, bf[nt], acc[1][nt]);
    }
  }
  #pragma unroll
  for (int mt = 0; mt < 2; ++mt)
    #pragma unroll
    for (int nt = 0; nt < 5; ++nt)
      #pragma unroll
      for (int reg = 0; reg < 4; ++reg)
        pred[wv][mt*16 + quad*4 + reg][nt*16 + r16] = acc[mt][nt][reg];
  __syncthreads();
  for (int e = tid; e < 2560; e += 256){
    int m = e >> 5, b = e & 31;
    float v = pred[0][b][m] + pred[1][b][m] + pred[2][b][m] + pred[3][b][m] + projb[m];
    out[(size_t)b*61440 + (size_t)m*768 + t] = v;
  }
}

// ---------------------------------------------------------------------------
extern "C" void kernel_launch(void* const* d_in, const int* in_sizes, int n_in,
                              void* d_out, int out_size, void* d_ws, size_t ws_size,
                              hipStream_t stream)
{
  const float* duration = (const float*)d_in[0];
  const float* decoder  = (const float*)d_in[1];
  const float* pre_w1   = (const float*)d_in[3];
  const float* pre_w2   = (const float*)d_in[4];
  const float* rnn1_wx  = (const float*)d_in[5];
  const float* rnn1_wh  = (const float*)d_in[6];
  const float* rnn1_b   = (const float*)d_in[7];
  const float* rnn1_g   = (const float*)d_in[8];
  const float* rnn1_bn  = (const float*)d_in[9];
  const float* rnn1_gc  = (const float*)d_in[10];
  const float* rnn1_bc  = (const float*)d_in[11];
  const float* rnn2_wx  = (const float*)d_in[12];
  const float* rnn2_wh  = (const float*)d_in[13];
  const float* rnn2_b   = (const float*)d_in[14];
  const float* rnn2_g   = (const float*)d_in[15];
  const float* rnn2_bn  = (const float*)d_in[16];
  const float* rnn2_gc  = (const float*)d_in[17];
  const float* rnn2_bc  = (const float*)d_in[18];
  const float* proj_w   = (const float*)d_in[19];
  const float* proj_b   = (const float*)d_in[20];
  float* out = (float*)d_out;

  char* w = (char*)d_ws;
  f16* cellin = (f16*)w;      w += (size_t)24576*800*2;
  f16* wxT1   = (f16*)w;      w += (size_t)4096*800*2;
  f16* whT1   = (f16*)w;      w += (size_t)4096*1024*2;
  f16* w2T    = (f16*)w;      w += (size_t)4096*2048*2;
  f16* projT  = (f16*)w;      w += 262144;
  f16* H2all  = (f16*)w;      w += (size_t)769*32768*2;
  f16* h1buf  = (f16*)w;      w += 262144;   // 4 slots x 32x1024 f16
  f16* h2buf  = (f16*)w;      w += 131072;   // 2 slots
  float* zbuf1 = (float*)w;   w += (size_t)32*4096*4;
  float* zbuf2 = (float*)w;   w += (size_t)32*4096*4;
  unsigned* tags = (unsigned*)w; w += 28672;
  const size_t need = (size_t)((char*)w - (char*)d_ws);
  if (ws_size < need){
    k_ws_report<<<(out_size + 255)/256, 256, 0, stream>>>(out, out_size, (float)(ws_size >> 20));
    return;
  }

  (void)hipMemsetAsync(tags, 0, 28672, stream);
  (void)hipMemsetAsync(h1buf, 0, 262144, stream);
  (void)hipMemsetAsync(h2buf, 0, 131072, stream);

  k_transpose_f16<<<dim3(4096/32, 25), 256, 0, stream>>>(rnn1_wx, wxT1, 800, 4096, 800, 0);
  k_transpose_f16<<<dim3(4096/32, 32), 256, 0, stream>>>(rnn1_wh, whT1, 1024, 4096, 1024, 0);
  k_transpose_f16<<<dim3(4096/32, 32), 256, 0, stream>>>(rnn2_wx, w2T, 1024, 4096, 2048, 0);
  k_transpose_f16<<<dim3(4096/32, 32), 256, 0, stream>>>(rnn2_wh, w2T, 1024, 4096, 2048, 1024);
  k_transpose_f16<<<dim3(3, 49), 256, 0, stream>>>(proj_w, projT, 1568, 80, 1568, 0);
  k_prenet<<<768, 256, 0, stream>>>(decoder, pre_w1, pre_w2, cellin);
  k_durfill<<<768, 256, 0, stream>>>(duration, cellin);
  k_recurrence<<<256, 512, 0, stream>>>(cellin, wxT1, whT1, w2T, H2all, h1buf, h2buf,
      zbuf1, zbuf2, tags,
      rnn1_b, rnn1_g, rnn1_bn, rnn1_gc, rnn1_bc,
      rnn2_b, rnn2_g, rnn2_bn, rnn2_gc, rnn2_bc);
  k_proj<<<768, 256, 0, stream>>>(H2all, cellin, projT, proj_b, out);
}